// Round 1
// baseline (1033.451 us; speedup 1.0000x reference)
//
#include <hip/hip_runtime.h>

#define NN 20000
#define NE 320000
#define EP (NE + NN)          // 340000 edges incl. self loops
#define NG 8
#define NHEAD 4
#define NCH 64
#define HC 256
#define NODE_IN 18
#define HID 64
#define NEG_SLOPE 0.2f
#define BN_EPS 1e-5f

// ---------------- workspace layout (float offsets) ----------------
#define OFF_XL    0u                      // [NN*256]
#define OFF_XR    5120000u                // [NN*256]
#define OFF_H1    10240000u               // [NN*256]
#define OFF_H0    15360000u               // [NN*64]  (h0, later reused as h2)
#define OFF_H3    16640000u               // [NN*64]
#define OFF_ZERO  17920000u               // start of zeroed region
#define OFF_LA    17920000u               // loop_attr [NN*4]
#define OFF_CNT   18000000u               // uint cnt [NN]
#define OFF_PSUM  18020000u               // [8*64]
#define OFF_PMAX  18020512u               // [8*64]
#define OFF_PCNT  18021024u               // [16]
#define ZERO_FLOATS (18021040u - 17920000u)
#define OFF_LOGIT 18021040u               // [EP*4]
#define OFF_RP    19381040u               // int [NN+1]
#define OFF_POS   19401041u               // int [NN]
#define OFF_EID   19421041u               // int [EP]

__device__ __forceinline__ float wave_sum(float v) {
  #pragma unroll
  for (int o = 32; o; o >>= 1) v += __shfl_xor(v, o);
  return v;
}
__device__ __forceinline__ float wave_max(float v) {
  #pragma unroll
  for (int o = 32; o; o >>= 1) v = fmaxf(v, __shfl_xor(v, o));
  return v;
}

// ------------------------------------------------------------------
// K1: per-dst edge count + sum of edge_attr (for self-loop fill 'mean')
__global__ __launch_bounds__(256) void k_edge_stats(
    const int* __restrict__ ei, const float* __restrict__ ea,
    float* __restrict__ loop_attr, unsigned* __restrict__ cnt) {
  int e = blockIdx.x * 256 + threadIdx.x;
  if (e >= NE) return;
  int d = ei[NE + e];
  atomicAdd(&cnt[d], 1u);
  #pragma unroll
  for (int j = 0; j < 4; j++) atomicAdd(&loop_attr[d * 4 + j], ea[e * 4 + j]);
}

__global__ __launch_bounds__(256) void k_loop_finalize(
    float* __restrict__ loop_attr, const unsigned* __restrict__ cnt) {
  int i = blockIdx.x * 256 + threadIdx.x;
  if (i >= NN * 4) return;
  float c = (float)cnt[i >> 2];
  if (c < 1.f) c = 1.f;
  loop_attr[i] = loop_attr[i] / c;
}

// ------------------------------------------------------------------
// K3: encoder: h0 = relu(x@W1+b1)@W2+b2   (one node per thread)
__global__ __launch_bounds__(256) void k_encoder(
    const float* __restrict__ x, const float* __restrict__ w1, const float* __restrict__ b1,
    const float* __restrict__ w2, const float* __restrict__ b2, float* __restrict__ h0) {
  __shared__ float W1[NODE_IN * HID];
  __shared__ float W2[HID * HID];
  __shared__ float B1[HID];
  __shared__ float B2[HID];
  for (int i = threadIdx.x; i < NODE_IN * HID; i += 256) W1[i] = w1[i];
  for (int i = threadIdx.x; i < HID * HID; i += 256) W2[i] = w2[i];
  if (threadIdx.x < HID) { B1[threadIdx.x] = b1[threadIdx.x]; B2[threadIdx.x] = b2[threadIdx.x]; }
  __syncthreads();
  int n = blockIdx.x * 256 + threadIdx.x;
  if (n >= NN) return;
  float xi[NODE_IN];
  #pragma unroll
  for (int i = 0; i < NODE_IN; i++) xi[i] = x[n * NODE_IN + i];
  float hid[HID];
  for (int j = 0; j < HID; j++) {
    float s = B1[j];
    #pragma unroll
    for (int i = 0; i < NODE_IN; i++) s += xi[i] * W1[i * HID + j];
    hid[j] = fmaxf(s, 0.f);
  }
  for (int j = 0; j < HID; j++) {
    float s = B2[j];
    #pragma unroll 8
    for (int k = 0; k < HID; k++) s += hid[k] * W2[k * HID + j];
    h0[(size_t)n * HID + j] = s;
  }
}

// ------------------------------------------------------------------
// K_scan: exclusive scan of (cnt[i]+1) -> row_ptr, pos  (single block)
__global__ __launch_bounds__(256) void k_scan(
    const unsigned* __restrict__ cnt, int* __restrict__ row_ptr, int* __restrict__ pos) {
  __shared__ int lds[256];
  __shared__ int carry;
  int tid = threadIdx.x;
  if (tid == 0) carry = 0;
  __syncthreads();
  for (int base = 0; base < NN; base += 256) {
    int idx = base + tid;
    int v = (idx < NN) ? ((int)cnt[idx] + 1) : 0;
    lds[tid] = v;
    __syncthreads();
    for (int off = 1; off < 256; off <<= 1) {
      int t = (tid >= off) ? lds[tid - off] : 0;
      __syncthreads();
      lds[tid] += t;
      __syncthreads();
    }
    int excl = carry + lds[tid] - v;
    if (idx < NN) { row_ptr[idx] = excl; pos[idx] = excl; }
    __syncthreads();
    if (tid == 0) carry += lds[255];
    __syncthreads();
  }
  if (tid == 0) row_ptr[NN] = carry;   // == EP
}

__global__ __launch_bounds__(256) void k_csr_scatter(
    const int* __restrict__ ei, int* __restrict__ pos, int* __restrict__ eid) {
  int e = blockIdx.x * 256 + threadIdx.x;
  if (e >= EP) return;
  int d = (e < NE) ? ei[NE + e] : (e - NE);
  int p = atomicAdd(&pos[d], 1);
  eid[p] = e;
}

// ------------------------------------------------------------------
// K4: OUT[NN][256] = A[NN][K] @ W[K][256]  (32 nodes x 256 cols / block)
template <int K>
__global__ __launch_bounds__(256) void k_gemm256(
    const float* __restrict__ A, const float* __restrict__ W, float* __restrict__ OUT) {
  __shared__ float Wl[32 * 256];
  __shared__ float Al[32 * 36];
  const int tid = threadIdx.x;
  const int n0 = blockIdx.x * 32;
  const int tx = tid & 63, ty = tid >> 6;
  float acc[8][4];
  #pragma unroll
  for (int m = 0; m < 8; m++)
    #pragma unroll
    for (int c = 0; c < 4; c++) acc[m][c] = 0.f;

  for (int kt = 0; kt < K; kt += 32) {
    #pragma unroll
    for (int r = 0; r < 8; r++) {
      int i4 = tid + 256 * r;            // 2048 float4 = 8192 floats
      int row = i4 >> 6;
      int col4 = (i4 & 63) * 4;
      *(float4*)&Wl[row * 256 + col4] = *(const float4*)&W[(size_t)(kt + row) * 256 + col4];
    }
    {
      int m = tid >> 3, kk = (tid & 7) * 4;
      float4 av = *(const float4*)&A[(size_t)(n0 + m) * K + kt + kk];
      Al[(kk + 0) * 36 + m] = av.x;
      Al[(kk + 1) * 36 + m] = av.y;
      Al[(kk + 2) * 36 + m] = av.z;
      Al[(kk + 3) * 36 + m] = av.w;
    }
    __syncthreads();
    #pragma unroll 8
    for (int k = 0; k < 32; k++) {
      float4 b = *(float4*)&Wl[k * 256 + tx * 4];
      float4 a0v = *(float4*)&Al[k * 36 + ty * 8];
      float4 a1v = *(float4*)&Al[k * 36 + ty * 8 + 4];
      float am[8] = {a0v.x, a0v.y, a0v.z, a0v.w, a1v.x, a1v.y, a1v.z, a1v.w};
      #pragma unroll
      for (int m = 0; m < 8; m++) {
        acc[m][0] += am[m] * b.x;
        acc[m][1] += am[m] * b.y;
        acc[m][2] += am[m] * b.z;
        acc[m][3] += am[m] * b.w;
      }
    }
    __syncthreads();
  }
  #pragma unroll
  for (int m = 0; m < 8; m++) {
    float4 o = {acc[m][0], acc[m][1], acc[m][2], acc[m][3]};
    *(float4*)&OUT[(size_t)(n0 + ty * 8 + m) * 256 + tx * 4] = o;
  }
}

// ------------------------------------------------------------------
// K5: per-edge GATv2 logits (1 wave per edge, lane = channel)
__global__ __launch_bounds__(256) void k_gat_logits(
    const float* __restrict__ xl, const float* __restrict__ xr,
    const float* __restrict__ we, const float* __restrict__ att,
    const int* __restrict__ ei, const float* __restrict__ ea,
    const float* __restrict__ loop_attr, float* __restrict__ logits) {
  int lane = threadIdx.x & 63;
  int e = blockIdx.x * 4 + (threadIdx.x >> 6);
  int s, d;
  const float* ap;
  if (e < NE) { s = ei[e]; d = ei[NE + e]; ap = &ea[(size_t)e * 4]; }
  else        { s = e - NE; d = s;         ap = &loop_attr[(size_t)(e - NE) * 4]; }
  float a0 = ap[0], a1 = ap[1], a2 = ap[2], a3 = ap[3];
  const float* xls = &xl[(size_t)s * HC];
  const float* xrd = &xr[(size_t)d * HC];
  #pragma unroll
  for (int h = 0; h < 4; h++) {
    int c = h * 64 + lane;
    float vee = a0 * we[c] + a1 * we[256 + c] + a2 * we[512 + c] + a3 * we[768 + c];
    float m = xls[c] + xrd[c] + vee;
    m = (m > 0.f) ? m : NEG_SLOPE * m;
    float v = wave_sum(m * att[c]);
    if (lane == 0) logits[(size_t)e * 4 + h] = v;
  }
}

// ------------------------------------------------------------------
// K6: per-node softmax + aggregation (+bias,+BN,+ELU).  1 wave / node.
template <int CONCAT>
__global__ __launch_bounds__(256) void k_gat_aggregate(
    const float* __restrict__ xl, const float* __restrict__ logits,
    const int* __restrict__ row_ptr, const int* __restrict__ eid,
    const int* __restrict__ ei, const float* __restrict__ bias,
    const float* __restrict__ bng, const float* __restrict__ bnb,
    float* __restrict__ outp) {
  int lane = threadIdx.x & 63;
  int i = blockIdx.x * 4 + (threadIdx.x >> 6);
  int start = row_ptr[i], end = row_ptr[i + 1];
  float mx0 = -1e30f, mx1 = -1e30f, mx2 = -1e30f, mx3 = -1e30f;
  for (int j = start + lane; j < end; j += 64) {
    const float* lg = &logits[(size_t)eid[j] * 4];
    mx0 = fmaxf(mx0, lg[0]); mx1 = fmaxf(mx1, lg[1]);
    mx2 = fmaxf(mx2, lg[2]); mx3 = fmaxf(mx3, lg[3]);
  }
  mx0 = wave_max(mx0); mx1 = wave_max(mx1); mx2 = wave_max(mx2); mx3 = wave_max(mx3);
  float dn0 = 0.f, dn1 = 0.f, dn2 = 0.f, dn3 = 0.f;
  for (int j = start + lane; j < end; j += 64) {
    const float* lg = &logits[(size_t)eid[j] * 4];
    dn0 += expf(lg[0] - mx0); dn1 += expf(lg[1] - mx1);
    dn2 += expf(lg[2] - mx2); dn3 += expf(lg[3] - mx3);
  }
  dn0 = wave_sum(dn0); dn1 = wave_sum(dn1); dn2 = wave_sum(dn2); dn3 = wave_sum(dn3);
  float r0 = 1.f / dn0, r1 = 1.f / dn1, r2 = 1.f / dn2, r3 = 1.f / dn3;
  float acc0 = 0.f, acc1 = 0.f, acc2 = 0.f, acc3 = 0.f;
  for (int j = start; j < end; ++j) {
    int e = eid[j];
    int s = (e < NE) ? ei[e] : (e - NE);
    const float* lg = &logits[(size_t)e * 4];
    const float* xs = &xl[(size_t)s * HC];
    float w0 = expf(lg[0] - mx0) * r0;
    float w1 = expf(lg[1] - mx1) * r1;
    float w2 = expf(lg[2] - mx2) * r2;
    float w3 = expf(lg[3] - mx3) * r3;
    acc0 += w0 * xs[lane];
    acc1 += w1 * xs[64 + lane];
    acc2 += w2 * xs[128 + lane];
    acc3 += w3 * xs[192 + lane];
  }
  const float inv_sqrt = rsqrtf(1.f + BN_EPS);
  if (CONCAT) {
    float a[4] = {acc0, acc1, acc2, acc3};
    #pragma unroll
    for (int h = 0; h < 4; h++) {
      int c = h * 64 + lane;
      float v = a[h] + bias[c];
      v = v * (bng[c] * inv_sqrt) + bnb[c];
      v = (v > 0.f) ? v : (expf(v) - 1.f);          // ELU
      outp[(size_t)i * 256 + c] = v;
    }
  } else {
    float v = 0.25f * (acc0 + acc1 + acc2 + acc3) + bias[lane];
    v = v * (bng[lane] * inv_sqrt) + bnb[lane];
    v = (v > 0.f) ? v : (expf(v) - 1.f);
    outp[(size_t)i * 64 + lane] = v;
  }
}

// ------------------------------------------------------------------
// K8: fused SAGE: h3 = relu(bn3(mean_agg@wl + bl + h2@wr))  (1 wave/node)
__global__ __launch_bounds__(256) void k_sage(
    const float* __restrict__ h2, const int* __restrict__ row_ptr,
    const int* __restrict__ eid, const int* __restrict__ ei,
    const unsigned* __restrict__ cnt,
    const float* __restrict__ wl, const float* __restrict__ bl,
    const float* __restrict__ wr, const float* __restrict__ bng,
    const float* __restrict__ bnb, float* __restrict__ h3) {
  __shared__ float agg_s[4][64];
  __shared__ float h2_s[4][64];
  int lane = threadIdx.x & 63;
  int w = threadIdx.x >> 6;
  int i = blockIdx.x * 4 + w;
  int start = row_ptr[i], end = row_ptr[i + 1];
  float a = 0.f;
  for (int j = start; j < end; ++j) {
    int e = eid[j];
    if (e < NE) a += h2[(size_t)ei[e] * 64 + lane];
  }
  float c = (float)cnt[i];
  if (c < 1.f) c = 1.f;
  agg_s[w][lane] = a / c;
  h2_s[w][lane] = h2[(size_t)i * 64 + lane];
  __syncthreads();
  float s = bl[lane];
  #pragma unroll 4
  for (int k = 0; k < 64; k++)
    s += agg_s[w][k] * wl[k * 64 + lane] + h2_s[w][k] * wr[k * 64 + lane];
  s = s * (bng[lane] * rsqrtf(1.f + BN_EPS)) + bnb[lane];
  s = fmaxf(s, 0.f);
  h3[(size_t)i * 64 + lane] = s;
}

// ------------------------------------------------------------------
// K9: pooling: per-graph sum / max / count   (thread = (node-group, feat))
__global__ __launch_bounds__(256) void k_pool(
    const float* __restrict__ h3, const int* __restrict__ batch,
    float* __restrict__ psum, float* __restrict__ pmax, float* __restrict__ pcnt) {
  int j = threadIdx.x & 63, grp = threadIdx.x >> 6;
  int nbase = blockIdx.x * 256 + grp * 64;
  float s = 0.f, m = 0.f, cn = 0.f;
  int cur = -1;
  for (int t = 0; t < 64; t++) {
    int n = nbase + t;
    if (n >= NN) break;
    int g = batch[n];
    if (g != cur) {
      if (cur >= 0) {
        atomicAdd(&psum[cur * 64 + j], s);
        atomicMax((int*)&pmax[cur * 64 + j], __float_as_int(m));
        if (j == 0) atomicAdd(&pcnt[cur], cn);
      }
      cur = g; s = 0.f; m = 0.f; cn = 0.f;
    }
    float v = h3[(size_t)n * 64 + j];
    s += v; m = fmaxf(m, v); cn += 1.f;
  }
  if (cur >= 0) {
    atomicAdd(&psum[cur * 64 + j], s);
    atomicMax((int*)&pmax[cur * 64 + j], __float_as_int(m));
    if (j == 0) atomicAdd(&pcnt[cur], cn);
  }
}

// ------------------------------------------------------------------
// K10: graph head (block per graph, 64 threads)
__global__ void k_graph_head(
    const float* __restrict__ psum, const float* __restrict__ pmax,
    const float* __restrict__ pcnt,
    const float* __restrict__ w1, const float* __restrict__ b1,
    const float* __restrict__ w2, const float* __restrict__ b2,
    const float* __restrict__ w3, const float* __restrict__ b3,
    float* __restrict__ out) {
  __shared__ float hp[128];
  __shared__ float z1[64];
  __shared__ float z2[32];
  int g = blockIdx.x, j = threadIdx.x;
  float c = pcnt[g];
  if (c < 1.f) c = 1.f;
  hp[j] = psum[g * 64 + j] / c;
  hp[64 + j] = pmax[g * 64 + j];
  __syncthreads();
  float s = b1[j];
  #pragma unroll 8
  for (int k = 0; k < 128; k++) s += hp[k] * w1[k * 64 + j];
  z1[j] = fmaxf(s, 0.f);
  __syncthreads();
  if (j < 32) {
    float s2 = b2[j];
    #pragma unroll 8
    for (int k = 0; k < 64; k++) s2 += z1[k] * w2[k * 32 + j];
    z2[j] = fmaxf(s2, 0.f);
  }
  __syncthreads();
  if (j == 0) {
    float s3 = b3[0];
    #pragma unroll
    for (int k = 0; k < 32; k++) s3 += z2[k] * w3[k];
    out[g] = 1.f / (1.f + expf(-s3));
  }
}

// ------------------------------------------------------------------
// K11: edge head (thread per edge; weights read lane-uniform -> s_load)
__global__ __launch_bounds__(256) void k_edge_head(
    const float* __restrict__ h3, const int* __restrict__ ei,
    const float* __restrict__ ea,
    const float* __restrict__ w1, const float* __restrict__ b1,
    const float* __restrict__ w2, const float* __restrict__ b2,
    float* __restrict__ out) {
  int e = blockIdx.x * 256 + threadIdx.x;
  if (e >= NE) return;
  int s = ei[e], d = ei[NE + e];
  float acc[32];
  #pragma unroll
  for (int j = 0; j < 32; j++) acc[j] = b1[j];
  const float4* hs = (const float4*)&h3[(size_t)s * 64];
  const float4* hd = (const float4*)&h3[(size_t)d * 64];
  for (int k4 = 0; k4 < 16; k4++) {
    float4 v = hs[k4];
    const float* w = &w1[k4 * 4 * 32];
    #pragma unroll
    for (int j = 0; j < 32; j++) acc[j] += v.x * w[j];
    #pragma unroll
    for (int j = 0; j < 32; j++) acc[j] += v.y * w[32 + j];
    #pragma unroll
    for (int j = 0; j < 32; j++) acc[j] += v.z * w[64 + j];
    #pragma unroll
    for (int j = 0; j < 32; j++) acc[j] += v.w * w[96 + j];
  }
  for (int k4 = 0; k4 < 16; k4++) {
    float4 v = hd[k4];
    const float* w = &w1[(64 + k4 * 4) * 32];
    #pragma unroll
    for (int j = 0; j < 32; j++) acc[j] += v.x * w[j];
    #pragma unroll
    for (int j = 0; j < 32; j++) acc[j] += v.y * w[32 + j];
    #pragma unroll
    for (int j = 0; j < 32; j++) acc[j] += v.z * w[64 + j];
    #pragma unroll
    for (int j = 0; j < 32; j++) acc[j] += v.w * w[96 + j];
  }
  {
    float4 v = *(const float4*)&ea[(size_t)e * 4];
    const float* w = &w1[128 * 32];
    #pragma unroll
    for (int j = 0; j < 32; j++) acc[j] += v.x * w[j];
    #pragma unroll
    for (int j = 0; j < 32; j++) acc[j] += v.y * w[32 + j];
    #pragma unroll
    for (int j = 0; j < 32; j++) acc[j] += v.z * w[64 + j];
    #pragma unroll
    for (int j = 0; j < 32; j++) acc[j] += v.w * w[96 + j];
  }
  float s2 = b2[0];
  #pragma unroll
  for (int j = 0; j < 32; j++) s2 += fmaxf(acc[j], 0.f) * w2[j];
  out[e] = 1.f / (1.f + expf(-s2));
}

// ------------------------------------------------------------------
extern "C" void kernel_launch(void* const* d_in, const int* in_sizes, int n_in,
                              void* d_out, int out_size, void* d_ws, size_t ws_size,
                              hipStream_t stream) {
  const float* x         = (const float*)d_in[0];
  const float* edge_attr = (const float*)d_in[1];
  const float* enc_w1 = (const float*)d_in[2];
  const float* enc_b1 = (const float*)d_in[3];
  const float* enc_w2 = (const float*)d_in[4];
  const float* enc_b2 = (const float*)d_in[5];
  const float* g1_wl = (const float*)d_in[6];
  const float* g1_wr = (const float*)d_in[7];
  const float* g1_we = (const float*)d_in[8];
  const float* g1_att = (const float*)d_in[9];
  const float* g1_b = (const float*)d_in[10];
  const float* bn1_g = (const float*)d_in[11];
  const float* bn1_b = (const float*)d_in[12];
  const float* g2_wl = (const float*)d_in[13];
  const float* g2_wr = (const float*)d_in[14];
  const float* g2_we = (const float*)d_in[15];
  const float* g2_att = (const float*)d_in[16];
  const float* g2_b = (const float*)d_in[17];
  const float* bn2_g = (const float*)d_in[18];
  const float* bn2_b = (const float*)d_in[19];
  const float* sage_wl = (const float*)d_in[20];
  const float* sage_bl = (const float*)d_in[21];
  const float* sage_wr = (const float*)d_in[22];
  const float* bn3_g = (const float*)d_in[23];
  const float* bn3_b = (const float*)d_in[24];
  const float* gh_w1 = (const float*)d_in[25];
  const float* gh_b1 = (const float*)d_in[26];
  const float* gh_w2 = (const float*)d_in[27];
  const float* gh_b2 = (const float*)d_in[28];
  const float* gh_w3 = (const float*)d_in[29];
  const float* gh_b3 = (const float*)d_in[30];
  const float* eh_w1 = (const float*)d_in[31];
  const float* eh_b1 = (const float*)d_in[32];
  const float* eh_w2 = (const float*)d_in[33];
  const float* eh_b2 = (const float*)d_in[34];
  const int* ei    = (const int*)d_in[35];
  const int* batch = (const int*)d_in[36];
  float* out = (float*)d_out;

  float* ws = (float*)d_ws;
  float* xl = ws + OFF_XL;
  float* xr = ws + OFF_XR;
  float* h1 = ws + OFF_H1;
  float* h0 = ws + OFF_H0;   // later h2
  float* h3 = ws + OFF_H3;
  float* la = ws + OFF_LA;
  unsigned* cnt = (unsigned*)(ws + OFF_CNT);
  float* psum = ws + OFF_PSUM;
  float* pmax = ws + OFF_PMAX;
  float* pcnt = ws + OFF_PCNT;
  float* logits = ws + OFF_LOGIT;
  int* row_ptr = (int*)(ws + OFF_RP);
  int* pos = (int*)(ws + OFF_POS);
  int* eid = (int*)(ws + OFF_EID);

  hipMemsetAsync(ws + OFF_ZERO, 0, ZERO_FLOATS * sizeof(float), stream);

  k_edge_stats<<<NE / 256, 256, 0, stream>>>(ei, edge_attr, la, cnt);
  k_loop_finalize<<<(NN * 4 + 255) / 256, 256, 0, stream>>>(la, cnt);
  k_encoder<<<(NN + 255) / 256, 256, 0, stream>>>(x, enc_w1, enc_b1, enc_w2, enc_b2, h0);
  k_scan<<<1, 256, 0, stream>>>(cnt, row_ptr, pos);
  k_csr_scatter<<<(EP + 255) / 256, 256, 0, stream>>>(ei, pos, eid);

  // ---- GAT layer 1 ----
  k_gemm256<64><<<NN / 32, 256, 0, stream>>>(h0, g1_wl, xl);
  k_gemm256<64><<<NN / 32, 256, 0, stream>>>(h0, g1_wr, xr);
  k_gat_logits<<<EP / 4, 256, 0, stream>>>(xl, xr, g1_we, g1_att, ei, edge_attr, la, logits);
  k_gat_aggregate<1><<<NN / 4, 256, 0, stream>>>(xl, logits, row_ptr, eid, ei, g1_b, bn1_g, bn1_b, h1);

  // ---- GAT layer 2 ----
  k_gemm256<256><<<NN / 32, 256, 0, stream>>>(h1, g2_wl, xl);
  k_gemm256<256><<<NN / 32, 256, 0, stream>>>(h1, g2_wr, xr);
  k_gat_logits<<<EP / 4, 256, 0, stream>>>(xl, xr, g2_we, g2_att, ei, edge_attr, la, logits);
  k_gat_aggregate<0><<<NN / 4, 256, 0, stream>>>(xl, logits, row_ptr, eid, ei, g2_b, bn2_g, bn2_b, h0);

  // ---- SAGE ----
  k_sage<<<NN / 4, 256, 0, stream>>>(h0, row_ptr, eid, ei, cnt, sage_wl, sage_bl, sage_wr, bn3_g, bn3_b, h3);

  // ---- pooling + heads ----
  k_pool<<<(NN + 255) / 256, 256, 0, stream>>>(h3, batch, psum, pmax, pcnt);
  k_graph_head<<<NG, 64, 0, stream>>>(psum, pmax, pcnt, gh_w1, gh_b1, gh_w2, gh_b2, gh_w3, gh_b3, out);
  k_edge_head<<<NE / 256, 256, 0, stream>>>(h3, ei, edge_attr, eh_w1, eh_b1, eh_w2, eh_b2, out + NG);
}

// Round 2
// 985.309 us; speedup vs baseline: 1.0489x; 1.0489x over previous
//
#include <hip/hip_runtime.h>

#define NN 20000
#define NE 320000
#define EP (NE + NN)          // 340000 edges incl. self loops
#define NG 8
#define HC 256
#define NODE_IN 18
#define HID 64
#define NEG_SLOPE 0.2f
#define BN_EPS 1e-5f
#define DEG_CAP 128

// ---------------- workspace layout (float offsets) ----------------
#define OFF_XL    0u                      // [NN*256]
#define OFF_XR    5120000u                // [NN*256]
#define OFF_H1    10240000u               // [NN*256]
#define OFF_H0    15360000u               // [NN*64]  (h0, later reused as h2)
#define OFF_H3    16640000u               // [NN*64]
#define OFF_ZERO  17920000u               // start of zeroed region
#define OFF_LA    17920000u               // loop_attr [NN*4]
#define OFF_CNT   18000000u               // uint cnt [NN]
#define OFF_PSUM  18020000u               // [8*64]
#define OFF_PMAX  18020512u               // [8*64]
#define OFF_PCNT  18021024u               // [16]
#define ZERO_FLOATS (18021040u - 17920000u)
#define OFF_RP    19381040u               // int [NN+1]
#define OFF_POS   19401041u               // int [NN]
#define OFF_EID   19421041u               // int [EP]

// ------------------------------------------------------------------
// K1: per-dst edge count + sum of edge_attr (for self-loop fill 'mean')
__global__ __launch_bounds__(256) void k_edge_stats(
    const int* __restrict__ ei, const float* __restrict__ ea,
    float* __restrict__ loop_attr, unsigned* __restrict__ cnt) {
  int e = blockIdx.x * 256 + threadIdx.x;
  if (e >= NE) return;
  int d = ei[NE + e];
  atomicAdd(&cnt[d], 1u);
  #pragma unroll
  for (int j = 0; j < 4; j++) atomicAdd(&loop_attr[d * 4 + j], ea[e * 4 + j]);
}

__global__ __launch_bounds__(256) void k_loop_finalize(
    float* __restrict__ loop_attr, const unsigned* __restrict__ cnt) {
  int i = blockIdx.x * 256 + threadIdx.x;
  if (i >= NN * 4) return;
  float c = (float)cnt[i >> 2];
  if (c < 1.f) c = 1.f;
  loop_attr[i] = loop_attr[i] / c;
}

// ------------------------------------------------------------------
// K3: encoder: h0 = relu(x@W1+b1)@W2+b2   (one node per thread)
__global__ __launch_bounds__(256) void k_encoder(
    const float* __restrict__ x, const float* __restrict__ w1, const float* __restrict__ b1,
    const float* __restrict__ w2, const float* __restrict__ b2, float* __restrict__ h0) {
  __shared__ float W1[NODE_IN * HID];
  __shared__ float W2[HID * HID];
  __shared__ float B1[HID];
  __shared__ float B2[HID];
  for (int i = threadIdx.x; i < NODE_IN * HID; i += 256) W1[i] = w1[i];
  for (int i = threadIdx.x; i < HID * HID; i += 256) W2[i] = w2[i];
  if (threadIdx.x < HID) { B1[threadIdx.x] = b1[threadIdx.x]; B2[threadIdx.x] = b2[threadIdx.x]; }
  __syncthreads();
  int n = blockIdx.x * 256 + threadIdx.x;
  if (n >= NN) return;
  float xi[NODE_IN];
  #pragma unroll
  for (int i = 0; i < NODE_IN; i++) xi[i] = x[n * NODE_IN + i];
  float hid[HID];
  for (int j = 0; j < HID; j++) {
    float s = B1[j];
    #pragma unroll
    for (int i = 0; i < NODE_IN; i++) s += xi[i] * W1[i * HID + j];
    hid[j] = fmaxf(s, 0.f);
  }
  for (int j = 0; j < HID; j++) {
    float s = B2[j];
    #pragma unroll 8
    for (int k = 0; k < HID; k++) s += hid[k] * W2[k * HID + j];
    h0[(size_t)n * HID + j] = s;
  }
}

// ------------------------------------------------------------------
// K_scan: exclusive scan of (cnt[i]+1) -> row_ptr, pos  (single block)
__global__ __launch_bounds__(256) void k_scan(
    const unsigned* __restrict__ cnt, int* __restrict__ row_ptr, int* __restrict__ pos) {
  __shared__ int lds[256];
  __shared__ int carry;
  int tid = threadIdx.x;
  if (tid == 0) carry = 0;
  __syncthreads();
  for (int base = 0; base < NN; base += 256) {
    int idx = base + tid;
    int v = (idx < NN) ? ((int)cnt[idx] + 1) : 0;
    lds[tid] = v;
    __syncthreads();
    for (int off = 1; off < 256; off <<= 1) {
      int t = (tid >= off) ? lds[tid - off] : 0;
      __syncthreads();
      lds[tid] += t;
      __syncthreads();
    }
    int excl = carry + lds[tid] - v;
    if (idx < NN) { row_ptr[idx] = excl; pos[idx] = excl; }
    __syncthreads();
    if (tid == 0) carry += lds[255];
    __syncthreads();
  }
  if (tid == 0) row_ptr[NN] = carry;   // == EP
}

__global__ __launch_bounds__(256) void k_csr_scatter(
    const int* __restrict__ ei, int* __restrict__ pos, int* __restrict__ eid) {
  int e = blockIdx.x * 256 + threadIdx.x;
  if (e >= EP) return;
  int d = (e < NE) ? ei[NE + e] : (e - NE);
  int p = atomicAdd(&pos[d], 1);
  eid[p] = e;
}

// ------------------------------------------------------------------
// K4: OUT[NN][256] = A[NN][K] @ W[K][256]  (32 nodes x 256 cols / block)
template <int K>
__global__ __launch_bounds__(256) void k_gemm256(
    const float* __restrict__ A, const float* __restrict__ W, float* __restrict__ OUT) {
  __shared__ float Wl[32 * 256];
  __shared__ float Al[32 * 36];
  const int tid = threadIdx.x;
  const int n0 = blockIdx.x * 32;
  const int tx = tid & 63, ty = tid >> 6;
  float acc[8][4];
  #pragma unroll
  for (int m = 0; m < 8; m++)
    #pragma unroll
    for (int c = 0; c < 4; c++) acc[m][c] = 0.f;

  for (int kt = 0; kt < K; kt += 32) {
    #pragma unroll
    for (int r = 0; r < 8; r++) {
      int i4 = tid + 256 * r;
      int row = i4 >> 6;
      int col4 = (i4 & 63) * 4;
      *(float4*)&Wl[row * 256 + col4] = *(const float4*)&W[(size_t)(kt + row) * 256 + col4];
    }
    {
      int m = tid >> 3, kk = (tid & 7) * 4;
      float4 av = *(const float4*)&A[(size_t)(n0 + m) * K + kt + kk];
      Al[(kk + 0) * 36 + m] = av.x;
      Al[(kk + 1) * 36 + m] = av.y;
      Al[(kk + 2) * 36 + m] = av.z;
      Al[(kk + 3) * 36 + m] = av.w;
    }
    __syncthreads();
    #pragma unroll 8
    for (int k = 0; k < 32; k++) {
      float4 b = *(float4*)&Wl[k * 256 + tx * 4];
      float4 a0v = *(float4*)&Al[k * 36 + ty * 8];
      float4 a1v = *(float4*)&Al[k * 36 + ty * 8 + 4];
      float am[8] = {a0v.x, a0v.y, a0v.z, a0v.w, a1v.x, a1v.y, a1v.z, a1v.w};
      #pragma unroll
      for (int m = 0; m < 8; m++) {
        acc[m][0] += am[m] * b.x;
        acc[m][1] += am[m] * b.y;
        acc[m][2] += am[m] * b.z;
        acc[m][3] += am[m] * b.w;
      }
    }
    __syncthreads();
  }
  #pragma unroll
  for (int m = 0; m < 8; m++) {
    float4 o = {acc[m][0], acc[m][1], acc[m][2], acc[m][3]};
    *(float4*)&OUT[(size_t)(n0 + ty * 8 + m) * 256 + tx * 4] = o;
  }
}

// ------------------------------------------------------------------
// K5: fused GATv2 per node: logits + online softmax + aggregate + epilogue.
// 1 wave / node, lane owns channels c = 4*lane..4*lane+3 (all in head lane>>4).
template <int CONCAT>
__global__ __launch_bounds__(256) void k_gat_fused(
    const float* __restrict__ xl, const float* __restrict__ xr,
    const float* __restrict__ we, const float* __restrict__ att,
    const int* __restrict__ ei, const float* __restrict__ ea,
    const float* __restrict__ loop_attr,
    const int* __restrict__ row_ptr, const int* __restrict__ eid,
    const float* __restrict__ bias, const float* __restrict__ bng,
    const float* __restrict__ bnb, float* __restrict__ outp) {
  __shared__ float slog[4][DEG_CAP * 4];     // per-wave cached head-logits
  const int lane = threadIdx.x & 63;
  const int w = threadIdx.x >> 6;
  const int i = blockIdx.x * 4 + w;
  const int c0 = lane * 4;
  const int hgrp = lane >> 4;                // head of this lane

  const float4 attv = *(const float4*)&att[c0];
  const float4 we0 = *(const float4*)&we[0 * HC + c0];
  const float4 we1 = *(const float4*)&we[1 * HC + c0];
  const float4 we2 = *(const float4*)&we[2 * HC + c0];
  const float4 we3 = *(const float4*)&we[3 * HC + c0];
  const float4 xrd = *(const float4*)&xr[(size_t)i * HC + c0];

  const int start = row_ptr[i];
  const int deg = row_ptr[i + 1] - start;

  float mx = -1e30f, dn = 0.f;               // per-lane == per-head online softmax

  // ---- pass 1: logits + online max/sum ----
  for (int jj = 0; jj < deg; ++jj) {
    int e = eid[start + jj];
    int s; const float* ap;
    if (e < NE) { s = ei[e]; ap = &ea[(size_t)e * 4]; }
    else        { s = e - NE; ap = &loop_attr[(size_t)(e - NE) * 4]; }
    float4 a = *(const float4*)ap;
    float4 xls = *(const float4*)&xl[(size_t)s * HC + c0];
    float m0 = xls.x + xrd.x + a.x * we0.x + a.y * we1.x + a.z * we2.x + a.w * we3.x;
    float m1 = xls.y + xrd.y + a.x * we0.y + a.y * we1.y + a.z * we2.y + a.w * we3.y;
    float m2 = xls.z + xrd.z + a.x * we0.z + a.y * we1.z + a.z * we2.z + a.w * we3.z;
    float m3 = xls.w + xrd.w + a.x * we0.w + a.y * we1.w + a.z * we2.w + a.w * we3.w;
    m0 = (m0 > 0.f) ? m0 : NEG_SLOPE * m0;
    m1 = (m1 > 0.f) ? m1 : NEG_SLOPE * m1;
    m2 = (m2 > 0.f) ? m2 : NEG_SLOPE * m2;
    m3 = (m3 > 0.f) ? m3 : NEG_SLOPE * m3;
    float lg = m0 * attv.x + m1 * attv.y + m2 * attv.z + m3 * attv.w;
    lg += __shfl_xor(lg, 1);
    lg += __shfl_xor(lg, 2);
    lg += __shfl_xor(lg, 4);
    lg += __shfl_xor(lg, 8);                 // head sum, broadcast within 16-lane group
    float nmx = fmaxf(mx, lg);
    dn = dn * __expf(mx - nmx) + __expf(lg - nmx);
    mx = nmx;
    if (jj < DEG_CAP && (lane & 15) == 0) slog[w][jj * 4 + hgrp] = lg;
  }
  const float rinv = 1.f / dn;

  // ---- pass 2: weighted aggregation ----
  float acc0 = 0.f, acc1 = 0.f, acc2 = 0.f, acc3 = 0.f;
  for (int jj = 0; jj < deg; ++jj) {
    int e = eid[start + jj];
    int s = (e < NE) ? ei[e] : (e - NE);
    float4 xls = *(const float4*)&xl[(size_t)s * HC + c0];
    float lg;
    if (jj < DEG_CAP) {
      lg = slog[w][jj * 4 + hgrp];
    } else {                                  // rare fallback: recompute
      const float* ap = (e < NE) ? &ea[(size_t)e * 4] : &loop_attr[(size_t)(e - NE) * 4];
      float4 a = *(const float4*)ap;
      float m0 = xls.x + xrd.x + a.x * we0.x + a.y * we1.x + a.z * we2.x + a.w * we3.x;
      float m1 = xls.y + xrd.y + a.x * we0.y + a.y * we1.y + a.z * we2.y + a.w * we3.y;
      float m2 = xls.z + xrd.z + a.x * we0.z + a.y * we1.z + a.z * we2.z + a.w * we3.z;
      float m3 = xls.w + xrd.w + a.x * we0.w + a.y * we1.w + a.z * we2.w + a.w * we3.w;
      m0 = (m0 > 0.f) ? m0 : NEG_SLOPE * m0;
      m1 = (m1 > 0.f) ? m1 : NEG_SLOPE * m1;
      m2 = (m2 > 0.f) ? m2 : NEG_SLOPE * m2;
      m3 = (m3 > 0.f) ? m3 : NEG_SLOPE * m3;
      lg = m0 * attv.x + m1 * attv.y + m2 * attv.z + m3 * attv.w;
      lg += __shfl_xor(lg, 1);
      lg += __shfl_xor(lg, 2);
      lg += __shfl_xor(lg, 4);
      lg += __shfl_xor(lg, 8);
    }
    float alpha = __expf(lg - mx) * rinv;
    acc0 += alpha * xls.x;
    acc1 += alpha * xls.y;
    acc2 += alpha * xls.z;
    acc3 += alpha * xls.w;
  }

  const float inv_sqrt = rsqrtf(1.f + BN_EPS);
  if (CONCAT) {
    float4 bi = *(const float4*)&bias[c0];
    float4 g = *(const float4*)&bng[c0];
    float4 bb = *(const float4*)&bnb[c0];
    float v0 = (acc0 + bi.x) * (g.x * inv_sqrt) + bb.x;
    float v1 = (acc1 + bi.y) * (g.y * inv_sqrt) + bb.y;
    float v2 = (acc2 + bi.z) * (g.z * inv_sqrt) + bb.z;
    float v3 = (acc3 + bi.w) * (g.w * inv_sqrt) + bb.w;
    v0 = (v0 > 0.f) ? v0 : (__expf(v0) - 1.f);
    v1 = (v1 > 0.f) ? v1 : (__expf(v1) - 1.f);
    v2 = (v2 > 0.f) ? v2 : (__expf(v2) - 1.f);
    v3 = (v3 > 0.f) ? v3 : (__expf(v3) - 1.f);
    float4 o = {v0, v1, v2, v3};
    *(float4*)&outp[(size_t)i * HC + c0] = o;
  } else {
    // mean over heads: sum lanes {l, l^16, l^32, l^48}
    acc0 += __shfl_xor(acc0, 16); acc0 += __shfl_xor(acc0, 32);
    acc1 += __shfl_xor(acc1, 16); acc1 += __shfl_xor(acc1, 32);
    acc2 += __shfl_xor(acc2, 16); acc2 += __shfl_xor(acc2, 32);
    acc3 += __shfl_xor(acc3, 16); acc3 += __shfl_xor(acc3, 32);
    if (lane < 16) {
      int cc = lane * 4;
      float4 bi = *(const float4*)&bias[cc];
      float4 g = *(const float4*)&bng[cc];
      float4 bb = *(const float4*)&bnb[cc];
      float v0 = (0.25f * acc0 + bi.x) * (g.x * inv_sqrt) + bb.x;
      float v1 = (0.25f * acc1 + bi.y) * (g.y * inv_sqrt) + bb.y;
      float v2 = (0.25f * acc2 + bi.z) * (g.z * inv_sqrt) + bb.z;
      float v3 = (0.25f * acc3 + bi.w) * (g.w * inv_sqrt) + bb.w;
      v0 = (v0 > 0.f) ? v0 : (__expf(v0) - 1.f);
      v1 = (v1 > 0.f) ? v1 : (__expf(v1) - 1.f);
      v2 = (v2 > 0.f) ? v2 : (__expf(v2) - 1.f);
      v3 = (v3 > 0.f) ? v3 : (__expf(v3) - 1.f);
      float4 o = {v0, v1, v2, v3};
      *(float4*)&outp[(size_t)i * 64 + cc] = o;
    }
  }
}

// ------------------------------------------------------------------
// K8: fused SAGE: h3 = relu(bn3(mean_agg@wl + bl + h2@wr))  (1 wave/node)
__global__ __launch_bounds__(256) void k_sage(
    const float* __restrict__ h2, const int* __restrict__ row_ptr,
    const int* __restrict__ eid, const int* __restrict__ ei,
    const unsigned* __restrict__ cnt,
    const float* __restrict__ wl, const float* __restrict__ bl,
    const float* __restrict__ wr, const float* __restrict__ bng,
    const float* __restrict__ bnb, float* __restrict__ h3) {
  __shared__ float agg_s[4][64];
  __shared__ float h2_s[4][64];
  int lane = threadIdx.x & 63;
  int w = threadIdx.x >> 6;
  int i = blockIdx.x * 4 + w;
  int start = row_ptr[i], end = row_ptr[i + 1];
  float a = 0.f;
  for (int j = start; j < end; ++j) {
    int e = eid[j];
    if (e < NE) a += h2[(size_t)ei[e] * 64 + lane];
  }
  float c = (float)cnt[i];
  if (c < 1.f) c = 1.f;
  agg_s[w][lane] = a / c;
  h2_s[w][lane] = h2[(size_t)i * 64 + lane];
  __syncthreads();
  float s = bl[lane];
  #pragma unroll 4
  for (int k = 0; k < 64; k++)
    s += agg_s[w][k] * wl[k * 64 + lane] + h2_s[w][k] * wr[k * 64 + lane];
  s = s * (bng[lane] * rsqrtf(1.f + BN_EPS)) + bnb[lane];
  s = fmaxf(s, 0.f);
  h3[(size_t)i * 64 + lane] = s;
}

// ------------------------------------------------------------------
// K9: pooling: per-graph sum / max / count
__global__ __launch_bounds__(256) void k_pool(
    const float* __restrict__ h3, const int* __restrict__ batch,
    float* __restrict__ psum, float* __restrict__ pmax, float* __restrict__ pcnt) {
  int j = threadIdx.x & 63, grp = threadIdx.x >> 6;
  int nbase = blockIdx.x * 256 + grp * 64;
  float s = 0.f, m = 0.f, cn = 0.f;
  int cur = -1;
  for (int t = 0; t < 64; t++) {
    int n = nbase + t;
    if (n >= NN) break;
    int g = batch[n];
    if (g != cur) {
      if (cur >= 0) {
        atomicAdd(&psum[cur * 64 + j], s);
        atomicMax((int*)&pmax[cur * 64 + j], __float_as_int(m));
        if (j == 0) atomicAdd(&pcnt[cur], cn);
      }
      cur = g; s = 0.f; m = 0.f; cn = 0.f;
    }
    float v = h3[(size_t)n * 64 + j];
    s += v; m = fmaxf(m, v); cn += 1.f;
  }
  if (cur >= 0) {
    atomicAdd(&psum[cur * 64 + j], s);
    atomicMax((int*)&pmax[cur * 64 + j], __float_as_int(m));
    if (j == 0) atomicAdd(&pcnt[cur], cn);
  }
}

// ------------------------------------------------------------------
// K10: graph head (block per graph, 64 threads)
__global__ void k_graph_head(
    const float* __restrict__ psum, const float* __restrict__ pmax,
    const float* __restrict__ pcnt,
    const float* __restrict__ w1, const float* __restrict__ b1,
    const float* __restrict__ w2, const float* __restrict__ b2,
    const float* __restrict__ w3, const float* __restrict__ b3,
    float* __restrict__ out) {
  __shared__ float hp[128];
  __shared__ float z1[64];
  __shared__ float z2[32];
  int g = blockIdx.x, j = threadIdx.x;
  float c = pcnt[g];
  if (c < 1.f) c = 1.f;
  hp[j] = psum[g * 64 + j] / c;
  hp[64 + j] = pmax[g * 64 + j];
  __syncthreads();
  float s = b1[j];
  #pragma unroll 8
  for (int k = 0; k < 128; k++) s += hp[k] * w1[k * 64 + j];
  z1[j] = fmaxf(s, 0.f);
  __syncthreads();
  if (j < 32) {
    float s2 = b2[j];
    #pragma unroll 8
    for (int k = 0; k < 64; k++) s2 += z1[k] * w2[k * 32 + j];
    z2[j] = fmaxf(s2, 0.f);
  }
  __syncthreads();
  if (j == 0) {
    float s3 = b3[0];
    #pragma unroll
    for (int k = 0; k < 32; k++) s3 += z2[k] * w3[k];
    out[g] = 1.f / (1.f + expf(-s3));
  }
}

// ------------------------------------------------------------------
// K11: edge head (thread per edge; weights read lane-uniform -> s_load)
__global__ __launch_bounds__(256) void k_edge_head(
    const float* __restrict__ h3, const int* __restrict__ ei,
    const float* __restrict__ ea,
    const float* __restrict__ w1, const float* __restrict__ b1,
    const float* __restrict__ w2, const float* __restrict__ b2,
    float* __restrict__ out) {
  int e = blockIdx.x * 256 + threadIdx.x;
  if (e >= NE) return;
  int s = ei[e], d = ei[NE + e];
  float acc[32];
  #pragma unroll
  for (int j = 0; j < 32; j++) acc[j] = b1[j];
  const float4* hs = (const float4*)&h3[(size_t)s * 64];
  const float4* hd = (const float4*)&h3[(size_t)d * 64];
  for (int k4 = 0; k4 < 16; k4++) {
    float4 v = hs[k4];
    const float* w = &w1[k4 * 4 * 32];
    #pragma unroll
    for (int j = 0; j < 32; j++) acc[j] += v.x * w[j];
    #pragma unroll
    for (int j = 0; j < 32; j++) acc[j] += v.y * w[32 + j];
    #pragma unroll
    for (int j = 0; j < 32; j++) acc[j] += v.z * w[64 + j];
    #pragma unroll
    for (int j = 0; j < 32; j++) acc[j] += v.w * w[96 + j];
  }
  for (int k4 = 0; k4 < 16; k4++) {
    float4 v = hd[k4];
    const float* w = &w1[(64 + k4 * 4) * 32];
    #pragma unroll
    for (int j = 0; j < 32; j++) acc[j] += v.x * w[j];
    #pragma unroll
    for (int j = 0; j < 32; j++) acc[j] += v.y * w[32 + j];
    #pragma unroll
    for (int j = 0; j < 32; j++) acc[j] += v.z * w[64 + j];
    #pragma unroll
    for (int j = 0; j < 32; j++) acc[j] += v.w * w[96 + j];
  }
  {
    float4 v = *(const float4*)&ea[(size_t)e * 4];
    const float* w = &w1[128 * 32];
    #pragma unroll
    for (int j = 0; j < 32; j++) acc[j] += v.x * w[j];
    #pragma unroll
    for (int j = 0; j < 32; j++) acc[j] += v.y * w[32 + j];
    #pragma unroll
    for (int j = 0; j < 32; j++) acc[j] += v.z * w[64 + j];
    #pragma unroll
    for (int j = 0; j < 32; j++) acc[j] += v.w * w[96 + j];
  }
  float s2 = b2[0];
  #pragma unroll
  for (int j = 0; j < 32; j++) s2 += fmaxf(acc[j], 0.f) * w2[j];
  out[e] = 1.f / (1.f + expf(-s2));
}

// ------------------------------------------------------------------
extern "C" void kernel_launch(void* const* d_in, const int* in_sizes, int n_in,
                              void* d_out, int out_size, void* d_ws, size_t ws_size,
                              hipStream_t stream) {
  const float* x         = (const float*)d_in[0];
  const float* edge_attr = (const float*)d_in[1];
  const float* enc_w1 = (const float*)d_in[2];
  const float* enc_b1 = (const float*)d_in[3];
  const float* enc_w2 = (const float*)d_in[4];
  const float* enc_b2 = (const float*)d_in[5];
  const float* g1_wl = (const float*)d_in[6];
  const float* g1_wr = (const float*)d_in[7];
  const float* g1_we = (const float*)d_in[8];
  const float* g1_att = (const float*)d_in[9];
  const float* g1_b = (const float*)d_in[10];
  const float* bn1_g = (const float*)d_in[11];
  const float* bn1_b = (const float*)d_in[12];
  const float* g2_wl = (const float*)d_in[13];
  const float* g2_wr = (const float*)d_in[14];
  const float* g2_we = (const float*)d_in[15];
  const float* g2_att = (const float*)d_in[16];
  const float* g2_b = (const float*)d_in[17];
  const float* bn2_g = (const float*)d_in[18];
  const float* bn2_b = (const float*)d_in[19];
  const float* sage_wl = (const float*)d_in[20];
  const float* sage_bl = (const float*)d_in[21];
  const float* sage_wr = (const float*)d_in[22];
  const float* bn3_g = (const float*)d_in[23];
  const float* bn3_b = (const float*)d_in[24];
  const float* gh_w1 = (const float*)d_in[25];
  const float* gh_b1 = (const float*)d_in[26];
  const float* gh_w2 = (const float*)d_in[27];
  const float* gh_b2 = (const float*)d_in[28];
  const float* gh_w3 = (const float*)d_in[29];
  const float* gh_b3 = (const float*)d_in[30];
  const float* eh_w1 = (const float*)d_in[31];
  const float* eh_b1 = (const float*)d_in[32];
  const float* eh_w2 = (const float*)d_in[33];
  const float* eh_b2 = (const float*)d_in[34];
  const int* ei    = (const int*)d_in[35];
  const int* batch = (const int*)d_in[36];
  float* out = (float*)d_out;

  float* ws = (float*)d_ws;
  float* xl = ws + OFF_XL;
  float* xr = ws + OFF_XR;
  float* h1 = ws + OFF_H1;
  float* h0 = ws + OFF_H0;   // later h2
  float* h3 = ws + OFF_H3;
  float* la = ws + OFF_LA;
  unsigned* cnt = (unsigned*)(ws + OFF_CNT);
  float* psum = ws + OFF_PSUM;
  float* pmax = ws + OFF_PMAX;
  float* pcnt = ws + OFF_PCNT;
  int* row_ptr = (int*)(ws + OFF_RP);
  int* pos = (int*)(ws + OFF_POS);
  int* eid = (int*)(ws + OFF_EID);

  hipMemsetAsync(ws + OFF_ZERO, 0, ZERO_FLOATS * sizeof(float), stream);

  k_edge_stats<<<NE / 256, 256, 0, stream>>>(ei, edge_attr, la, cnt);
  k_loop_finalize<<<(NN * 4 + 255) / 256, 256, 0, stream>>>(la, cnt);
  k_encoder<<<(NN + 255) / 256, 256, 0, stream>>>(x, enc_w1, enc_b1, enc_w2, enc_b2, h0);
  k_scan<<<1, 256, 0, stream>>>(cnt, row_ptr, pos);
  k_csr_scatter<<<(EP + 255) / 256, 256, 0, stream>>>(ei, pos, eid);

  // ---- GAT layer 1 ----
  k_gemm256<64><<<NN / 32, 256, 0, stream>>>(h0, g1_wl, xl);
  k_gemm256<64><<<NN / 32, 256, 0, stream>>>(h0, g1_wr, xr);
  k_gat_fused<1><<<NN / 4, 256, 0, stream>>>(xl, xr, g1_we, g1_att, ei, edge_attr, la,
                                             row_ptr, eid, g1_b, bn1_g, bn1_b, h1);

  // ---- GAT layer 2 ----
  k_gemm256<256><<<NN / 32, 256, 0, stream>>>(h1, g2_wl, xl);
  k_gemm256<256><<<NN / 32, 256, 0, stream>>>(h1, g2_wr, xr);
  k_gat_fused<0><<<NN / 4, 256, 0, stream>>>(xl, xr, g2_we, g2_att, ei, edge_attr, la,
                                             row_ptr, eid, g2_b, bn2_g, bn2_b, h0);

  // ---- SAGE ----
  k_sage<<<NN / 4, 256, 0, stream>>>(h0, row_ptr, eid, ei, cnt, sage_wl, sage_bl, sage_wr, bn3_g, bn3_b, h3);

  // ---- pooling + heads ----
  k_pool<<<(NN + 255) / 256, 256, 0, stream>>>(h3, batch, psum, pmax, pcnt);
  k_graph_head<<<NG, 64, 0, stream>>>(psum, pmax, pcnt, gh_w1, gh_b1, gh_w2, gh_b2, gh_w3, gh_b3, out);
  k_edge_head<<<NE / 256, 256, 0, stream>>>(h3, ei, edge_attr, eh_w1, eh_b1, eh_w2, eh_b2, out + NG);
}

// Round 3
// 705.058 us; speedup vs baseline: 1.4658x; 1.3975x over previous
//
#include <hip/hip_runtime.h>

#define NN 20000
#define NE 320000
#define EP (NE + NN)          // 340000 edges incl. self loops
#define NG 8
#define HC 256
#define NODE_IN 18
#define HID 64
#define NEG_SLOPE 0.2f
#define BN_EPS 1e-5f

// ---------------- workspace layout (float offsets) ----------------
#define OFF_XL    0u                      // [NN*256]
#define OFF_XR    5120000u                // [NN*256]
#define OFF_H1    10240000u               // [NN*256]
#define OFF_H0    15360000u               // [NN*64]  (h0, later reused as h2)
#define OFF_H3    16640000u               // [NN*64]
#define OFF_ZERO  17920000u               // start of zeroed region
#define OFF_LA    17920000u               // loop_attr [NN*4]
#define OFF_CNT   18000000u               // uint cnt [NN]
#define OFF_PSUM  18020000u               // [8*64]
#define OFF_PMAX  18020512u               // [8*64]
#define OFF_PCNT  18021024u               // [16]
#define ZERO_FLOATS (18021040u - 17920000u)
#define OFF_EACSR 18021040u               // float4-aligned: [EP*4] CSR-ordered edge attrs
#define OFF_RP    19381040u               // int [NN+1]
#define OFF_POS   19401041u               // int [NN]
#define OFF_SRC   19421041u               // int [EP]  (sign bit = self-loop flag)

// ------------------------------------------------------------------
// K1: per-dst edge count + sum of edge_attr (for self-loop fill 'mean')
__global__ __launch_bounds__(256) void k_edge_stats(
    const int* __restrict__ ei, const float* __restrict__ ea,
    float* __restrict__ loop_attr, unsigned* __restrict__ cnt) {
  int e = blockIdx.x * 256 + threadIdx.x;
  if (e >= NE) return;
  int d = ei[NE + e];
  atomicAdd(&cnt[d], 1u);
  #pragma unroll
  for (int j = 0; j < 4; j++) atomicAdd(&loop_attr[d * 4 + j], ea[e * 4 + j]);
}

__global__ __launch_bounds__(256) void k_loop_finalize(
    float* __restrict__ loop_attr, const unsigned* __restrict__ cnt) {
  int i = blockIdx.x * 256 + threadIdx.x;
  if (i >= NN * 4) return;
  float c = (float)cnt[i >> 2];
  if (c < 1.f) c = 1.f;
  loop_attr[i] = loop_attr[i] / c;
}

// ------------------------------------------------------------------
// K3: encoder: h0 = relu(x@W1+b1)@W2+b2   (one node per thread)
__global__ __launch_bounds__(256) void k_encoder(
    const float* __restrict__ x, const float* __restrict__ w1, const float* __restrict__ b1,
    const float* __restrict__ w2, const float* __restrict__ b2, float* __restrict__ h0) {
  __shared__ float W1[NODE_IN * HID];
  __shared__ float W2[HID * HID];
  __shared__ float B1[HID];
  __shared__ float B2[HID];
  for (int i = threadIdx.x; i < NODE_IN * HID; i += 256) W1[i] = w1[i];
  for (int i = threadIdx.x; i < HID * HID; i += 256) W2[i] = w2[i];
  if (threadIdx.x < HID) { B1[threadIdx.x] = b1[threadIdx.x]; B2[threadIdx.x] = b2[threadIdx.x]; }
  __syncthreads();
  int n = blockIdx.x * 256 + threadIdx.x;
  if (n >= NN) return;
  float xi[NODE_IN];
  #pragma unroll
  for (int i = 0; i < NODE_IN; i++) xi[i] = x[n * NODE_IN + i];
  float hid[HID];
  for (int j = 0; j < HID; j++) {
    float s = B1[j];
    #pragma unroll
    for (int i = 0; i < NODE_IN; i++) s += xi[i] * W1[i * HID + j];
    hid[j] = fmaxf(s, 0.f);
  }
  for (int j = 0; j < HID; j++) {
    float s = B2[j];
    #pragma unroll 8
    for (int k = 0; k < HID; k++) s += hid[k] * W2[k * HID + j];
    h0[(size_t)n * HID + j] = s;
  }
}

// ------------------------------------------------------------------
// K_scan: exclusive scan of (cnt[i]+1) -> row_ptr, pos  (single block)
__global__ __launch_bounds__(256) void k_scan(
    const unsigned* __restrict__ cnt, int* __restrict__ row_ptr, int* __restrict__ pos) {
  __shared__ int lds[256];
  __shared__ int carry;
  int tid = threadIdx.x;
  if (tid == 0) carry = 0;
  __syncthreads();
  for (int base = 0; base < NN; base += 256) {
    int idx = base + tid;
    int v = (idx < NN) ? ((int)cnt[idx] + 1) : 0;
    lds[tid] = v;
    __syncthreads();
    for (int off = 1; off < 256; off <<= 1) {
      int t = (tid >= off) ? lds[tid - off] : 0;
      __syncthreads();
      lds[tid] += t;
      __syncthreads();
    }
    int excl = carry + lds[tid] - v;
    if (idx < NN) { row_ptr[idx] = excl; pos[idx] = excl; }
    __syncthreads();
    if (tid == 0) carry += lds[255];
    __syncthreads();
  }
  if (tid == 0) row_ptr[NN] = carry;   // == EP
}

// K_scatter: CSR slot -> src id (sign bit = self loop) + CSR-ordered edge attrs
__global__ __launch_bounds__(256) void k_csr_scatter(
    const int* __restrict__ ei, int* __restrict__ pos,
    const float* __restrict__ ea, const float* __restrict__ loop_attr,
    int* __restrict__ srcs, float* __restrict__ ea_csr) {
  int e = blockIdx.x * 256 + threadIdx.x;
  if (e >= EP) return;
  int d, s, flag;
  float4 av;
  if (e < NE) {
    s = ei[e]; d = ei[NE + e]; flag = 0;
    av = *(const float4*)&ea[(size_t)e * 4];
  } else {
    s = e - NE; d = s; flag = (int)0x80000000;
    av = *(const float4*)&loop_attr[(size_t)(e - NE) * 4];
  }
  int p = atomicAdd(&pos[d], 1);
  srcs[p] = s | flag;
  *(float4*)&ea_csr[(size_t)p * 4] = av;
}

// ------------------------------------------------------------------
// K4: OUT[NN][256] = A[NN][K] @ W[K][256]  (32 nodes x 256 cols / block)
template <int K>
__global__ __launch_bounds__(256) void k_gemm256(
    const float* __restrict__ A, const float* __restrict__ W, float* __restrict__ OUT) {
  __shared__ float Wl[32 * 256];
  __shared__ float Al[32 * 36];
  const int tid = threadIdx.x;
  const int n0 = blockIdx.x * 32;
  const int tx = tid & 63, ty = tid >> 6;
  float acc[8][4];
  #pragma unroll
  for (int m = 0; m < 8; m++)
    #pragma unroll
    for (int c = 0; c < 4; c++) acc[m][c] = 0.f;

  for (int kt = 0; kt < K; kt += 32) {
    #pragma unroll
    for (int r = 0; r < 8; r++) {
      int i4 = tid + 256 * r;
      int row = i4 >> 6;
      int col4 = (i4 & 63) * 4;
      *(float4*)&Wl[row * 256 + col4] = *(const float4*)&W[(size_t)(kt + row) * 256 + col4];
    }
    {
      int m = tid >> 3, kk = (tid & 7) * 4;
      float4 av = *(const float4*)&A[(size_t)(n0 + m) * K + kt + kk];
      Al[(kk + 0) * 36 + m] = av.x;
      Al[(kk + 1) * 36 + m] = av.y;
      Al[(kk + 2) * 36 + m] = av.z;
      Al[(kk + 3) * 36 + m] = av.w;
    }
    __syncthreads();
    #pragma unroll 8
    for (int k = 0; k < 32; k++) {
      float4 b = *(float4*)&Wl[k * 256 + tx * 4];
      float4 a0v = *(float4*)&Al[k * 36 + ty * 8];
      float4 a1v = *(float4*)&Al[k * 36 + ty * 8 + 4];
      float am[8] = {a0v.x, a0v.y, a0v.z, a0v.w, a1v.x, a1v.y, a1v.z, a1v.w};
      #pragma unroll
      for (int m = 0; m < 8; m++) {
        acc[m][0] += am[m] * b.x;
        acc[m][1] += am[m] * b.y;
        acc[m][2] += am[m] * b.z;
        acc[m][3] += am[m] * b.w;
      }
    }
    __syncthreads();
  }
  #pragma unroll
  for (int m = 0; m < 8; m++) {
    float4 o = {acc[m][0], acc[m][1], acc[m][2], acc[m][3]};
    *(float4*)&OUT[(size_t)(n0 + ty * 8 + m) * 256 + tx * 4] = o;
  }
}

// ------------------------------------------------------------------
// K5: fused GATv2, ONE pass: logits + online softmax + aggregation + epilogue.
// 1 wave / node, lane owns channels c = 4*lane..4*lane+3 (head = lane>>4).
// Dual independent online accumulators (A/B) for 2 gathers in flight.
template <int CONCAT>
__global__ __launch_bounds__(256) void k_gat_fused(
    const float* __restrict__ xl, const float* __restrict__ xr,
    const float* __restrict__ we, const float* __restrict__ att,
    const int* __restrict__ srcs, const float* __restrict__ ea_csr,
    const int* __restrict__ row_ptr,
    const float* __restrict__ bias, const float* __restrict__ bng,
    const float* __restrict__ bnb, float* __restrict__ outp) {
  const int lane = threadIdx.x & 63;
  const int w = threadIdx.x >> 6;
  const int i = blockIdx.x * 4 + w;
  const int c0 = lane * 4;

  const float4 attv = *(const float4*)&att[c0];
  const float4 we0 = *(const float4*)&we[0 * HC + c0];
  const float4 we1 = *(const float4*)&we[1 * HC + c0];
  const float4 we2 = *(const float4*)&we[2 * HC + c0];
  const float4 we3 = *(const float4*)&we[3 * HC + c0];
  const float4 xrd = *(const float4*)&xr[(size_t)i * HC + c0];

  const int start = row_ptr[i];
  const int deg = row_ptr[i + 1] - start;

  float mxA = -1e30f, dnA = 0.f, aA0 = 0.f, aA1 = 0.f, aA2 = 0.f, aA3 = 0.f;
  float mxB = -1e30f, dnB = 0.f, aB0 = 0.f, aB1 = 0.f, aB2 = 0.f, aB3 = 0.f;

  for (int base = 0; base < deg; base += 64) {
    int rem = deg - base;
    if (rem > 64) rem = 64;
    int sv = 0;
    if (lane < rem) sv = srcs[start + base + lane];
    int jj = 0;
    for (; jj + 2 <= rem; jj += 2) {
      int s0 = __shfl(sv, jj) & 0x7fffffff;
      int s1 = __shfl(sv, jj + 1) & 0x7fffffff;
      float4 a0 = *(const float4*)&ea_csr[(size_t)(start + base + jj) * 4];
      float4 a1 = *(const float4*)&ea_csr[(size_t)(start + base + jj + 1) * 4];
      float4 x0 = *(const float4*)&xl[(size_t)s0 * HC + c0];
      float4 x1 = *(const float4*)&xl[(size_t)s1 * HC + c0];
      // ---- edge 0 -> stream A ----
      {
        float m0 = x0.x + xrd.x + a0.x * we0.x + a0.y * we1.x + a0.z * we2.x + a0.w * we3.x;
        float m1 = x0.y + xrd.y + a0.x * we0.y + a0.y * we1.y + a0.z * we2.y + a0.w * we3.y;
        float m2 = x0.z + xrd.z + a0.x * we0.z + a0.y * we1.z + a0.z * we2.z + a0.w * we3.z;
        float m3 = x0.w + xrd.w + a0.x * we0.w + a0.y * we1.w + a0.z * we2.w + a0.w * we3.w;
        m0 = (m0 > 0.f) ? m0 : NEG_SLOPE * m0;
        m1 = (m1 > 0.f) ? m1 : NEG_SLOPE * m1;
        m2 = (m2 > 0.f) ? m2 : NEG_SLOPE * m2;
        m3 = (m3 > 0.f) ? m3 : NEG_SLOPE * m3;
        float lg = m0 * attv.x + m1 * attv.y + m2 * attv.z + m3 * attv.w;
        lg += __shfl_xor(lg, 1);
        lg += __shfl_xor(lg, 2);
        lg += __shfl_xor(lg, 4);
        lg += __shfl_xor(lg, 8);
        float nmx = fmaxf(mxA, lg);
        float sc = __expf(mxA - nmx);
        float p = __expf(lg - nmx);
        dnA = dnA * sc + p;
        aA0 = fmaf(aA0, sc, p * x0.x);
        aA1 = fmaf(aA1, sc, p * x0.y);
        aA2 = fmaf(aA2, sc, p * x0.z);
        aA3 = fmaf(aA3, sc, p * x0.w);
        mxA = nmx;
      }
      // ---- edge 1 -> stream B ----
      {
        float m0 = x1.x + xrd.x + a1.x * we0.x + a1.y * we1.x + a1.z * we2.x + a1.w * we3.x;
        float m1 = x1.y + xrd.y + a1.x * we0.y + a1.y * we1.y + a1.z * we2.y + a1.w * we3.y;
        float m2 = x1.z + xrd.z + a1.x * we0.z + a1.y * we1.z + a1.z * we2.z + a1.w * we3.z;
        float m3 = x1.w + xrd.w + a1.x * we0.w + a1.y * we1.w + a1.z * we2.w + a1.w * we3.w;
        m0 = (m0 > 0.f) ? m0 : NEG_SLOPE * m0;
        m1 = (m1 > 0.f) ? m1 : NEG_SLOPE * m1;
        m2 = (m2 > 0.f) ? m2 : NEG_SLOPE * m2;
        m3 = (m3 > 0.f) ? m3 : NEG_SLOPE * m3;
        float lg = m0 * attv.x + m1 * attv.y + m2 * attv.z + m3 * attv.w;
        lg += __shfl_xor(lg, 1);
        lg += __shfl_xor(lg, 2);
        lg += __shfl_xor(lg, 4);
        lg += __shfl_xor(lg, 8);
        float nmx = fmaxf(mxB, lg);
        float sc = __expf(mxB - nmx);
        float p = __expf(lg - nmx);
        dnB = dnB * sc + p;
        aB0 = fmaf(aB0, sc, p * x1.x);
        aB1 = fmaf(aB1, sc, p * x1.y);
        aB2 = fmaf(aB2, sc, p * x1.z);
        aB3 = fmaf(aB3, sc, p * x1.w);
        mxB = nmx;
      }
    }
    if (jj < rem) {   // tail edge -> stream A
      int s0 = __shfl(sv, jj) & 0x7fffffff;
      float4 a0 = *(const float4*)&ea_csr[(size_t)(start + base + jj) * 4];
      float4 x0 = *(const float4*)&xl[(size_t)s0 * HC + c0];
      float m0 = x0.x + xrd.x + a0.x * we0.x + a0.y * we1.x + a0.z * we2.x + a0.w * we3.x;
      float m1 = x0.y + xrd.y + a0.x * we0.y + a0.y * we1.y + a0.z * we2.y + a0.w * we3.y;
      float m2 = x0.z + xrd.z + a0.x * we0.z + a0.y * we1.z + a0.z * we2.z + a0.w * we3.z;
      float m3 = x0.w + xrd.w + a0.x * we0.w + a0.y * we1.w + a0.z * we2.w + a0.w * we3.w;
      m0 = (m0 > 0.f) ? m0 : NEG_SLOPE * m0;
      m1 = (m1 > 0.f) ? m1 : NEG_SLOPE * m1;
      m2 = (m2 > 0.f) ? m2 : NEG_SLOPE * m2;
      m3 = (m3 > 0.f) ? m3 : NEG_SLOPE * m3;
      float lg = m0 * attv.x + m1 * attv.y + m2 * attv.z + m3 * attv.w;
      lg += __shfl_xor(lg, 1);
      lg += __shfl_xor(lg, 2);
      lg += __shfl_xor(lg, 4);
      lg += __shfl_xor(lg, 8);
      float nmx = fmaxf(mxA, lg);
      float sc = __expf(mxA - nmx);
      float p = __expf(lg - nmx);
      dnA = dnA * sc + p;
      aA0 = fmaf(aA0, sc, p * x0.x);
      aA1 = fmaf(aA1, sc, p * x0.y);
      aA2 = fmaf(aA2, sc, p * x0.z);
      aA3 = fmaf(aA3, sc, p * x0.w);
      mxA = nmx;
    }
  }

  // merge streams
  float m = fmaxf(mxA, mxB);
  float sA = __expf(mxA - m), sB = __expf(mxB - m);
  float dn = dnA * sA + dnB * sB;
  float rinv = 1.f / dn;
  float acc0 = (aA0 * sA + aB0 * sB) * rinv;
  float acc1 = (aA1 * sA + aB1 * sB) * rinv;
  float acc2 = (aA2 * sA + aB2 * sB) * rinv;
  float acc3 = (aA3 * sA + aB3 * sB) * rinv;

  const float inv_sqrt = rsqrtf(1.f + BN_EPS);
  if (CONCAT) {
    float4 bi = *(const float4*)&bias[c0];
    float4 g = *(const float4*)&bng[c0];
    float4 bb = *(const float4*)&bnb[c0];
    float v0 = (acc0 + bi.x) * (g.x * inv_sqrt) + bb.x;
    float v1 = (acc1 + bi.y) * (g.y * inv_sqrt) + bb.y;
    float v2 = (acc2 + bi.z) * (g.z * inv_sqrt) + bb.z;
    float v3 = (acc3 + bi.w) * (g.w * inv_sqrt) + bb.w;
    v0 = (v0 > 0.f) ? v0 : (__expf(v0) - 1.f);
    v1 = (v1 > 0.f) ? v1 : (__expf(v1) - 1.f);
    v2 = (v2 > 0.f) ? v2 : (__expf(v2) - 1.f);
    v3 = (v3 > 0.f) ? v3 : (__expf(v3) - 1.f);
    float4 o = {v0, v1, v2, v3};
    *(float4*)&outp[(size_t)i * HC + c0] = o;
  } else {
    // mean over heads: sum lanes {l, l^16, l^32, l^48} (acc already normalized)
    acc0 += __shfl_xor(acc0, 16); acc0 += __shfl_xor(acc0, 32);
    acc1 += __shfl_xor(acc1, 16); acc1 += __shfl_xor(acc1, 32);
    acc2 += __shfl_xor(acc2, 16); acc2 += __shfl_xor(acc2, 32);
    acc3 += __shfl_xor(acc3, 16); acc3 += __shfl_xor(acc3, 32);
    if (lane < 16) {
      int cc = lane * 4;
      float4 bi = *(const float4*)&bias[cc];
      float4 g = *(const float4*)&bng[cc];
      float4 bb = *(const float4*)&bnb[cc];
      float v0 = (0.25f * acc0 + bi.x) * (g.x * inv_sqrt) + bb.x;
      float v1 = (0.25f * acc1 + bi.y) * (g.y * inv_sqrt) + bb.y;
      float v2 = (0.25f * acc2 + bi.z) * (g.z * inv_sqrt) + bb.z;
      float v3 = (0.25f * acc3 + bi.w) * (g.w * inv_sqrt) + bb.w;
      v0 = (v0 > 0.f) ? v0 : (__expf(v0) - 1.f);
      v1 = (v1 > 0.f) ? v1 : (__expf(v1) - 1.f);
      v2 = (v2 > 0.f) ? v2 : (__expf(v2) - 1.f);
      v3 = (v3 > 0.f) ? v3 : (__expf(v3) - 1.f);
      float4 o = {v0, v1, v2, v3};
      *(float4*)&outp[(size_t)i * 64 + cc] = o;
    }
  }
}

// ------------------------------------------------------------------
// K8: fused SAGE: h3 = relu(bn3(mean_agg@wl + bl + h2@wr))  (1 wave/node)
__global__ __launch_bounds__(256) void k_sage(
    const float* __restrict__ h2, const int* __restrict__ row_ptr,
    const int* __restrict__ srcs, const unsigned* __restrict__ cnt,
    const float* __restrict__ wl, const float* __restrict__ bl,
    const float* __restrict__ wr, const float* __restrict__ bng,
    const float* __restrict__ bnb, float* __restrict__ h3) {
  __shared__ float agg_s[4][64];
  __shared__ float h2_s[4][64];
  int lane = threadIdx.x & 63;
  int w = threadIdx.x >> 6;
  int i = blockIdx.x * 4 + w;
  int start = row_ptr[i], end = row_ptr[i + 1];
  float a = 0.f;
  for (int j = start; j < end; ++j) {
    int sv = srcs[j];
    if (sv >= 0) a += h2[(size_t)sv * 64 + lane];   // skip self-loop slots
  }
  float c = (float)cnt[i];
  if (c < 1.f) c = 1.f;
  agg_s[w][lane] = a / c;
  h2_s[w][lane] = h2[(size_t)i * 64 + lane];
  __syncthreads();
  float s = bl[lane];
  #pragma unroll 4
  for (int k = 0; k < 64; k++)
    s += agg_s[w][k] * wl[k * 64 + lane] + h2_s[w][k] * wr[k * 64 + lane];
  s = s * (bng[lane] * rsqrtf(1.f + BN_EPS)) + bnb[lane];
  s = fmaxf(s, 0.f);
  h3[(size_t)i * 64 + lane] = s;
}

// ------------------------------------------------------------------
// K9: pooling: per-graph sum / max / count
__global__ __launch_bounds__(256) void k_pool(
    const float* __restrict__ h3, const int* __restrict__ batch,
    float* __restrict__ psum, float* __restrict__ pmax, float* __restrict__ pcnt) {
  int j = threadIdx.x & 63, grp = threadIdx.x >> 6;
  int nbase = blockIdx.x * 256 + grp * 64;
  float s = 0.f, m = 0.f, cn = 0.f;
  int cur = -1;
  for (int t = 0; t < 64; t++) {
    int n = nbase + t;
    if (n >= NN) break;
    int g = batch[n];
    if (g != cur) {
      if (cur >= 0) {
        atomicAdd(&psum[cur * 64 + j], s);
        atomicMax((int*)&pmax[cur * 64 + j], __float_as_int(m));
        if (j == 0) atomicAdd(&pcnt[cur], cn);
      }
      cur = g; s = 0.f; m = 0.f; cn = 0.f;
    }
    float v = h3[(size_t)n * 64 + j];
    s += v; m = fmaxf(m, v); cn += 1.f;
  }
  if (cur >= 0) {
    atomicAdd(&psum[cur * 64 + j], s);
    atomicMax((int*)&pmax[cur * 64 + j], __float_as_int(m));
    if (j == 0) atomicAdd(&pcnt[cur], cn);
  }
}

// ------------------------------------------------------------------
// K10: graph head (block per graph, 64 threads)
__global__ void k_graph_head(
    const float* __restrict__ psum, const float* __restrict__ pmax,
    const float* __restrict__ pcnt,
    const float* __restrict__ w1, const float* __restrict__ b1,
    const float* __restrict__ w2, const float* __restrict__ b2,
    const float* __restrict__ w3, const float* __restrict__ b3,
    float* __restrict__ out) {
  __shared__ float hp[128];
  __shared__ float z1[64];
  __shared__ float z2[32];
  int g = blockIdx.x, j = threadIdx.x;
  float c = pcnt[g];
  if (c < 1.f) c = 1.f;
  hp[j] = psum[g * 64 + j] / c;
  hp[64 + j] = pmax[g * 64 + j];
  __syncthreads();
  float s = b1[j];
  #pragma unroll 8
  for (int k = 0; k < 128; k++) s += hp[k] * w1[k * 64 + j];
  z1[j] = fmaxf(s, 0.f);
  __syncthreads();
  if (j < 32) {
    float s2 = b2[j];
    #pragma unroll 8
    for (int k = 0; k < 64; k++) s2 += z1[k] * w2[k * 32 + j];
    z2[j] = fmaxf(s2, 0.f);
  }
  __syncthreads();
  if (j == 0) {
    float s3 = b3[0];
    #pragma unroll
    for (int k = 0; k < 32; k++) s3 += z2[k] * w3[k];
    out[g] = 1.f / (1.f + expf(-s3));
  }
}

// ------------------------------------------------------------------
// K11: edge head (thread per edge; weights read lane-uniform -> s_load)
__global__ __launch_bounds__(256) void k_edge_head(
    const float* __restrict__ h3, const int* __restrict__ ei,
    const float* __restrict__ ea,
    const float* __restrict__ w1, const float* __restrict__ b1,
    const float* __restrict__ w2, const float* __restrict__ b2,
    float* __restrict__ out) {
  int e = blockIdx.x * 256 + threadIdx.x;
  if (e >= NE) return;
  int s = ei[e], d = ei[NE + e];
  float acc[32];
  #pragma unroll
  for (int j = 0; j < 32; j++) acc[j] = b1[j];
  const float4* hs = (const float4*)&h3[(size_t)s * 64];
  const float4* hd = (const float4*)&h3[(size_t)d * 64];
  for (int k4 = 0; k4 < 16; k4++) {
    float4 v = hs[k4];
    const float* w = &w1[k4 * 4 * 32];
    #pragma unroll
    for (int j = 0; j < 32; j++) acc[j] += v.x * w[j];
    #pragma unroll
    for (int j = 0; j < 32; j++) acc[j] += v.y * w[32 + j];
    #pragma unroll
    for (int j = 0; j < 32; j++) acc[j] += v.z * w[64 + j];
    #pragma unroll
    for (int j = 0; j < 32; j++) acc[j] += v.w * w[96 + j];
  }
  for (int k4 = 0; k4 < 16; k4++) {
    float4 v = hd[k4];
    const float* w = &w1[(64 + k4 * 4) * 32];
    #pragma unroll
    for (int j = 0; j < 32; j++) acc[j] += v.x * w[j];
    #pragma unroll
    for (int j = 0; j < 32; j++) acc[j] += v.y * w[32 + j];
    #pragma unroll
    for (int j = 0; j < 32; j++) acc[j] += v.z * w[64 + j];
    #pragma unroll
    for (int j = 0; j < 32; j++) acc[j] += v.w * w[96 + j];
  }
  {
    float4 v = *(const float4*)&ea[(size_t)e * 4];
    const float* w = &w1[128 * 32];
    #pragma unroll
    for (int j = 0; j < 32; j++) acc[j] += v.x * w[j];
    #pragma unroll
    for (int j = 0; j < 32; j++) acc[j] += v.y * w[32 + j];
    #pragma unroll
    for (int j = 0; j < 32; j++) acc[j] += v.z * w[64 + j];
    #pragma unroll
    for (int j = 0; j < 32; j++) acc[j] += v.w * w[96 + j];
  }
  float s2 = b2[0];
  #pragma unroll
  for (int j = 0; j < 32; j++) s2 += fmaxf(acc[j], 0.f) * w2[j];
  out[e] = 1.f / (1.f + expf(-s2));
}

// ------------------------------------------------------------------
extern "C" void kernel_launch(void* const* d_in, const int* in_sizes, int n_in,
                              void* d_out, int out_size, void* d_ws, size_t ws_size,
                              hipStream_t stream) {
  const float* x         = (const float*)d_in[0];
  const float* edge_attr = (const float*)d_in[1];
  const float* enc_w1 = (const float*)d_in[2];
  const float* enc_b1 = (const float*)d_in[3];
  const float* enc_w2 = (const float*)d_in[4];
  const float* enc_b2 = (const float*)d_in[5];
  const float* g1_wl = (const float*)d_in[6];
  const float* g1_wr = (const float*)d_in[7];
  const float* g1_we = (const float*)d_in[8];
  const float* g1_att = (const float*)d_in[9];
  const float* g1_b = (const float*)d_in[10];
  const float* bn1_g = (const float*)d_in[11];
  const float* bn1_b = (const float*)d_in[12];
  const float* g2_wl = (const float*)d_in[13];
  const float* g2_wr = (const float*)d_in[14];
  const float* g2_we = (const float*)d_in[15];
  const float* g2_att = (const float*)d_in[16];
  const float* g2_b = (const float*)d_in[17];
  const float* bn2_g = (const float*)d_in[18];
  const float* bn2_b = (const float*)d_in[19];
  const float* sage_wl = (const float*)d_in[20];
  const float* sage_bl = (const float*)d_in[21];
  const float* sage_wr = (const float*)d_in[22];
  const float* bn3_g = (const float*)d_in[23];
  const float* bn3_b = (const float*)d_in[24];
  const float* gh_w1 = (const float*)d_in[25];
  const float* gh_b1 = (const float*)d_in[26];
  const float* gh_w2 = (const float*)d_in[27];
  const float* gh_b2 = (const float*)d_in[28];
  const float* gh_w3 = (const float*)d_in[29];
  const float* gh_b3 = (const float*)d_in[30];
  const float* eh_w1 = (const float*)d_in[31];
  const float* eh_b1 = (const float*)d_in[32];
  const float* eh_w2 = (const float*)d_in[33];
  const float* eh_b2 = (const float*)d_in[34];
  const int* ei    = (const int*)d_in[35];
  const int* batch = (const int*)d_in[36];
  float* out = (float*)d_out;

  float* ws = (float*)d_ws;
  float* xl = ws + OFF_XL;
  float* xr = ws + OFF_XR;
  float* h1 = ws + OFF_H1;
  float* h0 = ws + OFF_H0;   // later h2
  float* h3 = ws + OFF_H3;
  float* la = ws + OFF_LA;
  unsigned* cnt = (unsigned*)(ws + OFF_CNT);
  float* psum = ws + OFF_PSUM;
  float* pmax = ws + OFF_PMAX;
  float* pcnt = ws + OFF_PCNT;
  float* ea_csr = ws + OFF_EACSR;
  int* row_ptr = (int*)(ws + OFF_RP);
  int* pos = (int*)(ws + OFF_POS);
  int* srcs = (int*)(ws + OFF_SRC);

  hipMemsetAsync(ws + OFF_ZERO, 0, ZERO_FLOATS * sizeof(float), stream);

  k_edge_stats<<<NE / 256, 256, 0, stream>>>(ei, edge_attr, la, cnt);
  k_loop_finalize<<<(NN * 4 + 255) / 256, 256, 0, stream>>>(la, cnt);
  k_encoder<<<(NN + 255) / 256, 256, 0, stream>>>(x, enc_w1, enc_b1, enc_w2, enc_b2, h0);
  k_scan<<<1, 256, 0, stream>>>(cnt, row_ptr, pos);
  k_csr_scatter<<<(EP + 255) / 256, 256, 0, stream>>>(ei, pos, edge_attr, la, srcs, ea_csr);

  // ---- GAT layer 1 ----
  k_gemm256<64><<<NN / 32, 256, 0, stream>>>(h0, g1_wl, xl);
  k_gemm256<64><<<NN / 32, 256, 0, stream>>>(h0, g1_wr, xr);
  k_gat_fused<1><<<NN / 4, 256, 0, stream>>>(xl, xr, g1_we, g1_att, srcs, ea_csr,
                                             row_ptr, g1_b, bn1_g, bn1_b, h1);

  // ---- GAT layer 2 ----
  k_gemm256<256><<<NN / 32, 256, 0, stream>>>(h1, g2_wl, xl);
  k_gemm256<256><<<NN / 32, 256, 0, stream>>>(h1, g2_wr, xr);
  k_gat_fused<0><<<NN / 4, 256, 0, stream>>>(xl, xr, g2_we, g2_att, srcs, ea_csr,
                                             row_ptr, g2_b, bn2_g, bn2_b, h0);

  // ---- SAGE ----
  k_sage<<<NN / 4, 256, 0, stream>>>(h0, row_ptr, srcs, cnt, sage_wl, sage_bl, sage_wr, bn3_g, bn3_b, h3);

  // ---- pooling + heads ----
  k_pool<<<(NN + 255) / 256, 256, 0, stream>>>(h3, batch, psum, pmax, pcnt);
  k_graph_head<<<NG, 64, 0, stream>>>(psum, pmax, pcnt, gh_w1, gh_b1, gh_w2, gh_b2, gh_w3, gh_b3, out);
  k_edge_head<<<NE / 256, 256, 0, stream>>>(h3, ei, edge_attr, eh_w1, eh_b1, eh_w2, eh_b2, out + NG);
}

// Round 4
// 591.339 us; speedup vs baseline: 1.7476x; 1.1923x over previous
//
#include <hip/hip_runtime.h>

#define NN 20000
#define NE 320000
#define EP (NE + NN)          // 340000 edges incl. self loops
#define NG 8
#define HC 256
#define NODE_IN 18
#define HID 64
#define NEG_SLOPE 0.2f
#define BN_EPS 1e-5f

// ---------------- workspace layout (float offsets) ----------------
#define OFF_XL    0u                      // [NN*256]
#define OFF_XR    5120000u                // [NN*256]
#define OFF_H1    10240000u               // [NN*256]
#define OFF_H0    15360000u               // [NN*64]  (h0, later reused as h2)
#define OFF_H3    16640000u               // [NN*64]
#define OFF_ZERO  17920000u               // start of zeroed region
#define OFF_LA    17920000u               // loop_attr [NN*4]
#define OFF_CNT   18000000u               // uint cnt [NN]
#define OFF_PSUM  18020000u               // [8*64]
#define OFF_PMAX  18020512u               // [8*64]
#define OFF_PCNT  18021024u               // [16]
#define ZERO_FLOATS (18021040u - 17920000u)
#define OFF_EACSR 18021040u               // float4-aligned: [EP*4] CSR-ordered edge attrs
#define OFF_RP    19381040u               // int [NN+1]
#define OFF_POS   19401041u               // int [NN]
#define OFF_SRC   19421041u               // int [EP]  (sign bit = self-loop flag)

// ------------------------------------------------------------------
// K1: per-dst edge count + sum of edge_attr (for self-loop fill 'mean')
__global__ __launch_bounds__(256) void k_edge_stats(
    const int* __restrict__ ei, const float* __restrict__ ea,
    float* __restrict__ loop_attr, unsigned* __restrict__ cnt) {
  int e = blockIdx.x * 256 + threadIdx.x;
  if (e >= NE) return;
  int d = ei[NE + e];
  atomicAdd(&cnt[d], 1u);
  #pragma unroll
  for (int j = 0; j < 4; j++) atomicAdd(&loop_attr[d * 4 + j], ea[e * 4 + j]);
}

__global__ __launch_bounds__(256) void k_loop_finalize(
    float* __restrict__ loop_attr, const unsigned* __restrict__ cnt) {
  int i = blockIdx.x * 256 + threadIdx.x;
  if (i >= NN * 4) return;
  float c = (float)cnt[i >> 2];
  if (c < 1.f) c = 1.f;
  loop_attr[i] = loop_attr[i] / c;
}

// ------------------------------------------------------------------
// K3: encoder, wave-per-node (lane = channel).  No per-thread arrays ->
// no scratch spill.  hid broadcast via per-wave LDS row.
#define ENC_NPW 4   // nodes per wave
__global__ __launch_bounds__(256) void k_encoder(
    const float* __restrict__ x, const float* __restrict__ w1, const float* __restrict__ b1,
    const float* __restrict__ w2, const float* __restrict__ b2, float* __restrict__ h0) {
  __shared__ float W1[NODE_IN * HID];
  __shared__ float W2[HID * HID];
  __shared__ float B1s[HID];
  __shared__ float B2s[HID];
  __shared__ float hid_s[4][HID];
  const int tid = threadIdx.x;
  for (int i = tid; i < NODE_IN * HID; i += 256) W1[i] = w1[i];
  for (int i = tid; i < HID * HID; i += 256) W2[i] = w2[i];
  if (tid < HID) { B1s[tid] = b1[tid]; B2s[tid] = b2[tid]; }
  __syncthreads();
  const int lane = tid & 63;
  const int w = tid >> 6;
  #pragma unroll
  for (int t = 0; t < ENC_NPW; t++) {
    const int n = blockIdx.x * (4 * ENC_NPW) + w * ENC_NPW + t;
    const float* xp = &x[(size_t)n * NODE_IN];
    float s = B1s[lane];
    #pragma unroll
    for (int i = 0; i < NODE_IN; i++) s += xp[i] * W1[i * HID + lane];
    hid_s[w][lane] = fmaxf(s, 0.f);       // same-wave write->read, lockstep safe
    float o = B2s[lane];
    #pragma unroll 8
    for (int k = 0; k < HID; k++) o += hid_s[w][k] * W2[k * HID + lane];
    h0[(size_t)n * HID + lane] = o;
  }
}

// ------------------------------------------------------------------
// K_scan: exclusive scan of (cnt[i]+1) -> row_ptr, pos  (single block)
__global__ __launch_bounds__(256) void k_scan(
    const unsigned* __restrict__ cnt, int* __restrict__ row_ptr, int* __restrict__ pos) {
  __shared__ int lds[256];
  __shared__ int carry;
  int tid = threadIdx.x;
  if (tid == 0) carry = 0;
  __syncthreads();
  for (int base = 0; base < NN; base += 256) {
    int idx = base + tid;
    int v = (idx < NN) ? ((int)cnt[idx] + 1) : 0;
    lds[tid] = v;
    __syncthreads();
    for (int off = 1; off < 256; off <<= 1) {
      int t = (tid >= off) ? lds[tid - off] : 0;
      __syncthreads();
      lds[tid] += t;
      __syncthreads();
    }
    int excl = carry + lds[tid] - v;
    if (idx < NN) { row_ptr[idx] = excl; pos[idx] = excl; }
    __syncthreads();
    if (tid == 0) carry += lds[255];
    __syncthreads();
  }
  if (tid == 0) row_ptr[NN] = carry;   // == EP
}

// K_scatter: CSR slot -> src id (sign bit = self loop) + CSR-ordered edge attrs
__global__ __launch_bounds__(256) void k_csr_scatter(
    const int* __restrict__ ei, int* __restrict__ pos,
    const float* __restrict__ ea, const float* __restrict__ loop_attr,
    int* __restrict__ srcs, float* __restrict__ ea_csr) {
  int e = blockIdx.x * 256 + threadIdx.x;
  if (e >= EP) return;
  int d, s, flag;
  float4 av;
  if (e < NE) {
    s = ei[e]; d = ei[NE + e]; flag = 0;
    av = *(const float4*)&ea[(size_t)e * 4];
  } else {
    s = e - NE; d = s; flag = (int)0x80000000;
    av = *(const float4*)&loop_attr[(size_t)(e - NE) * 4];
  }
  int p = atomicAdd(&pos[d], 1);
  srcs[p] = s | flag;
  *(float4*)&ea_csr[(size_t)p * 4] = av;
}

// ------------------------------------------------------------------
// K4: OUT[NN][256] = A[NN][K] @ W[K][256]  (32 nodes x 256 cols / block)
template <int K>
__global__ __launch_bounds__(256) void k_gemm256(
    const float* __restrict__ A, const float* __restrict__ W, float* __restrict__ OUT) {
  __shared__ float Wl[32 * 256];
  __shared__ float Al[32 * 36];
  const int tid = threadIdx.x;
  const int n0 = blockIdx.x * 32;
  const int tx = tid & 63, ty = tid >> 6;
  float acc[8][4];
  #pragma unroll
  for (int m = 0; m < 8; m++)
    #pragma unroll
    for (int c = 0; c < 4; c++) acc[m][c] = 0.f;

  for (int kt = 0; kt < K; kt += 32) {
    #pragma unroll
    for (int r = 0; r < 8; r++) {
      int i4 = tid + 256 * r;
      int row = i4 >> 6;
      int col4 = (i4 & 63) * 4;
      *(float4*)&Wl[row * 256 + col4] = *(const float4*)&W[(size_t)(kt + row) * 256 + col4];
    }
    {
      int m = tid >> 3, kk = (tid & 7) * 4;
      float4 av = *(const float4*)&A[(size_t)(n0 + m) * K + kt + kk];
      Al[(kk + 0) * 36 + m] = av.x;
      Al[(kk + 1) * 36 + m] = av.y;
      Al[(kk + 2) * 36 + m] = av.z;
      Al[(kk + 3) * 36 + m] = av.w;
    }
    __syncthreads();
    #pragma unroll 8
    for (int k = 0; k < 32; k++) {
      float4 b = *(float4*)&Wl[k * 256 + tx * 4];
      float4 a0v = *(float4*)&Al[k * 36 + ty * 8];
      float4 a1v = *(float4*)&Al[k * 36 + ty * 8 + 4];
      float am[8] = {a0v.x, a0v.y, a0v.z, a0v.w, a1v.x, a1v.y, a1v.z, a1v.w};
      #pragma unroll
      for (int m = 0; m < 8; m++) {
        acc[m][0] += am[m] * b.x;
        acc[m][1] += am[m] * b.y;
        acc[m][2] += am[m] * b.z;
        acc[m][3] += am[m] * b.w;
      }
    }
    __syncthreads();
  }
  #pragma unroll
  for (int m = 0; m < 8; m++) {
    float4 o = {acc[m][0], acc[m][1], acc[m][2], acc[m][3]};
    *(float4*)&OUT[(size_t)(n0 + ty * 8 + m) * 256 + tx * 4] = o;
  }
}

// ------------------------------------------------------------------
// K5: fused GATv2, ONE pass: logits + online softmax + aggregation + epilogue.
// 1 wave / node, lane owns channels c = 4*lane..4*lane+3 (head = lane>>4).
// Dual independent online accumulators (A/B) for 2 gathers in flight.
template <int CONCAT>
__global__ __launch_bounds__(256) void k_gat_fused(
    const float* __restrict__ xl, const float* __restrict__ xr,
    const float* __restrict__ we, const float* __restrict__ att,
    const int* __restrict__ srcs, const float* __restrict__ ea_csr,
    const int* __restrict__ row_ptr,
    const float* __restrict__ bias, const float* __restrict__ bng,
    const float* __restrict__ bnb, float* __restrict__ outp) {
  const int lane = threadIdx.x & 63;
  const int w = threadIdx.x >> 6;
  const int i = blockIdx.x * 4 + w;
  const int c0 = lane * 4;

  const float4 attv = *(const float4*)&att[c0];
  const float4 we0 = *(const float4*)&we[0 * HC + c0];
  const float4 we1 = *(const float4*)&we[1 * HC + c0];
  const float4 we2 = *(const float4*)&we[2 * HC + c0];
  const float4 we3 = *(const float4*)&we[3 * HC + c0];
  const float4 xrd = *(const float4*)&xr[(size_t)i * HC + c0];

  const int start = row_ptr[i];
  const int deg = row_ptr[i + 1] - start;

  float mxA = -1e30f, dnA = 0.f, aA0 = 0.f, aA1 = 0.f, aA2 = 0.f, aA3 = 0.f;
  float mxB = -1e30f, dnB = 0.f, aB0 = 0.f, aB1 = 0.f, aB2 = 0.f, aB3 = 0.f;

  for (int base = 0; base < deg; base += 64) {
    int rem = deg - base;
    if (rem > 64) rem = 64;
    int sv = 0;
    if (lane < rem) sv = srcs[start + base + lane];
    int jj = 0;
    for (; jj + 2 <= rem; jj += 2) {
      int s0 = __shfl(sv, jj) & 0x7fffffff;
      int s1 = __shfl(sv, jj + 1) & 0x7fffffff;
      float4 a0 = *(const float4*)&ea_csr[(size_t)(start + base + jj) * 4];
      float4 a1 = *(const float4*)&ea_csr[(size_t)(start + base + jj + 1) * 4];
      float4 x0 = *(const float4*)&xl[(size_t)s0 * HC + c0];
      float4 x1 = *(const float4*)&xl[(size_t)s1 * HC + c0];
      // ---- edge 0 -> stream A ----
      {
        float m0 = x0.x + xrd.x + a0.x * we0.x + a0.y * we1.x + a0.z * we2.x + a0.w * we3.x;
        float m1 = x0.y + xrd.y + a0.x * we0.y + a0.y * we1.y + a0.z * we2.y + a0.w * we3.y;
        float m2 = x0.z + xrd.z + a0.x * we0.z + a0.y * we1.z + a0.z * we2.z + a0.w * we3.z;
        float m3 = x0.w + xrd.w + a0.x * we0.w + a0.y * we1.w + a0.z * we2.w + a0.w * we3.w;
        m0 = (m0 > 0.f) ? m0 : NEG_SLOPE * m0;
        m1 = (m1 > 0.f) ? m1 : NEG_SLOPE * m1;
        m2 = (m2 > 0.f) ? m2 : NEG_SLOPE * m2;
        m3 = (m3 > 0.f) ? m3 : NEG_SLOPE * m3;
        float lg = m0 * attv.x + m1 * attv.y + m2 * attv.z + m3 * attv.w;
        lg += __shfl_xor(lg, 1);
        lg += __shfl_xor(lg, 2);
        lg += __shfl_xor(lg, 4);
        lg += __shfl_xor(lg, 8);
        float nmx = fmaxf(mxA, lg);
        float sc = __expf(mxA - nmx);
        float p = __expf(lg - nmx);
        dnA = dnA * sc + p;
        aA0 = fmaf(aA0, sc, p * x0.x);
        aA1 = fmaf(aA1, sc, p * x0.y);
        aA2 = fmaf(aA2, sc, p * x0.z);
        aA3 = fmaf(aA3, sc, p * x0.w);
        mxA = nmx;
      }
      // ---- edge 1 -> stream B ----
      {
        float m0 = x1.x + xrd.x + a1.x * we0.x + a1.y * we1.x + a1.z * we2.x + a1.w * we3.x;
        float m1 = x1.y + xrd.y + a1.x * we0.y + a1.y * we1.y + a1.z * we2.y + a1.w * we3.y;
        float m2 = x1.z + xrd.z + a1.x * we0.z + a1.y * we1.z + a1.z * we2.z + a1.w * we3.z;
        float m3 = x1.w + xrd.w + a1.x * we0.w + a1.y * we1.w + a1.z * we2.w + a1.w * we3.w;
        m0 = (m0 > 0.f) ? m0 : NEG_SLOPE * m0;
        m1 = (m1 > 0.f) ? m1 : NEG_SLOPE * m1;
        m2 = (m2 > 0.f) ? m2 : NEG_SLOPE * m2;
        m3 = (m3 > 0.f) ? m3 : NEG_SLOPE * m3;
        float lg = m0 * attv.x + m1 * attv.y + m2 * attv.z + m3 * attv.w;
        lg += __shfl_xor(lg, 1);
        lg += __shfl_xor(lg, 2);
        lg += __shfl_xor(lg, 4);
        lg += __shfl_xor(lg, 8);
        float nmx = fmaxf(mxB, lg);
        float sc = __expf(mxB - nmx);
        float p = __expf(lg - nmx);
        dnB = dnB * sc + p;
        aB0 = fmaf(aB0, sc, p * x1.x);
        aB1 = fmaf(aB1, sc, p * x1.y);
        aB2 = fmaf(aB2, sc, p * x1.z);
        aB3 = fmaf(aB3, sc, p * x1.w);
        mxB = nmx;
      }
    }
    if (jj < rem) {   // tail edge -> stream A
      int s0 = __shfl(sv, jj) & 0x7fffffff;
      float4 a0 = *(const float4*)&ea_csr[(size_t)(start + base + jj) * 4];
      float4 x0 = *(const float4*)&xl[(size_t)s0 * HC + c0];
      float m0 = x0.x + xrd.x + a0.x * we0.x + a0.y * we1.x + a0.z * we2.x + a0.w * we3.x;
      float m1 = x0.y + xrd.y + a0.x * we0.y + a0.y * we1.y + a0.z * we2.y + a0.w * we3.y;
      float m2 = x0.z + xrd.z + a0.x * we0.z + a0.y * we1.z + a0.z * we2.z + a0.w * we3.z;
      float m3 = x0.w + xrd.w + a0.x * we0.w + a0.y * we1.w + a0.z * we2.w + a0.w * we3.w;
      m0 = (m0 > 0.f) ? m0 : NEG_SLOPE * m0;
      m1 = (m1 > 0.f) ? m1 : NEG_SLOPE * m1;
      m2 = (m2 > 0.f) ? m2 : NEG_SLOPE * m2;
      m3 = (m3 > 0.f) ? m3 : NEG_SLOPE * m3;
      float lg = m0 * attv.x + m1 * attv.y + m2 * attv.z + m3 * attv.w;
      lg += __shfl_xor(lg, 1);
      lg += __shfl_xor(lg, 2);
      lg += __shfl_xor(lg, 4);
      lg += __shfl_xor(lg, 8);
      float nmx = fmaxf(mxA, lg);
      float sc = __expf(mxA - nmx);
      float p = __expf(lg - nmx);
      dnA = dnA * sc + p;
      aA0 = fmaf(aA0, sc, p * x0.x);
      aA1 = fmaf(aA1, sc, p * x0.y);
      aA2 = fmaf(aA2, sc, p * x0.z);
      aA3 = fmaf(aA3, sc, p * x0.w);
      mxA = nmx;
    }
  }

  // merge streams
  float m = fmaxf(mxA, mxB);
  float sA = __expf(mxA - m), sB = __expf(mxB - m);
  float dn = dnA * sA + dnB * sB;
  float rinv = 1.f / dn;
  float acc0 = (aA0 * sA + aB0 * sB) * rinv;
  float acc1 = (aA1 * sA + aB1 * sB) * rinv;
  float acc2 = (aA2 * sA + aB2 * sB) * rinv;
  float acc3 = (aA3 * sA + aB3 * sB) * rinv;

  const float inv_sqrt = rsqrtf(1.f + BN_EPS);
  if (CONCAT) {
    float4 bi = *(const float4*)&bias[c0];
    float4 g = *(const float4*)&bng[c0];
    float4 bb = *(const float4*)&bnb[c0];
    float v0 = (acc0 + bi.x) * (g.x * inv_sqrt) + bb.x;
    float v1 = (acc1 + bi.y) * (g.y * inv_sqrt) + bb.y;
    float v2 = (acc2 + bi.z) * (g.z * inv_sqrt) + bb.z;
    float v3 = (acc3 + bi.w) * (g.w * inv_sqrt) + bb.w;
    v0 = (v0 > 0.f) ? v0 : (__expf(v0) - 1.f);
    v1 = (v1 > 0.f) ? v1 : (__expf(v1) - 1.f);
    v2 = (v2 > 0.f) ? v2 : (__expf(v2) - 1.f);
    v3 = (v3 > 0.f) ? v3 : (__expf(v3) - 1.f);
    float4 o = {v0, v1, v2, v3};
    *(float4*)&outp[(size_t)i * HC + c0] = o;
  } else {
    // mean over heads: sum lanes {l, l^16, l^32, l^48} (acc already normalized)
    acc0 += __shfl_xor(acc0, 16); acc0 += __shfl_xor(acc0, 32);
    acc1 += __shfl_xor(acc1, 16); acc1 += __shfl_xor(acc1, 32);
    acc2 += __shfl_xor(acc2, 16); acc2 += __shfl_xor(acc2, 32);
    acc3 += __shfl_xor(acc3, 16); acc3 += __shfl_xor(acc3, 32);
    if (lane < 16) {
      int cc = lane * 4;
      float4 bi = *(const float4*)&bias[cc];
      float4 g = *(const float4*)&bng[cc];
      float4 bb = *(const float4*)&bnb[cc];
      float v0 = (0.25f * acc0 + bi.x) * (g.x * inv_sqrt) + bb.x;
      float v1 = (0.25f * acc1 + bi.y) * (g.y * inv_sqrt) + bb.y;
      float v2 = (0.25f * acc2 + bi.z) * (g.z * inv_sqrt) + bb.z;
      float v3 = (0.25f * acc3 + bi.w) * (g.w * inv_sqrt) + bb.w;
      v0 = (v0 > 0.f) ? v0 : (__expf(v0) - 1.f);
      v1 = (v1 > 0.f) ? v1 : (__expf(v1) - 1.f);
      v2 = (v2 > 0.f) ? v2 : (__expf(v2) - 1.f);
      v3 = (v3 > 0.f) ? v3 : (__expf(v3) - 1.f);
      float4 o = {v0, v1, v2, v3};
      *(float4*)&outp[(size_t)i * 64 + cc] = o;
    }
  }
}

// ------------------------------------------------------------------
// K8: fused SAGE: h3 = relu(bn3(mean_agg@wl + bl + h2@wr))  (1 wave/node)
__global__ __launch_bounds__(256) void k_sage(
    const float* __restrict__ h2, const int* __restrict__ row_ptr,
    const int* __restrict__ srcs, const unsigned* __restrict__ cnt,
    const float* __restrict__ wl, const float* __restrict__ bl,
    const float* __restrict__ wr, const float* __restrict__ bng,
    const float* __restrict__ bnb, float* __restrict__ h3) {
  __shared__ float agg_s[4][64];
  __shared__ float h2_s[4][64];
  int lane = threadIdx.x & 63;
  int w = threadIdx.x >> 6;
  int i = blockIdx.x * 4 + w;
  int start = row_ptr[i], end = row_ptr[i + 1];
  float a = 0.f;
  for (int j = start; j < end; ++j) {
    int sv = srcs[j];
    if (sv >= 0) a += h2[(size_t)sv * 64 + lane];   // skip self-loop slots
  }
  float c = (float)cnt[i];
  if (c < 1.f) c = 1.f;
  agg_s[w][lane] = a / c;
  h2_s[w][lane] = h2[(size_t)i * 64 + lane];
  __syncthreads();
  float s = bl[lane];
  #pragma unroll 4
  for (int k = 0; k < 64; k++)
    s += agg_s[w][k] * wl[k * 64 + lane] + h2_s[w][k] * wr[k * 64 + lane];
  s = s * (bng[lane] * rsqrtf(1.f + BN_EPS)) + bnb[lane];
  s = fmaxf(s, 0.f);
  h3[(size_t)i * 64 + lane] = s;
}

// ------------------------------------------------------------------
// K9: pooling: per-graph sum / max / count
__global__ __launch_bounds__(256) void k_pool(
    const float* __restrict__ h3, const int* __restrict__ batch,
    float* __restrict__ psum, float* __restrict__ pmax, float* __restrict__ pcnt) {
  int j = threadIdx.x & 63, grp = threadIdx.x >> 6;
  int nbase = blockIdx.x * 256 + grp * 64;
  float s = 0.f, m = 0.f, cn = 0.f;
  int cur = -1;
  for (int t = 0; t < 64; t++) {
    int n = nbase + t;
    if (n >= NN) break;
    int g = batch[n];
    if (g != cur) {
      if (cur >= 0) {
        atomicAdd(&psum[cur * 64 + j], s);
        atomicMax((int*)&pmax[cur * 64 + j], __float_as_int(m));
        if (j == 0) atomicAdd(&pcnt[cur], cn);
      }
      cur = g; s = 0.f; m = 0.f; cn = 0.f;
    }
    float v = h3[(size_t)n * 64 + j];
    s += v; m = fmaxf(m, v); cn += 1.f;
  }
  if (cur >= 0) {
    atomicAdd(&psum[cur * 64 + j], s);
    atomicMax((int*)&pmax[cur * 64 + j], __float_as_int(m));
    if (j == 0) atomicAdd(&pcnt[cur], cn);
  }
}

// ------------------------------------------------------------------
// K10: graph head (block per graph, 64 threads)
__global__ void k_graph_head(
    const float* __restrict__ psum, const float* __restrict__ pmax,
    const float* __restrict__ pcnt,
    const float* __restrict__ w1, const float* __restrict__ b1,
    const float* __restrict__ w2, const float* __restrict__ b2,
    const float* __restrict__ w3, const float* __restrict__ b3,
    float* __restrict__ out) {
  __shared__ float hp[128];
  __shared__ float z1[64];
  __shared__ float z2[32];
  int g = blockIdx.x, j = threadIdx.x;
  float c = pcnt[g];
  if (c < 1.f) c = 1.f;
  hp[j] = psum[g * 64 + j] / c;
  hp[64 + j] = pmax[g * 64 + j];
  __syncthreads();
  float s = b1[j];
  #pragma unroll 8
  for (int k = 0; k < 128; k++) s += hp[k] * w1[k * 64 + j];
  z1[j] = fmaxf(s, 0.f);
  __syncthreads();
  if (j < 32) {
    float s2 = b2[j];
    #pragma unroll 8
    for (int k = 0; k < 64; k++) s2 += z1[k] * w2[k * 32 + j];
    z2[j] = fmaxf(s2, 0.f);
  }
  __syncthreads();
  if (j == 0) {
    float s3 = b3[0];
    #pragma unroll
    for (int k = 0; k < 32; k++) s3 += z2[k] * w3[k];
    out[g] = 1.f / (1.f + expf(-s3));
  }
}

// ------------------------------------------------------------------
// K11: edge head (thread per edge; weights read lane-uniform -> s_load)
__global__ __launch_bounds__(256) void k_edge_head(
    const float* __restrict__ h3, const int* __restrict__ ei,
    const float* __restrict__ ea,
    const float* __restrict__ w1, const float* __restrict__ b1,
    const float* __restrict__ w2, const float* __restrict__ b2,
    float* __restrict__ out) {
  int e = blockIdx.x * 256 + threadIdx.x;
  if (e >= NE) return;
  int s = ei[e], d = ei[NE + e];
  float acc[32];
  #pragma unroll
  for (int j = 0; j < 32; j++) acc[j] = b1[j];
  const float4* hs = (const float4*)&h3[(size_t)s * 64];
  const float4* hd = (const float4*)&h3[(size_t)d * 64];
  for (int k4 = 0; k4 < 16; k4++) {
    float4 v = hs[k4];
    const float* w = &w1[k4 * 4 * 32];
    #pragma unroll
    for (int j = 0; j < 32; j++) acc[j] += v.x * w[j];
    #pragma unroll
    for (int j = 0; j < 32; j++) acc[j] += v.y * w[32 + j];
    #pragma unroll
    for (int j = 0; j < 32; j++) acc[j] += v.z * w[64 + j];
    #pragma unroll
    for (int j = 0; j < 32; j++) acc[j] += v.w * w[96 + j];
  }
  for (int k4 = 0; k4 < 16; k4++) {
    float4 v = hd[k4];
    const float* w = &w1[(64 + k4 * 4) * 32];
    #pragma unroll
    for (int j = 0; j < 32; j++) acc[j] += v.x * w[j];
    #pragma unroll
    for (int j = 0; j < 32; j++) acc[j] += v.y * w[32 + j];
    #pragma unroll
    for (int j = 0; j < 32; j++) acc[j] += v.z * w[64 + j];
    #pragma unroll
    for (int j = 0; j < 32; j++) acc[j] += v.w * w[96 + j];
  }
  {
    float4 v = *(const float4*)&ea[(size_t)e * 4];
    const float* w = &w1[128 * 32];
    #pragma unroll
    for (int j = 0; j < 32; j++) acc[j] += v.x * w[j];
    #pragma unroll
    for (int j = 0; j < 32; j++) acc[j] += v.y * w[32 + j];
    #pragma unroll
    for (int j = 0; j < 32; j++) acc[j] += v.z * w[64 + j];
    #pragma unroll
    for (int j = 0; j < 32; j++) acc[j] += v.w * w[96 + j];
  }
  float s2 = b2[0];
  #pragma unroll
  for (int j = 0; j < 32; j++) s2 += fmaxf(acc[j], 0.f) * w2[j];
  out[e] = 1.f / (1.f + expf(-s2));
}

// ------------------------------------------------------------------
extern "C" void kernel_launch(void* const* d_in, const int* in_sizes, int n_in,
                              void* d_out, int out_size, void* d_ws, size_t ws_size,
                              hipStream_t stream) {
  const float* x         = (const float*)d_in[0];
  const float* edge_attr = (const float*)d_in[1];
  const float* enc_w1 = (const float*)d_in[2];
  const float* enc_b1 = (const float*)d_in[3];
  const float* enc_w2 = (const float*)d_in[4];
  const float* enc_b2 = (const float*)d_in[5];
  const float* g1_wl = (const float*)d_in[6];
  const float* g1_wr = (const float*)d_in[7];
  const float* g1_we = (const float*)d_in[8];
  const float* g1_att = (const float*)d_in[9];
  const float* g1_b = (const float*)d_in[10];
  const float* bn1_g = (const float*)d_in[11];
  const float* bn1_b = (const float*)d_in[12];
  const float* g2_wl = (const float*)d_in[13];
  const float* g2_wr = (const float*)d_in[14];
  const float* g2_we = (const float*)d_in[15];
  const float* g2_att = (const float*)d_in[16];
  const float* g2_b = (const float*)d_in[17];
  const float* bn2_g = (const float*)d_in[18];
  const float* bn2_b = (const float*)d_in[19];
  const float* sage_wl = (const float*)d_in[20];
  const float* sage_bl = (const float*)d_in[21];
  const float* sage_wr = (const float*)d_in[22];
  const float* bn3_g = (const float*)d_in[23];
  const float* bn3_b = (const float*)d_in[24];
  const float* gh_w1 = (const float*)d_in[25];
  const float* gh_b1 = (const float*)d_in[26];
  const float* gh_w2 = (const float*)d_in[27];
  const float* gh_b2 = (const float*)d_in[28];
  const float* gh_w3 = (const float*)d_in[29];
  const float* gh_b3 = (const float*)d_in[30];
  const float* eh_w1 = (const float*)d_in[31];
  const float* eh_b1 = (const float*)d_in[32];
  const float* eh_w2 = (const float*)d_in[33];
  const float* eh_b2 = (const float*)d_in[34];
  const int* ei    = (const int*)d_in[35];
  const int* batch = (const int*)d_in[36];
  float* out = (float*)d_out;

  float* ws = (float*)d_ws;
  float* xl = ws + OFF_XL;
  float* xr = ws + OFF_XR;
  float* h1 = ws + OFF_H1;
  float* h0 = ws + OFF_H0;   // later h2
  float* h3 = ws + OFF_H3;
  float* la = ws + OFF_LA;
  unsigned* cnt = (unsigned*)(ws + OFF_CNT);
  float* psum = ws + OFF_PSUM;
  float* pmax = ws + OFF_PMAX;
  float* pcnt = ws + OFF_PCNT;
  float* ea_csr = ws + OFF_EACSR;
  int* row_ptr = (int*)(ws + OFF_RP);
  int* pos = (int*)(ws + OFF_POS);
  int* srcs = (int*)(ws + OFF_SRC);

  hipMemsetAsync(ws + OFF_ZERO, 0, ZERO_FLOATS * sizeof(float), stream);

  k_edge_stats<<<NE / 256, 256, 0, stream>>>(ei, edge_attr, la, cnt);
  k_loop_finalize<<<(NN * 4 + 255) / 256, 256, 0, stream>>>(la, cnt);
  k_encoder<<<NN / (4 * ENC_NPW), 256, 0, stream>>>(x, enc_w1, enc_b1, enc_w2, enc_b2, h0);
  k_scan<<<1, 256, 0, stream>>>(cnt, row_ptr, pos);
  k_csr_scatter<<<(EP + 255) / 256, 256, 0, stream>>>(ei, pos, edge_attr, la, srcs, ea_csr);

  // ---- GAT layer 1 ----
  k_gemm256<64><<<NN / 32, 256, 0, stream>>>(h0, g1_wl, xl);
  k_gemm256<64><<<NN / 32, 256, 0, stream>>>(h0, g1_wr, xr);
  k_gat_fused<1><<<NN / 4, 256, 0, stream>>>(xl, xr, g1_we, g1_att, srcs, ea_csr,
                                             row_ptr, g1_b, bn1_g, bn1_b, h1);

  // ---- GAT layer 2 ----
  k_gemm256<256><<<NN / 32, 256, 0, stream>>>(h1, g2_wl, xl);
  k_gemm256<256><<<NN / 32, 256, 0, stream>>>(h1, g2_wr, xr);
  k_gat_fused<0><<<NN / 4, 256, 0, stream>>>(xl, xr, g2_we, g2_att, srcs, ea_csr,
                                             row_ptr, g2_b, bn2_g, bn2_b, h0);

  // ---- SAGE ----
  k_sage<<<NN / 4, 256, 0, stream>>>(h0, row_ptr, srcs, cnt, sage_wl, sage_bl, sage_wr, bn3_g, bn3_b, h3);

  // ---- pooling + heads ----
  k_pool<<<(NN + 255) / 256, 256, 0, stream>>>(h3, batch, psum, pmax, pcnt);
  k_graph_head<<<NG, 64, 0, stream>>>(psum, pmax, pcnt, gh_w1, gh_b1, gh_w2, gh_b2, gh_w3, gh_b3, out);
  k_edge_head<<<NE / 256, 256, 0, stream>>>(h3, ei, edge_attr, eh_w1, eh_b1, eh_w2, eh_b2, out + NG);
}

// Round 5
// 512.152 us; speedup vs baseline: 2.0179x; 1.1546x over previous
//
#include <hip/hip_runtime.h>

#define NN 20000
#define NE 320000
#define EP (NE + NN)          // 340000 edges incl. self loops
#define NG 8
#define HC 256
#define NODE_IN 18
#define HID 64
#define NEG_SLOPE 0.2f
#define BN_EPS 1e-5f

// ---------------- workspace layout (float offsets) ----------------
#define OFF_XL    0u                      // [NN*256]
#define OFF_XR    5120000u                // [NN*256]
#define OFF_H1    10240000u               // [NN*256]
#define OFF_H0    15360000u               // [NN*64]  (h0, later reused as h2)
#define OFF_H3    16640000u               // [NN*64]
#define OFF_ZERO  17920000u               // start of zeroed region
#define OFF_LA    17920000u               // loop_attr [NN*4]
#define OFF_CNT   18000000u               // uint cnt [NN]
#define OFF_PSUM  18020000u               // [8*64]
#define OFF_PMAX  18020512u               // [8*64]
#define OFF_PCNT  18021024u               // [16]
#define ZERO_FLOATS (18021040u - 17920000u)
#define OFF_EACSR 18021040u               // float4-aligned: [EP*4] CSR-ordered edge attrs
#define OFF_RP    19381040u               // int [NN+1]
#define OFF_POS   19401041u               // int [NN]
#define OFF_SRC   19421041u               // int [EP]  (sign bit = self-loop flag)
#define OFF_BSUM  19761056u               // int [32] block sums for scan

#define SCAN_ELEM 1024
#define SCAN_NB ((NN + SCAN_ELEM - 1) / SCAN_ELEM)   // 20

// ------------------------------------------------------------------
// K1: per-dst edge count + sum of edge_attr (for self-loop fill 'mean')
__global__ __launch_bounds__(256) void k_edge_stats(
    const int* __restrict__ ei, const float* __restrict__ ea,
    float* __restrict__ loop_attr, unsigned* __restrict__ cnt) {
  int e = blockIdx.x * 256 + threadIdx.x;
  if (e >= NE) return;
  int d = ei[NE + e];
  atomicAdd(&cnt[d], 1u);
  #pragma unroll
  for (int j = 0; j < 4; j++) atomicAdd(&loop_attr[d * 4 + j], ea[e * 4 + j]);
}

__global__ __launch_bounds__(256) void k_loop_finalize(
    float* __restrict__ loop_attr, const unsigned* __restrict__ cnt) {
  int i = blockIdx.x * 256 + threadIdx.x;
  if (i >= NN * 4) return;
  float c = (float)cnt[i >> 2];
  if (c < 1.f) c = 1.f;
  loop_attr[i] = loop_attr[i] / c;
}

// ------------------------------------------------------------------
// K3: encoder, wave-per-node (lane = channel).
#define ENC_NPW 4   // nodes per wave
__global__ __launch_bounds__(256) void k_encoder(
    const float* __restrict__ x, const float* __restrict__ w1, const float* __restrict__ b1,
    const float* __restrict__ w2, const float* __restrict__ b2, float* __restrict__ h0) {
  __shared__ float W1[NODE_IN * HID];
  __shared__ float W2[HID * HID];
  __shared__ float B1s[HID];
  __shared__ float B2s[HID];
  __shared__ float hid_s[4][HID];
  const int tid = threadIdx.x;
  for (int i = tid; i < NODE_IN * HID; i += 256) W1[i] = w1[i];
  for (int i = tid; i < HID * HID; i += 256) W2[i] = w2[i];
  if (tid < HID) { B1s[tid] = b1[tid]; B2s[tid] = b2[tid]; }
  __syncthreads();
  const int lane = tid & 63;
  const int w = tid >> 6;
  #pragma unroll
  for (int t = 0; t < ENC_NPW; t++) {
    const int n = blockIdx.x * (4 * ENC_NPW) + w * ENC_NPW + t;
    const float* xp = &x[(size_t)n * NODE_IN];
    float s = B1s[lane];
    #pragma unroll
    for (int i = 0; i < NODE_IN; i++) s += xp[i] * W1[i * HID + lane];
    hid_s[w][lane] = fmaxf(s, 0.f);       // same-wave write->read, lockstep safe
    float o = B2s[lane];
    #pragma unroll 8
    for (int k = 0; k < HID; k++) o += hid_s[w][k] * W2[k * HID + lane];
    h0[(size_t)n * HID + lane] = o;
  }
}

// ------------------------------------------------------------------
// K_scan_blk: per-block scan of (cnt[i]+1), 1024 elems/block, local prefixes
// into row_ptr, block totals into bsums.  ONE barrier.
__global__ __launch_bounds__(256) void k_scan_blk(
    const unsigned* __restrict__ cnt, int* __restrict__ row_ptr, int* __restrict__ bsums) {
  __shared__ int wsum[4];
  const int tid = threadIdx.x, lane = tid & 63, w = tid >> 6;
  const int i0 = blockIdx.x * SCAN_ELEM + tid * 4;
  int v0 = (i0 + 0 < NN) ? ((int)cnt[i0 + 0] + 1) : 0;
  int v1 = (i0 + 1 < NN) ? ((int)cnt[i0 + 1] + 1) : 0;
  int v2 = (i0 + 2 < NN) ? ((int)cnt[i0 + 2] + 1) : 0;
  int v3 = (i0 + 3 < NN) ? ((int)cnt[i0 + 3] + 1) : 0;
  int tsum = v0 + v1 + v2 + v3;
  int incl = tsum;
  #pragma unroll
  for (int off = 1; off < 64; off <<= 1) {
    int t = __shfl_up(incl, off);
    if (lane >= off) incl += t;
  }
  if (lane == 63) wsum[w] = incl;
  __syncthreads();
  int p = incl - tsum;                  // exclusive within wave
  #pragma unroll
  for (int k = 0; k < 4; k++) if (k < w) p += wsum[k];
  if (i0 + 0 < NN) row_ptr[i0 + 0] = p;
  if (i0 + 1 < NN) row_ptr[i0 + 1] = p + v0;
  if (i0 + 2 < NN) row_ptr[i0 + 2] = p + v0 + v1;
  if (i0 + 3 < NN) row_ptr[i0 + 3] = p + v0 + v1 + v2;
  if (tid == 0) bsums[blockIdx.x] = wsum[0] + wsum[1] + wsum[2] + wsum[3];
}

// K_scan_add: add cross-block offset in place; emit pos; row_ptr[NN]=EP.
__global__ __launch_bounds__(256) void k_scan_add(
    const int* __restrict__ bsums, int* __restrict__ row_ptr, int* __restrict__ pos) {
  const int b = blockIdx.x, tid = threadIdx.x;
  int off = 0;
  for (int j = 0; j < b; j++) off += bsums[j];
  const int i0 = b * SCAN_ELEM + tid * 4;
  #pragma unroll
  for (int k = 0; k < 4; k++) {
    int i = i0 + k;
    if (i < NN) {
      int v = row_ptr[i] + off;
      row_ptr[i] = v;
      pos[i] = v;
    }
  }
  if (b == 0 && tid == 0) row_ptr[NN] = EP;
}

// K_scatter: CSR slot -> src id (sign bit = self loop) + CSR-ordered edge attrs
__global__ __launch_bounds__(256) void k_csr_scatter(
    const int* __restrict__ ei, int* __restrict__ pos,
    const float* __restrict__ ea, const float* __restrict__ loop_attr,
    int* __restrict__ srcs, float* __restrict__ ea_csr) {
  int e = blockIdx.x * 256 + threadIdx.x;
  if (e >= EP) return;
  int d, s, flag;
  float4 av;
  if (e < NE) {
    s = ei[e]; d = ei[NE + e]; flag = 0;
    av = *(const float4*)&ea[(size_t)e * 4];
  } else {
    s = e - NE; d = s; flag = (int)0x80000000;
    av = *(const float4*)&loop_attr[(size_t)(e - NE) * 4];
  }
  int p = atomicAdd(&pos[d], 1);
  srcs[p] = s | flag;
  *(float4*)&ea_csr[(size_t)p * 4] = av;
}

// ------------------------------------------------------------------
// K4: OUT[NN][256] = A[NN][K] @ W[K][256]  (32 nodes x 256 cols / block)
template <int K>
__global__ __launch_bounds__(256) void k_gemm256(
    const float* __restrict__ A, const float* __restrict__ W, float* __restrict__ OUT) {
  __shared__ float Wl[32 * 256];
  __shared__ float Al[32 * 36];
  const int tid = threadIdx.x;
  const int n0 = blockIdx.x * 32;
  const int tx = tid & 63, ty = tid >> 6;
  float acc[8][4];
  #pragma unroll
  for (int m = 0; m < 8; m++)
    #pragma unroll
    for (int c = 0; c < 4; c++) acc[m][c] = 0.f;

  for (int kt = 0; kt < K; kt += 32) {
    #pragma unroll
    for (int r = 0; r < 8; r++) {
      int i4 = tid + 256 * r;
      int row = i4 >> 6;
      int col4 = (i4 & 63) * 4;
      *(float4*)&Wl[row * 256 + col4] = *(const float4*)&W[(size_t)(kt + row) * 256 + col4];
    }
    {
      int m = tid >> 3, kk = (tid & 7) * 4;
      float4 av = *(const float4*)&A[(size_t)(n0 + m) * K + kt + kk];
      Al[(kk + 0) * 36 + m] = av.x;
      Al[(kk + 1) * 36 + m] = av.y;
      Al[(kk + 2) * 36 + m] = av.z;
      Al[(kk + 3) * 36 + m] = av.w;
    }
    __syncthreads();
    #pragma unroll 8
    for (int k = 0; k < 32; k++) {
      float4 b = *(float4*)&Wl[k * 256 + tx * 4];
      float4 a0v = *(float4*)&Al[k * 36 + ty * 8];
      float4 a1v = *(float4*)&Al[k * 36 + ty * 8 + 4];
      float am[8] = {a0v.x, a0v.y, a0v.z, a0v.w, a1v.x, a1v.y, a1v.z, a1v.w};
      #pragma unroll
      for (int m = 0; m < 8; m++) {
        acc[m][0] += am[m] * b.x;
        acc[m][1] += am[m] * b.y;
        acc[m][2] += am[m] * b.z;
        acc[m][3] += am[m] * b.w;
      }
    }
    __syncthreads();
  }
  #pragma unroll
  for (int m = 0; m < 8; m++) {
    float4 o = {acc[m][0], acc[m][1], acc[m][2], acc[m][3]};
    *(float4*)&OUT[(size_t)(n0 + ty * 8 + m) * 256 + tx * 4] = o;
  }
}

// ------------------------------------------------------------------
// K5: fused GATv2, ONE pass: logits + online softmax + aggregation + epilogue.
// 1 wave / node, lane owns channels c = 4*lane..4*lane+3 (head = lane>>4).
// Dual independent online accumulators (A/B) for 2 gathers in flight.
template <int CONCAT>
__global__ __launch_bounds__(256) void k_gat_fused(
    const float* __restrict__ xl, const float* __restrict__ xr,
    const float* __restrict__ we, const float* __restrict__ att,
    const int* __restrict__ srcs, const float* __restrict__ ea_csr,
    const int* __restrict__ row_ptr,
    const float* __restrict__ bias, const float* __restrict__ bng,
    const float* __restrict__ bnb, float* __restrict__ outp) {
  const int lane = threadIdx.x & 63;
  const int w = threadIdx.x >> 6;
  const int i = blockIdx.x * 4 + w;
  const int c0 = lane * 4;

  const float4 attv = *(const float4*)&att[c0];
  const float4 we0 = *(const float4*)&we[0 * HC + c0];
  const float4 we1 = *(const float4*)&we[1 * HC + c0];
  const float4 we2 = *(const float4*)&we[2 * HC + c0];
  const float4 we3 = *(const float4*)&we[3 * HC + c0];
  const float4 xrd = *(const float4*)&xr[(size_t)i * HC + c0];

  const int start = row_ptr[i];
  const int deg = row_ptr[i + 1] - start;

  float mxA = -1e30f, dnA = 0.f, aA0 = 0.f, aA1 = 0.f, aA2 = 0.f, aA3 = 0.f;
  float mxB = -1e30f, dnB = 0.f, aB0 = 0.f, aB1 = 0.f, aB2 = 0.f, aB3 = 0.f;

  for (int base = 0; base < deg; base += 64) {
    int rem = deg - base;
    if (rem > 64) rem = 64;
    int sv = 0;
    if (lane < rem) sv = srcs[start + base + lane];
    int jj = 0;
    for (; jj + 2 <= rem; jj += 2) {
      int s0 = __shfl(sv, jj) & 0x7fffffff;
      int s1 = __shfl(sv, jj + 1) & 0x7fffffff;
      float4 a0 = *(const float4*)&ea_csr[(size_t)(start + base + jj) * 4];
      float4 a1 = *(const float4*)&ea_csr[(size_t)(start + base + jj + 1) * 4];
      float4 x0 = *(const float4*)&xl[(size_t)s0 * HC + c0];
      float4 x1 = *(const float4*)&xl[(size_t)s1 * HC + c0];
      // ---- edge 0 -> stream A ----
      {
        float m0 = x0.x + xrd.x + a0.x * we0.x + a0.y * we1.x + a0.z * we2.x + a0.w * we3.x;
        float m1 = x0.y + xrd.y + a0.x * we0.y + a0.y * we1.y + a0.z * we2.y + a0.w * we3.y;
        float m2 = x0.z + xrd.z + a0.x * we0.z + a0.y * we1.z + a0.z * we2.z + a0.w * we3.z;
        float m3 = x0.w + xrd.w + a0.x * we0.w + a0.y * we1.w + a0.z * we2.w + a0.w * we3.w;
        m0 = (m0 > 0.f) ? m0 : NEG_SLOPE * m0;
        m1 = (m1 > 0.f) ? m1 : NEG_SLOPE * m1;
        m2 = (m2 > 0.f) ? m2 : NEG_SLOPE * m2;
        m3 = (m3 > 0.f) ? m3 : NEG_SLOPE * m3;
        float lg = m0 * attv.x + m1 * attv.y + m2 * attv.z + m3 * attv.w;
        lg += __shfl_xor(lg, 1);
        lg += __shfl_xor(lg, 2);
        lg += __shfl_xor(lg, 4);
        lg += __shfl_xor(lg, 8);
        float nmx = fmaxf(mxA, lg);
        float sc = __expf(mxA - nmx);
        float p = __expf(lg - nmx);
        dnA = dnA * sc + p;
        aA0 = fmaf(aA0, sc, p * x0.x);
        aA1 = fmaf(aA1, sc, p * x0.y);
        aA2 = fmaf(aA2, sc, p * x0.z);
        aA3 = fmaf(aA3, sc, p * x0.w);
        mxA = nmx;
      }
      // ---- edge 1 -> stream B ----
      {
        float m0 = x1.x + xrd.x + a1.x * we0.x + a1.y * we1.x + a1.z * we2.x + a1.w * we3.x;
        float m1 = x1.y + xrd.y + a1.x * we0.y + a1.y * we1.y + a1.z * we2.y + a1.w * we3.y;
        float m2 = x1.z + xrd.z + a1.x * we0.z + a1.y * we1.z + a1.z * we2.z + a1.w * we3.z;
        float m3 = x1.w + xrd.w + a1.x * we0.w + a1.y * we1.w + a1.z * we2.w + a1.w * we3.w;
        m0 = (m0 > 0.f) ? m0 : NEG_SLOPE * m0;
        m1 = (m1 > 0.f) ? m1 : NEG_SLOPE * m1;
        m2 = (m2 > 0.f) ? m2 : NEG_SLOPE * m2;
        m3 = (m3 > 0.f) ? m3 : NEG_SLOPE * m3;
        float lg = m0 * attv.x + m1 * attv.y + m2 * attv.z + m3 * attv.w;
        lg += __shfl_xor(lg, 1);
        lg += __shfl_xor(lg, 2);
        lg += __shfl_xor(lg, 4);
        lg += __shfl_xor(lg, 8);
        float nmx = fmaxf(mxB, lg);
        float sc = __expf(mxB - nmx);
        float p = __expf(lg - nmx);
        dnB = dnB * sc + p;
        aB0 = fmaf(aB0, sc, p * x1.x);
        aB1 = fmaf(aB1, sc, p * x1.y);
        aB2 = fmaf(aB2, sc, p * x1.z);
        aB3 = fmaf(aB3, sc, p * x1.w);
        mxB = nmx;
      }
    }
    if (jj < rem) {   // tail edge -> stream A
      int s0 = __shfl(sv, jj) & 0x7fffffff;
      float4 a0 = *(const float4*)&ea_csr[(size_t)(start + base + jj) * 4];
      float4 x0 = *(const float4*)&xl[(size_t)s0 * HC + c0];
      float m0 = x0.x + xrd.x + a0.x * we0.x + a0.y * we1.x + a0.z * we2.x + a0.w * we3.x;
      float m1 = x0.y + xrd.y + a0.x * we0.y + a0.y * we1.y + a0.z * we2.y + a0.w * we3.y;
      float m2 = x0.z + xrd.z + a0.x * we0.z + a0.y * we1.z + a0.z * we2.z + a0.w * we3.z;
      float m3 = x0.w + xrd.w + a0.x * we0.w + a0.y * we1.w + a0.z * we2.w + a0.w * we3.w;
      m0 = (m0 > 0.f) ? m0 : NEG_SLOPE * m0;
      m1 = (m1 > 0.f) ? m1 : NEG_SLOPE * m1;
      m2 = (m2 > 0.f) ? m2 : NEG_SLOPE * m2;
      m3 = (m3 > 0.f) ? m3 : NEG_SLOPE * m3;
      float lg = m0 * attv.x + m1 * attv.y + m2 * attv.z + m3 * attv.w;
      lg += __shfl_xor(lg, 1);
      lg += __shfl_xor(lg, 2);
      lg += __shfl_xor(lg, 4);
      lg += __shfl_xor(lg, 8);
      float nmx = fmaxf(mxA, lg);
      float sc = __expf(mxA - nmx);
      float p = __expf(lg - nmx);
      dnA = dnA * sc + p;
      aA0 = fmaf(aA0, sc, p * x0.x);
      aA1 = fmaf(aA1, sc, p * x0.y);
      aA2 = fmaf(aA2, sc, p * x0.z);
      aA3 = fmaf(aA3, sc, p * x0.w);
      mxA = nmx;
    }
  }

  // merge streams
  float m = fmaxf(mxA, mxB);
  float sA = __expf(mxA - m), sB = __expf(mxB - m);
  float dn = dnA * sA + dnB * sB;
  float rinv = 1.f / dn;
  float acc0 = (aA0 * sA + aB0 * sB) * rinv;
  float acc1 = (aA1 * sA + aB1 * sB) * rinv;
  float acc2 = (aA2 * sA + aB2 * sB) * rinv;
  float acc3 = (aA3 * sA + aB3 * sB) * rinv;

  const float inv_sqrt = rsqrtf(1.f + BN_EPS);
  if (CONCAT) {
    float4 bi = *(const float4*)&bias[c0];
    float4 g = *(const float4*)&bng[c0];
    float4 bb = *(const float4*)&bnb[c0];
    float v0 = (acc0 + bi.x) * (g.x * inv_sqrt) + bb.x;
    float v1 = (acc1 + bi.y) * (g.y * inv_sqrt) + bb.y;
    float v2 = (acc2 + bi.z) * (g.z * inv_sqrt) + bb.z;
    float v3 = (acc3 + bi.w) * (g.w * inv_sqrt) + bb.w;
    v0 = (v0 > 0.f) ? v0 : (__expf(v0) - 1.f);
    v1 = (v1 > 0.f) ? v1 : (__expf(v1) - 1.f);
    v2 = (v2 > 0.f) ? v2 : (__expf(v2) - 1.f);
    v3 = (v3 > 0.f) ? v3 : (__expf(v3) - 1.f);
    float4 o = {v0, v1, v2, v3};
    *(float4*)&outp[(size_t)i * HC + c0] = o;
  } else {
    // mean over heads: sum lanes {l, l^16, l^32, l^48} (acc already normalized)
    acc0 += __shfl_xor(acc0, 16); acc0 += __shfl_xor(acc0, 32);
    acc1 += __shfl_xor(acc1, 16); acc1 += __shfl_xor(acc1, 32);
    acc2 += __shfl_xor(acc2, 16); acc2 += __shfl_xor(acc2, 32);
    acc3 += __shfl_xor(acc3, 16); acc3 += __shfl_xor(acc3, 32);
    if (lane < 16) {
      int cc = lane * 4;
      float4 bi = *(const float4*)&bias[cc];
      float4 g = *(const float4*)&bng[cc];
      float4 bb = *(const float4*)&bnb[cc];
      float v0 = (0.25f * acc0 + bi.x) * (g.x * inv_sqrt) + bb.x;
      float v1 = (0.25f * acc1 + bi.y) * (g.y * inv_sqrt) + bb.y;
      float v2 = (0.25f * acc2 + bi.z) * (g.z * inv_sqrt) + bb.z;
      float v3 = (0.25f * acc3 + bi.w) * (g.w * inv_sqrt) + bb.w;
      v0 = (v0 > 0.f) ? v0 : (__expf(v0) - 1.f);
      v1 = (v1 > 0.f) ? v1 : (__expf(v1) - 1.f);
      v2 = (v2 > 0.f) ? v2 : (__expf(v2) - 1.f);
      v3 = (v3 > 0.f) ? v3 : (__expf(v3) - 1.f);
      float4 o = {v0, v1, v2, v3};
      *(float4*)&outp[(size_t)i * 64 + cc] = o;
    }
  }
}

// ------------------------------------------------------------------
// K8: fused SAGE: h3 = relu(bn3(mean_agg@wl + bl + h2@wr))  (1 wave/node)
__global__ __launch_bounds__(256) void k_sage(
    const float* __restrict__ h2, const int* __restrict__ row_ptr,
    const int* __restrict__ srcs, const unsigned* __restrict__ cnt,
    const float* __restrict__ wl, const float* __restrict__ bl,
    const float* __restrict__ wr, const float* __restrict__ bng,
    const float* __restrict__ bnb, float* __restrict__ h3) {
  __shared__ float agg_s[4][64];
  __shared__ float h2_s[4][64];
  int lane = threadIdx.x & 63;
  int w = threadIdx.x >> 6;
  int i = blockIdx.x * 4 + w;
  int start = row_ptr[i], end = row_ptr[i + 1];
  float a = 0.f;
  for (int j = start; j < end; ++j) {
    int sv = srcs[j];
    if (sv >= 0) a += h2[(size_t)sv * 64 + lane];   // skip self-loop slots
  }
  float c = (float)cnt[i];
  if (c < 1.f) c = 1.f;
  agg_s[w][lane] = a / c;
  h2_s[w][lane] = h2[(size_t)i * 64 + lane];
  __syncthreads();
  float s = bl[lane];
  #pragma unroll 4
  for (int k = 0; k < 64; k++)
    s += agg_s[w][k] * wl[k * 64 + lane] + h2_s[w][k] * wr[k * 64 + lane];
  s = s * (bng[lane] * rsqrtf(1.f + BN_EPS)) + bnb[lane];
  s = fmaxf(s, 0.f);
  h3[(size_t)i * 64 + lane] = s;
}

// ------------------------------------------------------------------
// K9: pooling: per-graph sum / max / count
__global__ __launch_bounds__(256) void k_pool(
    const float* __restrict__ h3, const int* __restrict__ batch,
    float* __restrict__ psum, float* __restrict__ pmax, float* __restrict__ pcnt) {
  int j = threadIdx.x & 63, grp = threadIdx.x >> 6;
  int nbase = blockIdx.x * 256 + grp * 64;
  float s = 0.f, m = 0.f, cn = 0.f;
  int cur = -1;
  for (int t = 0; t < 64; t++) {
    int n = nbase + t;
    if (n >= NN) break;
    int g = batch[n];
    if (g != cur) {
      if (cur >= 0) {
        atomicAdd(&psum[cur * 64 + j], s);
        atomicMax((int*)&pmax[cur * 64 + j], __float_as_int(m));
        if (j == 0) atomicAdd(&pcnt[cur], cn);
      }
      cur = g; s = 0.f; m = 0.f; cn = 0.f;
    }
    float v = h3[(size_t)n * 64 + j];
    s += v; m = fmaxf(m, v); cn += 1.f;
  }
  if (cur >= 0) {
    atomicAdd(&psum[cur * 64 + j], s);
    atomicMax((int*)&pmax[cur * 64 + j], __float_as_int(m));
    if (j == 0) atomicAdd(&pcnt[cur], cn);
  }
}

// ------------------------------------------------------------------
// K10: graph head (block per graph, 64 threads)
__global__ void k_graph_head(
    const float* __restrict__ psum, const float* __restrict__ pmax,
    const float* __restrict__ pcnt,
    const float* __restrict__ w1, const float* __restrict__ b1,
    const float* __restrict__ w2, const float* __restrict__ b2,
    const float* __restrict__ w3, const float* __restrict__ b3,
    float* __restrict__ out) {
  __shared__ float hp[128];
  __shared__ float z1[64];
  __shared__ float z2[32];
  int g = blockIdx.x, j = threadIdx.x;
  float c = pcnt[g];
  if (c < 1.f) c = 1.f;
  hp[j] = psum[g * 64 + j] / c;
  hp[64 + j] = pmax[g * 64 + j];
  __syncthreads();
  float s = b1[j];
  #pragma unroll 8
  for (int k = 0; k < 128; k++) s += hp[k] * w1[k * 64 + j];
  z1[j] = fmaxf(s, 0.f);
  __syncthreads();
  if (j < 32) {
    float s2 = b2[j];
    #pragma unroll 8
    for (int k = 0; k < 64; k++) s2 += z1[k] * w2[k * 32 + j];
    z2[j] = fmaxf(s2, 0.f);
  }
  __syncthreads();
  if (j == 0) {
    float s3 = b3[0];
    #pragma unroll
    for (int k = 0; k < 32; k++) s3 += z2[k] * w3[k];
    out[g] = 1.f / (1.f + expf(-s3));
  }
}

// ------------------------------------------------------------------
// K11: edge head (thread per edge; weights read lane-uniform -> s_load)
__global__ __launch_bounds__(256) void k_edge_head(
    const float* __restrict__ h3, const int* __restrict__ ei,
    const float* __restrict__ ea,
    const float* __restrict__ w1, const float* __restrict__ b1,
    const float* __restrict__ w2, const float* __restrict__ b2,
    float* __restrict__ out) {
  int e = blockIdx.x * 256 + threadIdx.x;
  if (e >= NE) return;
  int s = ei[e], d = ei[NE + e];
  float acc[32];
  #pragma unroll
  for (int j = 0; j < 32; j++) acc[j] = b1[j];
  const float4* hs = (const float4*)&h3[(size_t)s * 64];
  const float4* hd = (const float4*)&h3[(size_t)d * 64];
  for (int k4 = 0; k4 < 16; k4++) {
    float4 v = hs[k4];
    const float* w = &w1[k4 * 4 * 32];
    #pragma unroll
    for (int j = 0; j < 32; j++) acc[j] += v.x * w[j];
    #pragma unroll
    for (int j = 0; j < 32; j++) acc[j] += v.y * w[32 + j];
    #pragma unroll
    for (int j = 0; j < 32; j++) acc[j] += v.z * w[64 + j];
    #pragma unroll
    for (int j = 0; j < 32; j++) acc[j] += v.w * w[96 + j];
  }
  for (int k4 = 0; k4 < 16; k4++) {
    float4 v = hd[k4];
    const float* w = &w1[(64 + k4 * 4) * 32];
    #pragma unroll
    for (int j = 0; j < 32; j++) acc[j] += v.x * w[j];
    #pragma unroll
    for (int j = 0; j < 32; j++) acc[j] += v.y * w[32 + j];
    #pragma unroll
    for (int j = 0; j < 32; j++) acc[j] += v.z * w[64 + j];
    #pragma unroll
    for (int j = 0; j < 32; j++) acc[j] += v.w * w[96 + j];
  }
  {
    float4 v = *(const float4*)&ea[(size_t)e * 4];
    const float* w = &w1[128 * 32];
    #pragma unroll
    for (int j = 0; j < 32; j++) acc[j] += v.x * w[j];
    #pragma unroll
    for (int j = 0; j < 32; j++) acc[j] += v.y * w[32 + j];
    #pragma unroll
    for (int j = 0; j < 32; j++) acc[j] += v.z * w[64 + j];
    #pragma unroll
    for (int j = 0; j < 32; j++) acc[j] += v.w * w[96 + j];
  }
  float s2 = b2[0];
  #pragma unroll
  for (int j = 0; j < 32; j++) s2 += fmaxf(acc[j], 0.f) * w2[j];
  out[e] = 1.f / (1.f + expf(-s2));
}

// ------------------------------------------------------------------
extern "C" void kernel_launch(void* const* d_in, const int* in_sizes, int n_in,
                              void* d_out, int out_size, void* d_ws, size_t ws_size,
                              hipStream_t stream) {
  const float* x         = (const float*)d_in[0];
  const float* edge_attr = (const float*)d_in[1];
  const float* enc_w1 = (const float*)d_in[2];
  const float* enc_b1 = (const float*)d_in[3];
  const float* enc_w2 = (const float*)d_in[4];
  const float* enc_b2 = (const float*)d_in[5];
  const float* g1_wl = (const float*)d_in[6];
  const float* g1_wr = (const float*)d_in[7];
  const float* g1_we = (const float*)d_in[8];
  const float* g1_att = (const float*)d_in[9];
  const float* g1_b = (const float*)d_in[10];
  const float* bn1_g = (const float*)d_in[11];
  const float* bn1_b = (const float*)d_in[12];
  const float* g2_wl = (const float*)d_in[13];
  const float* g2_wr = (const float*)d_in[14];
  const float* g2_we = (const float*)d_in[15];
  const float* g2_att = (const float*)d_in[16];
  const float* g2_b = (const float*)d_in[17];
  const float* bn2_g = (const float*)d_in[18];
  const float* bn2_b = (const float*)d_in[19];
  const float* sage_wl = (const float*)d_in[20];
  const float* sage_bl = (const float*)d_in[21];
  const float* sage_wr = (const float*)d_in[22];
  const float* bn3_g = (const float*)d_in[23];
  const float* bn3_b = (const float*)d_in[24];
  const float* gh_w1 = (const float*)d_in[25];
  const float* gh_b1 = (const float*)d_in[26];
  const float* gh_w2 = (const float*)d_in[27];
  const float* gh_b2 = (const float*)d_in[28];
  const float* gh_w3 = (const float*)d_in[29];
  const float* gh_b3 = (const float*)d_in[30];
  const float* eh_w1 = (const float*)d_in[31];
  const float* eh_b1 = (const float*)d_in[32];
  const float* eh_w2 = (const float*)d_in[33];
  const float* eh_b2 = (const float*)d_in[34];
  const int* ei    = (const int*)d_in[35];
  const int* batch = (const int*)d_in[36];
  float* out = (float*)d_out;

  float* ws = (float*)d_ws;
  float* xl = ws + OFF_XL;
  float* xr = ws + OFF_XR;
  float* h1 = ws + OFF_H1;
  float* h0 = ws + OFF_H0;   // later h2
  float* h3 = ws + OFF_H3;
  float* la = ws + OFF_LA;
  unsigned* cnt = (unsigned*)(ws + OFF_CNT);
  float* psum = ws + OFF_PSUM;
  float* pmax = ws + OFF_PMAX;
  float* pcnt = ws + OFF_PCNT;
  float* ea_csr = ws + OFF_EACSR;
  int* row_ptr = (int*)(ws + OFF_RP);
  int* pos = (int*)(ws + OFF_POS);
  int* srcs = (int*)(ws + OFF_SRC);
  int* bsums = (int*)(ws + OFF_BSUM);

  hipMemsetAsync(ws + OFF_ZERO, 0, ZERO_FLOATS * sizeof(float), stream);

  k_edge_stats<<<NE / 256, 256, 0, stream>>>(ei, edge_attr, la, cnt);
  k_loop_finalize<<<(NN * 4 + 255) / 256, 256, 0, stream>>>(la, cnt);
  k_encoder<<<NN / (4 * ENC_NPW), 256, 0, stream>>>(x, enc_w1, enc_b1, enc_w2, enc_b2, h0);
  k_scan_blk<<<SCAN_NB, 256, 0, stream>>>(cnt, row_ptr, bsums);
  k_scan_add<<<SCAN_NB, 256, 0, stream>>>(bsums, row_ptr, pos);
  k_csr_scatter<<<(EP + 255) / 256, 256, 0, stream>>>(ei, pos, edge_attr, la, srcs, ea_csr);

  // ---- GAT layer 1 ----
  k_gemm256<64><<<NN / 32, 256, 0, stream>>>(h0, g1_wl, xl);
  k_gemm256<64><<<NN / 32, 256, 0, stream>>>(h0, g1_wr, xr);
  k_gat_fused<1><<<NN / 4, 256, 0, stream>>>(xl, xr, g1_we, g1_att, srcs, ea_csr,
                                             row_ptr, g1_b, bn1_g, bn1_b, h1);

  // ---- GAT layer 2 ----
  k_gemm256<256><<<NN / 32, 256, 0, stream>>>(h1, g2_wl, xl);
  k_gemm256<256><<<NN / 32, 256, 0, stream>>>(h1, g2_wr, xr);
  k_gat_fused<0><<<NN / 4, 256, 0, stream>>>(xl, xr, g2_we, g2_att, srcs, ea_csr,
                                             row_ptr, g2_b, bn2_g, bn2_b, h0);

  // ---- SAGE ----
  k_sage<<<NN / 4, 256, 0, stream>>>(h0, row_ptr, srcs, cnt, sage_wl, sage_bl, sage_wr, bn3_g, bn3_b, h3);

  // ---- pooling + heads ----
  k_pool<<<(NN + 255) / 256, 256, 0, stream>>>(h3, batch, psum, pmax, pcnt);
  k_graph_head<<<NG, 64, 0, stream>>>(psum, pmax, pcnt, gh_w1, gh_b1, gh_w2, gh_b2, gh_w3, gh_b3, out);
  k_edge_head<<<NE / 256, 256, 0, stream>>>(h3, ei, edge_attr, eh_w1, eh_b1, eh_w2, eh_b2, out + NG);
}

// Round 6
// 441.642 us; speedup vs baseline: 2.3400x; 1.1597x over previous
//
#include <hip/hip_runtime.h>

#define NN 20000
#define NE 320000
#define EP (NE + NN)          // 340000 edges incl. self loops
#define NG 8
#define HC 256
#define NODE_IN 18
#define HID 64
#define NEG_SLOPE 0.2f
#define BN_EPS 1e-5f

// ---------------- workspace layout (float offsets) ----------------
#define OFF_XL    0u                      // [NN*256]  (also rank[NE] during CSR build)
#define OFF_XR    5120000u                // [NN*256]
#define OFF_H1    10240000u               // [NN*256]
#define OFF_H0    15360000u               // [NN*64]  (h0, later reused as h2)
#define OFF_H3    16640000u               // [NN*64]
#define OFF_ZERO  18000000u               // start of zeroed region
#define OFF_CNT   18000000u               // uint cnt [NN]
#define OFF_PSUM  18020000u               // [8*64]
#define OFF_PMAX  18020512u               // [8*64]
#define OFF_PCNT  18021024u               // [16]
#define ZERO_FLOATS (18021040u - 18000000u)
#define OFF_EACSR 18021040u               // float4-aligned: [EP*4] CSR-ordered edge attrs
#define OFF_RP    19381040u               // int [NN+1]
#define OFF_SRC   19421041u               // int [EP]  (sign bit = self-loop flag)
#define OFF_BSUM  19761056u               // int [32] block sums for scan

#define SCAN_ELEM 1024
#define SCAN_NB ((NN + SCAN_ELEM - 1) / SCAN_ELEM)   // 20

// ------------------------------------------------------------------
// K1: per-dst edge count; returned old value = rank of edge within its dst row.
__global__ __launch_bounds__(256) void k_count(
    const int* __restrict__ ei, unsigned* __restrict__ cnt, int* __restrict__ rank) {
  int e = blockIdx.x * 256 + threadIdx.x;
  if (e >= NE) return;
  int d = ei[NE + e];
  rank[e] = (int)atomicAdd(&cnt[d], 1u);
}

// ------------------------------------------------------------------
// K3: encoder, wave-per-node (lane = channel).
#define ENC_NPW 4   // nodes per wave
__global__ __launch_bounds__(256) void k_encoder(
    const float* __restrict__ x, const float* __restrict__ w1, const float* __restrict__ b1,
    const float* __restrict__ w2, const float* __restrict__ b2, float* __restrict__ h0) {
  __shared__ float W1[NODE_IN * HID];
  __shared__ float W2[HID * HID];
  __shared__ float B1s[HID];
  __shared__ float B2s[HID];
  __shared__ float hid_s[4][HID];
  const int tid = threadIdx.x;
  for (int i = tid; i < NODE_IN * HID; i += 256) W1[i] = w1[i];
  for (int i = tid; i < HID * HID; i += 256) W2[i] = w2[i];
  if (tid < HID) { B1s[tid] = b1[tid]; B2s[tid] = b2[tid]; }
  __syncthreads();
  const int lane = tid & 63;
  const int w = tid >> 6;
  #pragma unroll
  for (int t = 0; t < ENC_NPW; t++) {
    const int n = blockIdx.x * (4 * ENC_NPW) + w * ENC_NPW + t;
    const float* xp = &x[(size_t)n * NODE_IN];
    float s = B1s[lane];
    #pragma unroll
    for (int i = 0; i < NODE_IN; i++) s += xp[i] * W1[i * HID + lane];
    hid_s[w][lane] = fmaxf(s, 0.f);       // same-wave write->read, lockstep safe
    float o = B2s[lane];
    #pragma unroll 8
    for (int k = 0; k < HID; k++) o += hid_s[w][k] * W2[k * HID + lane];
    h0[(size_t)n * HID + lane] = o;
  }
}

// ------------------------------------------------------------------
// K_scan_blk: per-block scan of (cnt[i]+1), 1024 elems/block, local prefixes
// into row_ptr, block totals into bsums.  ONE barrier.
__global__ __launch_bounds__(256) void k_scan_blk(
    const unsigned* __restrict__ cnt, int* __restrict__ row_ptr, int* __restrict__ bsums) {
  __shared__ int wsum[4];
  const int tid = threadIdx.x, lane = tid & 63, w = tid >> 6;
  const int i0 = blockIdx.x * SCAN_ELEM + tid * 4;
  int v0 = (i0 + 0 < NN) ? ((int)cnt[i0 + 0] + 1) : 0;
  int v1 = (i0 + 1 < NN) ? ((int)cnt[i0 + 1] + 1) : 0;
  int v2 = (i0 + 2 < NN) ? ((int)cnt[i0 + 2] + 1) : 0;
  int v3 = (i0 + 3 < NN) ? ((int)cnt[i0 + 3] + 1) : 0;
  int tsum = v0 + v1 + v2 + v3;
  int incl = tsum;
  #pragma unroll
  for (int off = 1; off < 64; off <<= 1) {
    int t = __shfl_up(incl, off);
    if (lane >= off) incl += t;
  }
  if (lane == 63) wsum[w] = incl;
  __syncthreads();
  int p = incl - tsum;                  // exclusive within wave
  #pragma unroll
  for (int k = 0; k < 4; k++) if (k < w) p += wsum[k];
  if (i0 + 0 < NN) row_ptr[i0 + 0] = p;
  if (i0 + 1 < NN) row_ptr[i0 + 1] = p + v0;
  if (i0 + 2 < NN) row_ptr[i0 + 2] = p + v0 + v1;
  if (i0 + 3 < NN) row_ptr[i0 + 3] = p + v0 + v1 + v2;
  if (tid == 0) bsums[blockIdx.x] = wsum[0] + wsum[1] + wsum[2] + wsum[3];
}

// K_scan_add: add cross-block offset in place; row_ptr[NN]=EP.
__global__ __launch_bounds__(256) void k_scan_add(
    const int* __restrict__ bsums, int* __restrict__ row_ptr) {
  const int b = blockIdx.x, tid = threadIdx.x;
  int off = 0;
  for (int j = 0; j < b; j++) off += bsums[j];
  const int i0 = b * SCAN_ELEM + tid * 4;
  #pragma unroll
  for (int k = 0; k < 4; k++) {
    int i = i0 + k;
    if (i < NN) row_ptr[i] += off;
  }
  if (b == 0 && tid == 0) row_ptr[NN] = EP;
}

// K_scatter: atomic-free CSR scatter: slot = row_ptr[d] + rank[e].
__global__ __launch_bounds__(256) void k_csr_scatter(
    const int* __restrict__ ei, const int* __restrict__ rank,
    const int* __restrict__ row_ptr, const float* __restrict__ ea,
    int* __restrict__ srcs, float* __restrict__ ea_csr) {
  int e = blockIdx.x * 256 + threadIdx.x;
  if (e >= NE) return;
  int s = ei[e], d = ei[NE + e];
  int p = row_ptr[d] + rank[e];
  srcs[p] = s;
  *(float4*)&ea_csr[(size_t)p * 4] = *(const float4*)&ea[(size_t)e * 4];
}

// K_loop_row: per node, self-loop attr = mean of row's real-edge attrs,
// written into the row's last (reserved) slot.  No atomics.
__global__ __launch_bounds__(256) void k_loop_row(
    const int* __restrict__ row_ptr, int* __restrict__ srcs, float* __restrict__ ea_csr) {
  int i = blockIdx.x * 256 + threadIdx.x;
  if (i >= NN) return;
  int start = row_ptr[i], last = row_ptr[i + 1] - 1;
  float sx = 0.f, sy = 0.f, sz = 0.f, sw = 0.f;
  for (int j = start; j < last; ++j) {
    float4 a = *(const float4*)&ea_csr[(size_t)j * 4];
    sx += a.x; sy += a.y; sz += a.z; sw += a.w;
  }
  float c = (float)(last - start);
  if (c < 1.f) c = 1.f;
  float rc = 1.f / c;
  float4 o = {sx * rc, sy * rc, sz * rc, sw * rc};
  *(float4*)&ea_csr[(size_t)last * 4] = o;
  srcs[last] = i | (int)0x80000000;
}

// ------------------------------------------------------------------
// K4: OUT[NN][256] = A[NN][K] @ W[K][256]  (32 nodes x 256 cols / block)
template <int K>
__global__ __launch_bounds__(256) void k_gemm256(
    const float* __restrict__ A, const float* __restrict__ W, float* __restrict__ OUT) {
  __shared__ float Wl[32 * 256];
  __shared__ float Al[32 * 36];
  const int tid = threadIdx.x;
  const int n0 = blockIdx.x * 32;
  const int tx = tid & 63, ty = tid >> 6;
  float acc[8][4];
  #pragma unroll
  for (int m = 0; m < 8; m++)
    #pragma unroll
    for (int c = 0; c < 4; c++) acc[m][c] = 0.f;

  for (int kt = 0; kt < K; kt += 32) {
    #pragma unroll
    for (int r = 0; r < 8; r++) {
      int i4 = tid + 256 * r;
      int row = i4 >> 6;
      int col4 = (i4 & 63) * 4;
      *(float4*)&Wl[row * 256 + col4] = *(const float4*)&W[(size_t)(kt + row) * 256 + col4];
    }
    {
      int m = tid >> 3, kk = (tid & 7) * 4;
      float4 av = *(const float4*)&A[(size_t)(n0 + m) * K + kt + kk];
      Al[(kk + 0) * 36 + m] = av.x;
      Al[(kk + 1) * 36 + m] = av.y;
      Al[(kk + 2) * 36 + m] = av.z;
      Al[(kk + 3) * 36 + m] = av.w;
    }
    __syncthreads();
    #pragma unroll 8
    for (int k = 0; k < 32; k++) {
      float4 b = *(float4*)&Wl[k * 256 + tx * 4];
      float4 a0v = *(float4*)&Al[k * 36 + ty * 8];
      float4 a1v = *(float4*)&Al[k * 36 + ty * 8 + 4];
      float am[8] = {a0v.x, a0v.y, a0v.z, a0v.w, a1v.x, a1v.y, a1v.z, a1v.w};
      #pragma unroll
      for (int m = 0; m < 8; m++) {
        acc[m][0] += am[m] * b.x;
        acc[m][1] += am[m] * b.y;
        acc[m][2] += am[m] * b.z;
        acc[m][3] += am[m] * b.w;
      }
    }
    __syncthreads();
  }
  #pragma unroll
  for (int m = 0; m < 8; m++) {
    float4 o = {acc[m][0], acc[m][1], acc[m][2], acc[m][3]};
    *(float4*)&OUT[(size_t)(n0 + ty * 8 + m) * 256 + tx * 4] = o;
  }
}

// ------------------------------------------------------------------
// K5: fused GATv2, ONE pass: logits + online softmax + aggregation + epilogue.
// 1 wave / node, lane owns channels c = 4*lane..4*lane+3 (head = lane>>4).
// Dual independent online accumulators (A/B) for 2 gathers in flight.
template <int CONCAT>
__global__ __launch_bounds__(256) void k_gat_fused(
    const float* __restrict__ xl, const float* __restrict__ xr,
    const float* __restrict__ we, const float* __restrict__ att,
    const int* __restrict__ srcs, const float* __restrict__ ea_csr,
    const int* __restrict__ row_ptr,
    const float* __restrict__ bias, const float* __restrict__ bng,
    const float* __restrict__ bnb, float* __restrict__ outp) {
  const int lane = threadIdx.x & 63;
  const int w = threadIdx.x >> 6;
  const int i = blockIdx.x * 4 + w;
  const int c0 = lane * 4;

  const float4 attv = *(const float4*)&att[c0];
  const float4 we0 = *(const float4*)&we[0 * HC + c0];
  const float4 we1 = *(const float4*)&we[1 * HC + c0];
  const float4 we2 = *(const float4*)&we[2 * HC + c0];
  const float4 we3 = *(const float4*)&we[3 * HC + c0];
  const float4 xrd = *(const float4*)&xr[(size_t)i * HC + c0];

  const int start = row_ptr[i];
  const int deg = row_ptr[i + 1] - start;

  float mxA = -1e30f, dnA = 0.f, aA0 = 0.f, aA1 = 0.f, aA2 = 0.f, aA3 = 0.f;
  float mxB = -1e30f, dnB = 0.f, aB0 = 0.f, aB1 = 0.f, aB2 = 0.f, aB3 = 0.f;

  for (int base = 0; base < deg; base += 64) {
    int rem = deg - base;
    if (rem > 64) rem = 64;
    int sv = 0;
    if (lane < rem) sv = srcs[start + base + lane];
    int jj = 0;
    for (; jj + 2 <= rem; jj += 2) {
      int s0 = __shfl(sv, jj) & 0x7fffffff;
      int s1 = __shfl(sv, jj + 1) & 0x7fffffff;
      float4 a0 = *(const float4*)&ea_csr[(size_t)(start + base + jj) * 4];
      float4 a1 = *(const float4*)&ea_csr[(size_t)(start + base + jj + 1) * 4];
      float4 x0 = *(const float4*)&xl[(size_t)s0 * HC + c0];
      float4 x1 = *(const float4*)&xl[(size_t)s1 * HC + c0];
      // ---- edge 0 -> stream A ----
      {
        float m0 = x0.x + xrd.x + a0.x * we0.x + a0.y * we1.x + a0.z * we2.x + a0.w * we3.x;
        float m1 = x0.y + xrd.y + a0.x * we0.y + a0.y * we1.y + a0.z * we2.y + a0.w * we3.y;
        float m2 = x0.z + xrd.z + a0.x * we0.z + a0.y * we1.z + a0.z * we2.z + a0.w * we3.z;
        float m3 = x0.w + xrd.w + a0.x * we0.w + a0.y * we1.w + a0.z * we2.w + a0.w * we3.w;
        m0 = (m0 > 0.f) ? m0 : NEG_SLOPE * m0;
        m1 = (m1 > 0.f) ? m1 : NEG_SLOPE * m1;
        m2 = (m2 > 0.f) ? m2 : NEG_SLOPE * m2;
        m3 = (m3 > 0.f) ? m3 : NEG_SLOPE * m3;
        float lg = m0 * attv.x + m1 * attv.y + m2 * attv.z + m3 * attv.w;
        lg += __shfl_xor(lg, 1);
        lg += __shfl_xor(lg, 2);
        lg += __shfl_xor(lg, 4);
        lg += __shfl_xor(lg, 8);
        float nmx = fmaxf(mxA, lg);
        float sc = __expf(mxA - nmx);
        float p = __expf(lg - nmx);
        dnA = dnA * sc + p;
        aA0 = fmaf(aA0, sc, p * x0.x);
        aA1 = fmaf(aA1, sc, p * x0.y);
        aA2 = fmaf(aA2, sc, p * x0.z);
        aA3 = fmaf(aA3, sc, p * x0.w);
        mxA = nmx;
      }
      // ---- edge 1 -> stream B ----
      {
        float m0 = x1.x + xrd.x + a1.x * we0.x + a1.y * we1.x + a1.z * we2.x + a1.w * we3.x;
        float m1 = x1.y + xrd.y + a1.x * we0.y + a1.y * we1.y + a1.z * we2.y + a1.w * we3.y;
        float m2 = x1.z + xrd.z + a1.x * we0.z + a1.y * we1.z + a1.z * we2.z + a1.w * we3.z;
        float m3 = x1.w + xrd.w + a1.x * we0.w + a1.y * we1.w + a1.z * we2.w + a1.w * we3.w;
        m0 = (m0 > 0.f) ? m0 : NEG_SLOPE * m0;
        m1 = (m1 > 0.f) ? m1 : NEG_SLOPE * m1;
        m2 = (m2 > 0.f) ? m2 : NEG_SLOPE * m2;
        m3 = (m3 > 0.f) ? m3 : NEG_SLOPE * m3;
        float lg = m0 * attv.x + m1 * attv.y + m2 * attv.z + m3 * attv.w;
        lg += __shfl_xor(lg, 1);
        lg += __shfl_xor(lg, 2);
        lg += __shfl_xor(lg, 4);
        lg += __shfl_xor(lg, 8);
        float nmx = fmaxf(mxB, lg);
        float sc = __expf(mxB - nmx);
        float p = __expf(lg - nmx);
        dnB = dnB * sc + p;
        aB0 = fmaf(aB0, sc, p * x1.x);
        aB1 = fmaf(aB1, sc, p * x1.y);
        aB2 = fmaf(aB2, sc, p * x1.z);
        aB3 = fmaf(aB3, sc, p * x1.w);
        mxB = nmx;
      }
    }
    if (jj < rem) {   // tail edge -> stream A
      int s0 = __shfl(sv, jj) & 0x7fffffff;
      float4 a0 = *(const float4*)&ea_csr[(size_t)(start + base + jj) * 4];
      float4 x0 = *(const float4*)&xl[(size_t)s0 * HC + c0];
      float m0 = x0.x + xrd.x + a0.x * we0.x + a0.y * we1.x + a0.z * we2.x + a0.w * we3.x;
      float m1 = x0.y + xrd.y + a0.x * we0.y + a0.y * we1.y + a0.z * we2.y + a0.w * we3.y;
      float m2 = x0.z + xrd.z + a0.x * we0.z + a0.y * we1.z + a0.z * we2.z + a0.w * we3.z;
      float m3 = x0.w + xrd.w + a0.x * we0.w + a0.y * we1.w + a0.z * we2.w + a0.w * we3.w;
      m0 = (m0 > 0.f) ? m0 : NEG_SLOPE * m0;
      m1 = (m1 > 0.f) ? m1 : NEG_SLOPE * m1;
      m2 = (m2 > 0.f) ? m2 : NEG_SLOPE * m2;
      m3 = (m3 > 0.f) ? m3 : NEG_SLOPE * m3;
      float lg = m0 * attv.x + m1 * attv.y + m2 * attv.z + m3 * attv.w;
      lg += __shfl_xor(lg, 1);
      lg += __shfl_xor(lg, 2);
      lg += __shfl_xor(lg, 4);
      lg += __shfl_xor(lg, 8);
      float nmx = fmaxf(mxA, lg);
      float sc = __expf(mxA - nmx);
      float p = __expf(lg - nmx);
      dnA = dnA * sc + p;
      aA0 = fmaf(aA0, sc, p * x0.x);
      aA1 = fmaf(aA1, sc, p * x0.y);
      aA2 = fmaf(aA2, sc, p * x0.z);
      aA3 = fmaf(aA3, sc, p * x0.w);
      mxA = nmx;
    }
  }

  // merge streams
  float m = fmaxf(mxA, mxB);
  float sA = __expf(mxA - m), sB = __expf(mxB - m);
  float dn = dnA * sA + dnB * sB;
  float rinv = 1.f / dn;
  float acc0 = (aA0 * sA + aB0 * sB) * rinv;
  float acc1 = (aA1 * sA + aB1 * sB) * rinv;
  float acc2 = (aA2 * sA + aB2 * sB) * rinv;
  float acc3 = (aA3 * sA + aB3 * sB) * rinv;

  const float inv_sqrt = rsqrtf(1.f + BN_EPS);
  if (CONCAT) {
    float4 bi = *(const float4*)&bias[c0];
    float4 g = *(const float4*)&bng[c0];
    float4 bb = *(const float4*)&bnb[c0];
    float v0 = (acc0 + bi.x) * (g.x * inv_sqrt) + bb.x;
    float v1 = (acc1 + bi.y) * (g.y * inv_sqrt) + bb.y;
    float v2 = (acc2 + bi.z) * (g.z * inv_sqrt) + bb.z;
    float v3 = (acc3 + bi.w) * (g.w * inv_sqrt) + bb.w;
    v0 = (v0 > 0.f) ? v0 : (__expf(v0) - 1.f);
    v1 = (v1 > 0.f) ? v1 : (__expf(v1) - 1.f);
    v2 = (v2 > 0.f) ? v2 : (__expf(v2) - 1.f);
    v3 = (v3 > 0.f) ? v3 : (__expf(v3) - 1.f);
    float4 o = {v0, v1, v2, v3};
    *(float4*)&outp[(size_t)i * HC + c0] = o;
  } else {
    // mean over heads: sum lanes {l, l^16, l^32, l^48} (acc already normalized)
    acc0 += __shfl_xor(acc0, 16); acc0 += __shfl_xor(acc0, 32);
    acc1 += __shfl_xor(acc1, 16); acc1 += __shfl_xor(acc1, 32);
    acc2 += __shfl_xor(acc2, 16); acc2 += __shfl_xor(acc2, 32);
    acc3 += __shfl_xor(acc3, 16); acc3 += __shfl_xor(acc3, 32);
    if (lane < 16) {
      int cc = lane * 4;
      float4 bi = *(const float4*)&bias[cc];
      float4 g = *(const float4*)&bng[cc];
      float4 bb = *(const float4*)&bnb[cc];
      float v0 = (0.25f * acc0 + bi.x) * (g.x * inv_sqrt) + bb.x;
      float v1 = (0.25f * acc1 + bi.y) * (g.y * inv_sqrt) + bb.y;
      float v2 = (0.25f * acc2 + bi.z) * (g.z * inv_sqrt) + bb.z;
      float v3 = (0.25f * acc3 + bi.w) * (g.w * inv_sqrt) + bb.w;
      v0 = (v0 > 0.f) ? v0 : (__expf(v0) - 1.f);
      v1 = (v1 > 0.f) ? v1 : (__expf(v1) - 1.f);
      v2 = (v2 > 0.f) ? v2 : (__expf(v2) - 1.f);
      v3 = (v3 > 0.f) ? v3 : (__expf(v3) - 1.f);
      float4 o = {v0, v1, v2, v3};
      *(float4*)&outp[(size_t)i * 64 + cc] = o;
    }
  }
}

// ------------------------------------------------------------------
// K8: fused SAGE: h3 = relu(bn3(mean_agg@wl + bl + h2@wr))  (1 wave/node)
__global__ __launch_bounds__(256) void k_sage(
    const float* __restrict__ h2, const int* __restrict__ row_ptr,
    const int* __restrict__ srcs, const unsigned* __restrict__ cnt,
    const float* __restrict__ wl, const float* __restrict__ bl,
    const float* __restrict__ wr, const float* __restrict__ bng,
    const float* __restrict__ bnb, float* __restrict__ h3) {
  __shared__ float agg_s[4][64];
  __shared__ float h2_s[4][64];
  int lane = threadIdx.x & 63;
  int w = threadIdx.x >> 6;
  int i = blockIdx.x * 4 + w;
  int start = row_ptr[i], end = row_ptr[i + 1];
  float a = 0.f;
  for (int j = start; j < end; ++j) {
    int sv = srcs[j];
    if (sv >= 0) a += h2[(size_t)sv * 64 + lane];   // skip self-loop slots
  }
  float c = (float)cnt[i];
  if (c < 1.f) c = 1.f;
  agg_s[w][lane] = a / c;
  h2_s[w][lane] = h2[(size_t)i * 64 + lane];
  __syncthreads();
  float s = bl[lane];
  #pragma unroll 4
  for (int k = 0; k < 64; k++)
    s += agg_s[w][k] * wl[k * 64 + lane] + h2_s[w][k] * wr[k * 64 + lane];
  s = s * (bng[lane] * rsqrtf(1.f + BN_EPS)) + bnb[lane];
  s = fmaxf(s, 0.f);
  h3[(size_t)i * 64 + lane] = s;
}

// ------------------------------------------------------------------
// K9: pooling: per-graph sum / max / count
__global__ __launch_bounds__(256) void k_pool(
    const float* __restrict__ h3, const int* __restrict__ batch,
    float* __restrict__ psum, float* __restrict__ pmax, float* __restrict__ pcnt) {
  int j = threadIdx.x & 63, grp = threadIdx.x >> 6;
  int nbase = blockIdx.x * 256 + grp * 64;
  float s = 0.f, m = 0.f, cn = 0.f;
  int cur = -1;
  for (int t = 0; t < 64; t++) {
    int n = nbase + t;
    if (n >= NN) break;
    int g = batch[n];
    if (g != cur) {
      if (cur >= 0) {
        atomicAdd(&psum[cur * 64 + j], s);
        atomicMax((int*)&pmax[cur * 64 + j], __float_as_int(m));
        if (j == 0) atomicAdd(&pcnt[cur], cn);
      }
      cur = g; s = 0.f; m = 0.f; cn = 0.f;
    }
    float v = h3[(size_t)n * 64 + j];
    s += v; m = fmaxf(m, v); cn += 1.f;
  }
  if (cur >= 0) {
    atomicAdd(&psum[cur * 64 + j], s);
    atomicMax((int*)&pmax[cur * 64 + j], __float_as_int(m));
    if (j == 0) atomicAdd(&pcnt[cur], cn);
  }
}

// ------------------------------------------------------------------
// K10: graph head (block per graph, 64 threads)
__global__ void k_graph_head(
    const float* __restrict__ psum, const float* __restrict__ pmax,
    const float* __restrict__ pcnt,
    const float* __restrict__ w1, const float* __restrict__ b1,
    const float* __restrict__ w2, const float* __restrict__ b2,
    const float* __restrict__ w3, const float* __restrict__ b3,
    float* __restrict__ out) {
  __shared__ float hp[128];
  __shared__ float z1[64];
  __shared__ float z2[32];
  int g = blockIdx.x, j = threadIdx.x;
  float c = pcnt[g];
  if (c < 1.f) c = 1.f;
  hp[j] = psum[g * 64 + j] / c;
  hp[64 + j] = pmax[g * 64 + j];
  __syncthreads();
  float s = b1[j];
  #pragma unroll 8
  for (int k = 0; k < 128; k++) s += hp[k] * w1[k * 64 + j];
  z1[j] = fmaxf(s, 0.f);
  __syncthreads();
  if (j < 32) {
    float s2 = b2[j];
    #pragma unroll 8
    for (int k = 0; k < 64; k++) s2 += z1[k] * w2[k * 32 + j];
    z2[j] = fmaxf(s2, 0.f);
  }
  __syncthreads();
  if (j == 0) {
    float s3 = b3[0];
    #pragma unroll
    for (int k = 0; k < 32; k++) s3 += z2[k] * w3[k];
    out[g] = 1.f / (1.f + expf(-s3));
  }
}

// ------------------------------------------------------------------
// K11: edge head (thread per edge; weights read lane-uniform -> s_load)
__global__ __launch_bounds__(256) void k_edge_head(
    const float* __restrict__ h3, const int* __restrict__ ei,
    const float* __restrict__ ea,
    const float* __restrict__ w1, const float* __restrict__ b1,
    const float* __restrict__ w2, const float* __restrict__ b2,
    float* __restrict__ out) {
  int e = blockIdx.x * 256 + threadIdx.x;
  if (e >= NE) return;
  int s = ei[e], d = ei[NE + e];
  float acc[32];
  #pragma unroll
  for (int j = 0; j < 32; j++) acc[j] = b1[j];
  const float4* hs = (const float4*)&h3[(size_t)s * 64];
  const float4* hd = (const float4*)&h3[(size_t)d * 64];
  for (int k4 = 0; k4 < 16; k4++) {
    float4 v = hs[k4];
    const float* w = &w1[k4 * 4 * 32];
    #pragma unroll
    for (int j = 0; j < 32; j++) acc[j] += v.x * w[j];
    #pragma unroll
    for (int j = 0; j < 32; j++) acc[j] += v.y * w[32 + j];
    #pragma unroll
    for (int j = 0; j < 32; j++) acc[j] += v.z * w[64 + j];
    #pragma unroll
    for (int j = 0; j < 32; j++) acc[j] += v.w * w[96 + j];
  }
  for (int k4 = 0; k4 < 16; k4++) {
    float4 v = hd[k4];
    const float* w = &w1[(64 + k4 * 4) * 32];
    #pragma unroll
    for (int j = 0; j < 32; j++) acc[j] += v.x * w[j];
    #pragma unroll
    for (int j = 0; j < 32; j++) acc[j] += v.y * w[32 + j];
    #pragma unroll
    for (int j = 0; j < 32; j++) acc[j] += v.z * w[64 + j];
    #pragma unroll
    for (int j = 0; j < 32; j++) acc[j] += v.w * w[96 + j];
  }
  {
    float4 v = *(const float4*)&ea[(size_t)e * 4];
    const float* w = &w1[128 * 32];
    #pragma unroll
    for (int j = 0; j < 32; j++) acc[j] += v.x * w[j];
    #pragma unroll
    for (int j = 0; j < 32; j++) acc[j] += v.y * w[32 + j];
    #pragma unroll
    for (int j = 0; j < 32; j++) acc[j] += v.z * w[64 + j];
    #pragma unroll
    for (int j = 0; j < 32; j++) acc[j] += v.w * w[96 + j];
  }
  float s2 = b2[0];
  #pragma unroll
  for (int j = 0; j < 32; j++) s2 += fmaxf(acc[j], 0.f) * w2[j];
  out[e] = 1.f / (1.f + expf(-s2));
}

// ------------------------------------------------------------------
extern "C" void kernel_launch(void* const* d_in, const int* in_sizes, int n_in,
                              void* d_out, int out_size, void* d_ws, size_t ws_size,
                              hipStream_t stream) {
  const float* x         = (const float*)d_in[0];
  const float* edge_attr = (const float*)d_in[1];
  const float* enc_w1 = (const float*)d_in[2];
  const float* enc_b1 = (const float*)d_in[3];
  const float* enc_w2 = (const float*)d_in[4];
  const float* enc_b2 = (const float*)d_in[5];
  const float* g1_wl = (const float*)d_in[6];
  const float* g1_wr = (const float*)d_in[7];
  const float* g1_we = (const float*)d_in[8];
  const float* g1_att = (const float*)d_in[9];
  const float* g1_b = (const float*)d_in[10];
  const float* bn1_g = (const float*)d_in[11];
  const float* bn1_b = (const float*)d_in[12];
  const float* g2_wl = (const float*)d_in[13];
  const float* g2_wr = (const float*)d_in[14];
  const float* g2_we = (const float*)d_in[15];
  const float* g2_att = (const float*)d_in[16];
  const float* g2_b = (const float*)d_in[17];
  const float* bn2_g = (const float*)d_in[18];
  const float* bn2_b = (const float*)d_in[19];
  const float* sage_wl = (const float*)d_in[20];
  const float* sage_bl = (const float*)d_in[21];
  const float* sage_wr = (const float*)d_in[22];
  const float* bn3_g = (const float*)d_in[23];
  const float* bn3_b = (const float*)d_in[24];
  const float* gh_w1 = (const float*)d_in[25];
  const float* gh_b1 = (const float*)d_in[26];
  const float* gh_w2 = (const float*)d_in[27];
  const float* gh_b2 = (const float*)d_in[28];
  const float* gh_w3 = (const float*)d_in[29];
  const float* gh_b3 = (const float*)d_in[30];
  const float* eh_w1 = (const float*)d_in[31];
  const float* eh_b1 = (const float*)d_in[32];
  const float* eh_w2 = (const float*)d_in[33];
  const float* eh_b2 = (const float*)d_in[34];
  const int* ei    = (const int*)d_in[35];
  const int* batch = (const int*)d_in[36];
  float* out = (float*)d_out;

  float* ws = (float*)d_ws;
  float* xl = ws + OFF_XL;
  float* xr = ws + OFF_XR;
  float* h1 = ws + OFF_H1;
  float* h0 = ws + OFF_H0;   // later h2
  float* h3 = ws + OFF_H3;
  unsigned* cnt = (unsigned*)(ws + OFF_CNT);
  float* psum = ws + OFF_PSUM;
  float* pmax = ws + OFF_PMAX;
  float* pcnt = ws + OFF_PCNT;
  float* ea_csr = ws + OFF_EACSR;
  int* row_ptr = (int*)(ws + OFF_RP);
  int* srcs = (int*)(ws + OFF_SRC);
  int* bsums = (int*)(ws + OFF_BSUM);
  int* rank = (int*)(ws + OFF_XL);   // transient: xl region unused until GEMMs

  hipMemsetAsync(ws + OFF_ZERO, 0, ZERO_FLOATS * sizeof(float), stream);

  k_count<<<NE / 256, 256, 0, stream>>>(ei, cnt, rank);
  k_encoder<<<NN / (4 * ENC_NPW), 256, 0, stream>>>(x, enc_w1, enc_b1, enc_w2, enc_b2, h0);
  k_scan_blk<<<SCAN_NB, 256, 0, stream>>>(cnt, row_ptr, bsums);
  k_scan_add<<<SCAN_NB, 256, 0, stream>>>(bsums, row_ptr);
  k_csr_scatter<<<NE / 256, 256, 0, stream>>>(ei, rank, row_ptr, edge_attr, srcs, ea_csr);
  k_loop_row<<<(NN + 255) / 256, 256, 0, stream>>>(row_ptr, srcs, ea_csr);

  // ---- GAT layer 1 ----
  k_gemm256<64><<<NN / 32, 256, 0, stream>>>(h0, g1_wl, xl);
  k_gemm256<64><<<NN / 32, 256, 0, stream>>>(h0, g1_wr, xr);
  k_gat_fused<1><<<NN / 4, 256, 0, stream>>>(xl, xr, g1_we, g1_att, srcs, ea_csr,
                                             row_ptr, g1_b, bn1_g, bn1_b, h1);

  // ---- GAT layer 2 ----
  k_gemm256<256><<<NN / 32, 256, 0, stream>>>(h1, g2_wl, xl);
  k_gemm256<256><<<NN / 32, 256, 0, stream>>>(h1, g2_wr, xr);
  k_gat_fused<0><<<NN / 4, 256, 0, stream>>>(xl, xr, g2_we, g2_att, srcs, ea_csr,
                                             row_ptr, g2_b, bn2_g, bn2_b, h0);

  // ---- SAGE ----
  k_sage<<<NN / 4, 256, 0, stream>>>(h0, row_ptr, srcs, cnt, sage_wl, sage_bl, sage_wr, bn3_g, bn3_b, h3);

  // ---- pooling + heads ----
  k_pool<<<(NN + 255) / 256, 256, 0, stream>>>(h3, batch, psum, pmax, pcnt);
  k_graph_head<<<NG, 64, 0, stream>>>(psum, pmax, pcnt, gh_w1, gh_b1, gh_w2, gh_b2, gh_w3, gh_b3, out);
  k_edge_head<<<NE / 256, 256, 0, stream>>>(h3, ei, edge_attr, eh_w1, eh_b1, eh_w2, eh_b2, out + NG);
}

// Round 7
// 409.480 us; speedup vs baseline: 2.5238x; 1.0785x over previous
//
#include <hip/hip_runtime.h>

#define NN 20000
#define NE 320000
#define EP (NE + NN)          // 340000 edges incl. self loops
#define NG 8
#define HC 256
#define NODE_IN 18
#define HID 64
#define NEG_SLOPE 0.2f
#define BN_EPS 1e-5f

// ---------------- workspace layout (float offsets) ----------------
#define OFF_XL    0u                      // bf16 [NN*256] (=2.56M floats); also rank[NE] during CSR build
#define OFF_XR    5120000u                // [NN*256]
#define OFF_H1    10240000u               // [NN*256]
#define OFF_H0    15360000u               // [NN*64]  (h0, later reused as h2)
#define OFF_H3    16640000u               // [NN*64]
#define OFF_ZERO  18000000u               // start of zeroed region
#define OFF_CNT   18000000u               // uint cnt [NN]
#define OFF_PSUM  18020000u               // [8*64]
#define OFF_PMAX  18020512u               // [8*64]
#define OFF_PCNT  18021024u               // [16]
#define ZERO_FLOATS (18021040u - 18000000u)
#define OFF_EACSR 18021040u               // float4-aligned: [EP*4] CSR-ordered edge attrs
#define OFF_RP    19381040u               // int [NN+1]
#define OFF_SRC   19421041u               // int [EP]  (sign bit = self-loop flag; self-loop is LAST slot of row)
#define OFF_BSUM  19761056u               // int [32] block sums for scan

#define SCAN_ELEM 1024
#define SCAN_NB ((NN + SCAN_ELEM - 1) / SCAN_ELEM)   // 20

__device__ __forceinline__ ushort f2bf(float f) {   // RNE float->bf16
  unsigned u = __float_as_uint(f);
  unsigned r = (u + 0x7fffu + ((u >> 16) & 1u)) >> 16;
  return (ushort)r;
}
__device__ __forceinline__ float bf2f(ushort b) {
  return __uint_as_float(((unsigned)b) << 16);
}

// ------------------------------------------------------------------
// K1: per-dst edge count; returned old value = rank of edge within its dst row.
__global__ __launch_bounds__(256) void k_count(
    const int* __restrict__ ei, unsigned* __restrict__ cnt, int* __restrict__ rank) {
  int e = blockIdx.x * 256 + threadIdx.x;
  if (e >= NE) return;
  int d = ei[NE + e];
  rank[e] = (int)atomicAdd(&cnt[d], 1u);
}

// ------------------------------------------------------------------
// K3: encoder, wave-per-node (lane = channel).
#define ENC_NPW 4   // nodes per wave
__global__ __launch_bounds__(256) void k_encoder(
    const float* __restrict__ x, const float* __restrict__ w1, const float* __restrict__ b1,
    const float* __restrict__ w2, const float* __restrict__ b2, float* __restrict__ h0) {
  __shared__ float W1[NODE_IN * HID];
  __shared__ float W2[HID * HID];
  __shared__ float B1s[HID];
  __shared__ float B2s[HID];
  __shared__ float hid_s[4][HID];
  const int tid = threadIdx.x;
  for (int i = tid; i < NODE_IN * HID; i += 256) W1[i] = w1[i];
  for (int i = tid; i < HID * HID; i += 256) W2[i] = w2[i];
  if (tid < HID) { B1s[tid] = b1[tid]; B2s[tid] = b2[tid]; }
  __syncthreads();
  const int lane = tid & 63;
  const int w = tid >> 6;
  #pragma unroll
  for (int t = 0; t < ENC_NPW; t++) {
    const int n = blockIdx.x * (4 * ENC_NPW) + w * ENC_NPW + t;
    const float* xp = &x[(size_t)n * NODE_IN];
    float s = B1s[lane];
    #pragma unroll
    for (int i = 0; i < NODE_IN; i++) s += xp[i] * W1[i * HID + lane];
    hid_s[w][lane] = fmaxf(s, 0.f);       // same-wave write->read, lockstep safe
    float o = B2s[lane];
    #pragma unroll 8
    for (int k = 0; k < HID; k++) o += hid_s[w][k] * W2[k * HID + lane];
    h0[(size_t)n * HID + lane] = o;
  }
}

// ------------------------------------------------------------------
// K_scan_blk: per-block scan of (cnt[i]+1), 1024 elems/block.
__global__ __launch_bounds__(256) void k_scan_blk(
    const unsigned* __restrict__ cnt, int* __restrict__ row_ptr, int* __restrict__ bsums) {
  __shared__ int wsum[4];
  const int tid = threadIdx.x, lane = tid & 63, w = tid >> 6;
  const int i0 = blockIdx.x * SCAN_ELEM + tid * 4;
  int v0 = (i0 + 0 < NN) ? ((int)cnt[i0 + 0] + 1) : 0;
  int v1 = (i0 + 1 < NN) ? ((int)cnt[i0 + 1] + 1) : 0;
  int v2 = (i0 + 2 < NN) ? ((int)cnt[i0 + 2] + 1) : 0;
  int v3 = (i0 + 3 < NN) ? ((int)cnt[i0 + 3] + 1) : 0;
  int tsum = v0 + v1 + v2 + v3;
  int incl = tsum;
  #pragma unroll
  for (int off = 1; off < 64; off <<= 1) {
    int t = __shfl_up(incl, off);
    if (lane >= off) incl += t;
  }
  if (lane == 63) wsum[w] = incl;
  __syncthreads();
  int p = incl - tsum;                  // exclusive within wave
  #pragma unroll
  for (int k = 0; k < 4; k++) if (k < w) p += wsum[k];
  if (i0 + 0 < NN) row_ptr[i0 + 0] = p;
  if (i0 + 1 < NN) row_ptr[i0 + 1] = p + v0;
  if (i0 + 2 < NN) row_ptr[i0 + 2] = p + v0 + v1;
  if (i0 + 3 < NN) row_ptr[i0 + 3] = p + v0 + v1 + v2;
  if (tid == 0) bsums[blockIdx.x] = wsum[0] + wsum[1] + wsum[2] + wsum[3];
}

// K_scan_add: add cross-block offset in place; row_ptr[NN]=EP.
__global__ __launch_bounds__(256) void k_scan_add(
    const int* __restrict__ bsums, int* __restrict__ row_ptr) {
  const int b = blockIdx.x, tid = threadIdx.x;
  int off = 0;
  for (int j = 0; j < b; j++) off += bsums[j];
  const int i0 = b * SCAN_ELEM + tid * 4;
  #pragma unroll
  for (int k = 0; k < 4; k++) {
    int i = i0 + k;
    if (i < NN) row_ptr[i] += off;
  }
  if (b == 0 && tid == 0) row_ptr[NN] = EP;
}

// K_scatter: atomic-free CSR scatter: slot = row_ptr[d] + rank[e].
__global__ __launch_bounds__(256) void k_csr_scatter(
    const int* __restrict__ ei, const int* __restrict__ rank,
    const int* __restrict__ row_ptr, const float* __restrict__ ea,
    int* __restrict__ srcs, float* __restrict__ ea_csr) {
  int e = blockIdx.x * 256 + threadIdx.x;
  if (e >= NE) return;
  int s = ei[e], d = ei[NE + e];
  int p = row_ptr[d] + rank[e];
  srcs[p] = s;
  *(float4*)&ea_csr[(size_t)p * 4] = *(const float4*)&ea[(size_t)e * 4];
}

// K_loop_row: self-loop attr = mean of row's real-edge attrs, into LAST slot.
__global__ __launch_bounds__(256) void k_loop_row(
    const int* __restrict__ row_ptr, int* __restrict__ srcs, float* __restrict__ ea_csr) {
  int i = blockIdx.x * 256 + threadIdx.x;
  if (i >= NN) return;
  int start = row_ptr[i], last = row_ptr[i + 1] - 1;
  float sx = 0.f, sy = 0.f, sz = 0.f, sw = 0.f;
  for (int j = start; j < last; ++j) {
    float4 a = *(const float4*)&ea_csr[(size_t)j * 4];
    sx += a.x; sy += a.y; sz += a.z; sw += a.w;
  }
  float c = (float)(last - start);
  if (c < 1.f) c = 1.f;
  float rc = 1.f / c;
  float4 o = {sx * rc, sy * rc, sz * rc, sw * rc};
  *(float4*)&ea_csr[(size_t)last * 4] = o;
  srcs[last] = i | (int)0x80000000;
}

// ------------------------------------------------------------------
// K4: OUT[NN][256] = A[NN][K] @ W[K][256]; OBF=1 -> bf16 output (ushort4).
template <int K, int OBF>
__global__ __launch_bounds__(256) void k_gemm256(
    const float* __restrict__ A, const float* __restrict__ W, void* __restrict__ OUTv) {
  __shared__ float Wl[32 * 256];
  __shared__ float Al[32 * 36];
  const int tid = threadIdx.x;
  const int n0 = blockIdx.x * 32;
  const int tx = tid & 63, ty = tid >> 6;
  float acc[8][4];
  #pragma unroll
  for (int m = 0; m < 8; m++)
    #pragma unroll
    for (int c = 0; c < 4; c++) acc[m][c] = 0.f;

  for (int kt = 0; kt < K; kt += 32) {
    #pragma unroll
    for (int r = 0; r < 8; r++) {
      int i4 = tid + 256 * r;
      int row = i4 >> 6;
      int col4 = (i4 & 63) * 4;
      *(float4*)&Wl[row * 256 + col4] = *(const float4*)&W[(size_t)(kt + row) * 256 + col4];
    }
    {
      int m = tid >> 3, kk = (tid & 7) * 4;
      float4 av = *(const float4*)&A[(size_t)(n0 + m) * K + kt + kk];
      Al[(kk + 0) * 36 + m] = av.x;
      Al[(kk + 1) * 36 + m] = av.y;
      Al[(kk + 2) * 36 + m] = av.z;
      Al[(kk + 3) * 36 + m] = av.w;
    }
    __syncthreads();
    #pragma unroll 8
    for (int k = 0; k < 32; k++) {
      float4 b = *(float4*)&Wl[k * 256 + tx * 4];
      float4 a0v = *(float4*)&Al[k * 36 + ty * 8];
      float4 a1v = *(float4*)&Al[k * 36 + ty * 8 + 4];
      float am[8] = {a0v.x, a0v.y, a0v.z, a0v.w, a1v.x, a1v.y, a1v.z, a1v.w};
      #pragma unroll
      for (int m = 0; m < 8; m++) {
        acc[m][0] += am[m] * b.x;
        acc[m][1] += am[m] * b.y;
        acc[m][2] += am[m] * b.z;
        acc[m][3] += am[m] * b.w;
      }
    }
    __syncthreads();
  }
  if (OBF) {
    ushort* OUT = (ushort*)OUTv;
    #pragma unroll
    for (int m = 0; m < 8; m++) {
      ushort4 o = {f2bf(acc[m][0]), f2bf(acc[m][1]), f2bf(acc[m][2]), f2bf(acc[m][3])};
      *(ushort4*)&OUT[(size_t)(n0 + ty * 8 + m) * 256 + tx * 4] = o;
    }
  } else {
    float* OUT = (float*)OUTv;
    #pragma unroll
    for (int m = 0; m < 8; m++) {
      float4 o = {acc[m][0], acc[m][1], acc[m][2], acc[m][3]};
      *(float4*)&OUT[(size_t)(n0 + ty * 8 + m) * 256 + tx * 4] = o;
    }
  }
}

// ------------------------------------------------------------------
// K5: fused GATv2 (xl gathered as bf16), online softmax, dual streams.
template <int CONCAT>
__global__ __launch_bounds__(256) void k_gat_fused(
    const ushort* __restrict__ xl, const float* __restrict__ xr,
    const float* __restrict__ we, const float* __restrict__ att,
    const int* __restrict__ srcs, const float* __restrict__ ea_csr,
    const int* __restrict__ row_ptr,
    const float* __restrict__ bias, const float* __restrict__ bng,
    const float* __restrict__ bnb, float* __restrict__ outp) {
  const int lane = threadIdx.x & 63;
  const int w = threadIdx.x >> 6;
  const int i = blockIdx.x * 4 + w;
  const int c0 = lane * 4;

  const float4 attv = *(const float4*)&att[c0];
  const float4 we0 = *(const float4*)&we[0 * HC + c0];
  const float4 we1 = *(const float4*)&we[1 * HC + c0];
  const float4 we2 = *(const float4*)&we[2 * HC + c0];
  const float4 we3 = *(const float4*)&we[3 * HC + c0];
  const float4 xrd = *(const float4*)&xr[(size_t)i * HC + c0];

  const int start = row_ptr[i];
  const int deg = row_ptr[i + 1] - start;

  float mxA = -1e30f, dnA = 0.f, aA0 = 0.f, aA1 = 0.f, aA2 = 0.f, aA3 = 0.f;
  float mxB = -1e30f, dnB = 0.f, aB0 = 0.f, aB1 = 0.f, aB2 = 0.f, aB3 = 0.f;

  for (int base = 0; base < deg; base += 64) {
    int rem = deg - base;
    if (rem > 64) rem = 64;
    int sv = 0;
    if (lane < rem) sv = srcs[start + base + lane];
    int jj = 0;
    for (; jj + 2 <= rem; jj += 2) {
      int s0 = __shfl(sv, jj) & 0x7fffffff;
      int s1 = __shfl(sv, jj + 1) & 0x7fffffff;
      float4 a0 = *(const float4*)&ea_csr[(size_t)(start + base + jj) * 4];
      float4 a1 = *(const float4*)&ea_csr[(size_t)(start + base + jj + 1) * 4];
      ushort4 u0 = *(const ushort4*)&xl[(size_t)s0 * HC + c0];
      ushort4 u1 = *(const ushort4*)&xl[(size_t)s1 * HC + c0];
      float x0x = bf2f(u0.x), x0y = bf2f(u0.y), x0z = bf2f(u0.z), x0w = bf2f(u0.w);
      float x1x = bf2f(u1.x), x1y = bf2f(u1.y), x1z = bf2f(u1.z), x1w = bf2f(u1.w);
      // ---- edge 0 -> stream A ----
      {
        float m0 = x0x + xrd.x + a0.x * we0.x + a0.y * we1.x + a0.z * we2.x + a0.w * we3.x;
        float m1 = x0y + xrd.y + a0.x * we0.y + a0.y * we1.y + a0.z * we2.y + a0.w * we3.y;
        float m2 = x0z + xrd.z + a0.x * we0.z + a0.y * we1.z + a0.z * we2.z + a0.w * we3.z;
        float m3 = x0w + xrd.w + a0.x * we0.w + a0.y * we1.w + a0.z * we2.w + a0.w * we3.w;
        m0 = (m0 > 0.f) ? m0 : NEG_SLOPE * m0;
        m1 = (m1 > 0.f) ? m1 : NEG_SLOPE * m1;
        m2 = (m2 > 0.f) ? m2 : NEG_SLOPE * m2;
        m3 = (m3 > 0.f) ? m3 : NEG_SLOPE * m3;
        float lg = m0 * attv.x + m1 * attv.y + m2 * attv.z + m3 * attv.w;
        lg += __shfl_xor(lg, 1);
        lg += __shfl_xor(lg, 2);
        lg += __shfl_xor(lg, 4);
        lg += __shfl_xor(lg, 8);
        float nmx = fmaxf(mxA, lg);
        float sc = __expf(mxA - nmx);
        float p = __expf(lg - nmx);
        dnA = dnA * sc + p;
        aA0 = fmaf(aA0, sc, p * x0x);
        aA1 = fmaf(aA1, sc, p * x0y);
        aA2 = fmaf(aA2, sc, p * x0z);
        aA3 = fmaf(aA3, sc, p * x0w);
        mxA = nmx;
      }
      // ---- edge 1 -> stream B ----
      {
        float m0 = x1x + xrd.x + a1.x * we0.x + a1.y * we1.x + a1.z * we2.x + a1.w * we3.x;
        float m1 = x1y + xrd.y + a1.x * we0.y + a1.y * we1.y + a1.z * we2.y + a1.w * we3.y;
        float m2 = x1z + xrd.z + a1.x * we0.z + a1.y * we1.z + a1.z * we2.z + a1.w * we3.z;
        float m3 = x1w + xrd.w + a1.x * we0.w + a1.y * we1.w + a1.z * we2.w + a1.w * we3.w;
        m0 = (m0 > 0.f) ? m0 : NEG_SLOPE * m0;
        m1 = (m1 > 0.f) ? m1 : NEG_SLOPE * m1;
        m2 = (m2 > 0.f) ? m2 : NEG_SLOPE * m2;
        m3 = (m3 > 0.f) ? m3 : NEG_SLOPE * m3;
        float lg = m0 * attv.x + m1 * attv.y + m2 * attv.z + m3 * attv.w;
        lg += __shfl_xor(lg, 1);
        lg += __shfl_xor(lg, 2);
        lg += __shfl_xor(lg, 4);
        lg += __shfl_xor(lg, 8);
        float nmx = fmaxf(mxB, lg);
        float sc = __expf(mxB - nmx);
        float p = __expf(lg - nmx);
        dnB = dnB * sc + p;
        aB0 = fmaf(aB0, sc, p * x1x);
        aB1 = fmaf(aB1, sc, p * x1y);
        aB2 = fmaf(aB2, sc, p * x1z);
        aB3 = fmaf(aB3, sc, p * x1w);
        mxB = nmx;
      }
    }
    if (jj < rem) {   // tail edge -> stream A
      int s0 = __shfl(sv, jj) & 0x7fffffff;
      float4 a0 = *(const float4*)&ea_csr[(size_t)(start + base + jj) * 4];
      ushort4 u0 = *(const ushort4*)&xl[(size_t)s0 * HC + c0];
      float x0x = bf2f(u0.x), x0y = bf2f(u0.y), x0z = bf2f(u0.z), x0w = bf2f(u0.w);
      float m0 = x0x + xrd.x + a0.x * we0.x + a0.y * we1.x + a0.z * we2.x + a0.w * we3.x;
      float m1 = x0y + xrd.y + a0.x * we0.y + a0.y * we1.y + a0.z * we2.y + a0.w * we3.y;
      float m2 = x0z + xrd.z + a0.x * we0.z + a0.y * we1.z + a0.z * we2.z + a0.w * we3.z;
      float m3 = x0w + xrd.w + a0.x * we0.w + a0.y * we1.w + a0.z * we2.w + a0.w * we3.w;
      m0 = (m0 > 0.f) ? m0 : NEG_SLOPE * m0;
      m1 = (m1 > 0.f) ? m1 : NEG_SLOPE * m1;
      m2 = (m2 > 0.f) ? m2 : NEG_SLOPE * m2;
      m3 = (m3 > 0.f) ? m3 : NEG_SLOPE * m3;
      float lg = m0 * attv.x + m1 * attv.y + m2 * attv.z + m3 * attv.w;
      lg += __shfl_xor(lg, 1);
      lg += __shfl_xor(lg, 2);
      lg += __shfl_xor(lg, 4);
      lg += __shfl_xor(lg, 8);
      float nmx = fmaxf(mxA, lg);
      float sc = __expf(mxA - nmx);
      float p = __expf(lg - nmx);
      dnA = dnA * sc + p;
      aA0 = fmaf(aA0, sc, p * x0x);
      aA1 = fmaf(aA1, sc, p * x0y);
      aA2 = fmaf(aA2, sc, p * x0z);
      aA3 = fmaf(aA3, sc, p * x0w);
      mxA = nmx;
    }
  }

  // merge streams
  float m = fmaxf(mxA, mxB);
  float sA = __expf(mxA - m), sB = __expf(mxB - m);
  float dn = dnA * sA + dnB * sB;
  float rinv = 1.f / dn;
  float acc0 = (aA0 * sA + aB0 * sB) * rinv;
  float acc1 = (aA1 * sA + aB1 * sB) * rinv;
  float acc2 = (aA2 * sA + aB2 * sB) * rinv;
  float acc3 = (aA3 * sA + aB3 * sB) * rinv;

  const float inv_sqrt = rsqrtf(1.f + BN_EPS);
  if (CONCAT) {
    float4 bi = *(const float4*)&bias[c0];
    float4 g = *(const float4*)&bng[c0];
    float4 bb = *(const float4*)&bnb[c0];
    float v0 = (acc0 + bi.x) * (g.x * inv_sqrt) + bb.x;
    float v1 = (acc1 + bi.y) * (g.y * inv_sqrt) + bb.y;
    float v2 = (acc2 + bi.z) * (g.z * inv_sqrt) + bb.z;
    float v3 = (acc3 + bi.w) * (g.w * inv_sqrt) + bb.w;
    v0 = (v0 > 0.f) ? v0 : (__expf(v0) - 1.f);
    v1 = (v1 > 0.f) ? v1 : (__expf(v1) - 1.f);
    v2 = (v2 > 0.f) ? v2 : (__expf(v2) - 1.f);
    v3 = (v3 > 0.f) ? v3 : (__expf(v3) - 1.f);
    float4 o = {v0, v1, v2, v3};
    *(float4*)&outp[(size_t)i * HC + c0] = o;
  } else {
    // mean over heads: sum lanes {l, l^16, l^32, l^48} (acc already normalized)
    acc0 += __shfl_xor(acc0, 16); acc0 += __shfl_xor(acc0, 32);
    acc1 += __shfl_xor(acc1, 16); acc1 += __shfl_xor(acc1, 32);
    acc2 += __shfl_xor(acc2, 16); acc2 += __shfl_xor(acc2, 32);
    acc3 += __shfl_xor(acc3, 16); acc3 += __shfl_xor(acc3, 32);
    if (lane < 16) {
      int cc = lane * 4;
      float4 bi = *(const float4*)&bias[cc];
      float4 g = *(const float4*)&bng[cc];
      float4 bb = *(const float4*)&bnb[cc];
      float v0 = (0.25f * acc0 + bi.x) * (g.x * inv_sqrt) + bb.x;
      float v1 = (0.25f * acc1 + bi.y) * (g.y * inv_sqrt) + bb.y;
      float v2 = (0.25f * acc2 + bi.z) * (g.z * inv_sqrt) + bb.z;
      float v3 = (0.25f * acc3 + bi.w) * (g.w * inv_sqrt) + bb.w;
      v0 = (v0 > 0.f) ? v0 : (__expf(v0) - 1.f);
      v1 = (v1 > 0.f) ? v1 : (__expf(v1) - 1.f);
      v2 = (v2 > 0.f) ? v2 : (__expf(v2) - 1.f);
      v3 = (v3 > 0.f) ? v3 : (__expf(v3) - 1.f);
      float4 o = {v0, v1, v2, v3};
      *(float4*)&outp[(size_t)i * 64 + cc] = o;
    }
  }
}

// ------------------------------------------------------------------
// K8: fused SAGE, prefetched srcs + 4 independent streams.
// Self-loop slot is always LAST in each row -> iterate real edges [start,end-1).
__global__ __launch_bounds__(256) void k_sage(
    const float* __restrict__ h2, const int* __restrict__ row_ptr,
    const int* __restrict__ srcs, const unsigned* __restrict__ cnt,
    const float* __restrict__ wl, const float* __restrict__ bl,
    const float* __restrict__ wr, const float* __restrict__ bng,
    const float* __restrict__ bnb, float* __restrict__ h3) {
  __shared__ float agg_s[4][64];
  __shared__ float h2_s[4][64];
  int lane = threadIdx.x & 63;
  int w = threadIdx.x >> 6;
  int i = blockIdx.x * 4 + w;
  int start = row_ptr[i];
  int nreal = row_ptr[i + 1] - 1 - start;   // excludes self-loop slot
  float a0 = 0.f, a1 = 0.f, a2 = 0.f, a3 = 0.f;
  for (int base = 0; base < nreal; base += 64) {
    int rem = nreal - base;
    if (rem > 64) rem = 64;
    int sv = 0;
    if (lane < rem) sv = srcs[start + base + lane];
    int jj = 0;
    for (; jj + 4 <= rem; jj += 4) {
      int s0 = __shfl(sv, jj);
      int s1 = __shfl(sv, jj + 1);
      int s2 = __shfl(sv, jj + 2);
      int s3 = __shfl(sv, jj + 3);
      a0 += h2[(size_t)s0 * 64 + lane];
      a1 += h2[(size_t)s1 * 64 + lane];
      a2 += h2[(size_t)s2 * 64 + lane];
      a3 += h2[(size_t)s3 * 64 + lane];
    }
    for (; jj < rem; ++jj) {
      int s0 = __shfl(sv, jj);
      a0 += h2[(size_t)s0 * 64 + lane];
    }
  }
  float a = (a0 + a1) + (a2 + a3);
  float c = (float)cnt[i];
  if (c < 1.f) c = 1.f;
  agg_s[w][lane] = a / c;
  h2_s[w][lane] = h2[(size_t)i * 64 + lane];
  __syncthreads();
  float s = bl[lane];
  #pragma unroll 4
  for (int k = 0; k < 64; k++)
    s += agg_s[w][k] * wl[k * 64 + lane] + h2_s[w][k] * wr[k * 64 + lane];
  s = s * (bng[lane] * rsqrtf(1.f + BN_EPS)) + bnb[lane];
  s = fmaxf(s, 0.f);
  h3[(size_t)i * 64 + lane] = s;
}

// ------------------------------------------------------------------
// K9: pooling: per-graph sum / max / count
__global__ __launch_bounds__(256) void k_pool(
    const float* __restrict__ h3, const int* __restrict__ batch,
    float* __restrict__ psum, float* __restrict__ pmax, float* __restrict__ pcnt) {
  int j = threadIdx.x & 63, grp = threadIdx.x >> 6;
  int nbase = blockIdx.x * 256 + grp * 64;
  float s = 0.f, m = 0.f, cn = 0.f;
  int cur = -1;
  for (int t = 0; t < 64; t++) {
    int n = nbase + t;
    if (n >= NN) break;
    int g = batch[n];
    if (g != cur) {
      if (cur >= 0) {
        atomicAdd(&psum[cur * 64 + j], s);
        atomicMax((int*)&pmax[cur * 64 + j], __float_as_int(m));
        if (j == 0) atomicAdd(&pcnt[cur], cn);
      }
      cur = g; s = 0.f; m = 0.f; cn = 0.f;
    }
    float v = h3[(size_t)n * 64 + j];
    s += v; m = fmaxf(m, v); cn += 1.f;
  }
  if (cur >= 0) {
    atomicAdd(&psum[cur * 64 + j], s);
    atomicMax((int*)&pmax[cur * 64 + j], __float_as_int(m));
    if (j == 0) atomicAdd(&pcnt[cur], cn);
  }
}

// ------------------------------------------------------------------
// K10: graph head (block per graph, 64 threads)
__global__ void k_graph_head(
    const float* __restrict__ psum, const float* __restrict__ pmax,
    const float* __restrict__ pcnt,
    const float* __restrict__ w1, const float* __restrict__ b1,
    const float* __restrict__ w2, const float* __restrict__ b2,
    const float* __restrict__ w3, const float* __restrict__ b3,
    float* __restrict__ out) {
  __shared__ float hp[128];
  __shared__ float z1[64];
  __shared__ float z2[32];
  int g = blockIdx.x, j = threadIdx.x;
  float c = pcnt[g];
  if (c < 1.f) c = 1.f;
  hp[j] = psum[g * 64 + j] / c;
  hp[64 + j] = pmax[g * 64 + j];
  __syncthreads();
  float s = b1[j];
  #pragma unroll 8
  for (int k = 0; k < 128; k++) s += hp[k] * w1[k * 64 + j];
  z1[j] = fmaxf(s, 0.f);
  __syncthreads();
  if (j < 32) {
    float s2 = b2[j];
    #pragma unroll 8
    for (int k = 0; k < 64; k++) s2 += z1[k] * w2[k * 32 + j];
    z2[j] = fmaxf(s2, 0.f);
  }
  __syncthreads();
  if (j == 0) {
    float s3 = b3[0];
    #pragma unroll
    for (int k = 0; k < 32; k++) s3 += z2[k] * w3[k];
    out[g] = 1.f / (1.f + expf(-s3));
  }
}

// ------------------------------------------------------------------
// K11: edge head (thread per edge; weights read lane-uniform -> s_load)
__global__ __launch_bounds__(256) void k_edge_head(
    const float* __restrict__ h3, const int* __restrict__ ei,
    const float* __restrict__ ea,
    const float* __restrict__ w1, const float* __restrict__ b1,
    const float* __restrict__ w2, const float* __restrict__ b2,
    float* __restrict__ out) {
  int e = blockIdx.x * 256 + threadIdx.x;
  if (e >= NE) return;
  int s = ei[e], d = ei[NE + e];
  float acc[32];
  #pragma unroll
  for (int j = 0; j < 32; j++) acc[j] = b1[j];
  const float4* hs = (const float4*)&h3[(size_t)s * 64];
  const float4* hd = (const float4*)&h3[(size_t)d * 64];
  for (int k4 = 0; k4 < 16; k4++) {
    float4 v = hs[k4];
    const float* w = &w1[k4 * 4 * 32];
    #pragma unroll
    for (int j = 0; j < 32; j++) acc[j] += v.x * w[j];
    #pragma unroll
    for (int j = 0; j < 32; j++) acc[j] += v.y * w[32 + j];
    #pragma unroll
    for (int j = 0; j < 32; j++) acc[j] += v.z * w[64 + j];
    #pragma unroll
    for (int j = 0; j < 32; j++) acc[j] += v.w * w[96 + j];
  }
  for (int k4 = 0; k4 < 16; k4++) {
    float4 v = hd[k4];
    const float* w = &w1[(64 + k4 * 4) * 32];
    #pragma unroll
    for (int j = 0; j < 32; j++) acc[j] += v.x * w[j];
    #pragma unroll
    for (int j = 0; j < 32; j++) acc[j] += v.y * w[32 + j];
    #pragma unroll
    for (int j = 0; j < 32; j++) acc[j] += v.z * w[64 + j];
    #pragma unroll
    for (int j = 0; j < 32; j++) acc[j] += v.w * w[96 + j];
  }
  {
    float4 v = *(const float4*)&ea[(size_t)e * 4];
    const float* w = &w1[128 * 32];
    #pragma unroll
    for (int j = 0; j < 32; j++) acc[j] += v.x * w[j];
    #pragma unroll
    for (int j = 0; j < 32; j++) acc[j] += v.y * w[32 + j];
    #pragma unroll
    for (int j = 0; j < 32; j++) acc[j] += v.z * w[64 + j];
    #pragma unroll
    for (int j = 0; j < 32; j++) acc[j] += v.w * w[96 + j];
  }
  float s2 = b2[0];
  #pragma unroll
  for (int j = 0; j < 32; j++) s2 += fmaxf(acc[j], 0.f) * w2[j];
  out[e] = 1.f / (1.f + expf(-s2));
}

// ------------------------------------------------------------------
extern "C" void kernel_launch(void* const* d_in, const int* in_sizes, int n_in,
                              void* d_out, int out_size, void* d_ws, size_t ws_size,
                              hipStream_t stream) {
  const float* x         = (const float*)d_in[0];
  const float* edge_attr = (const float*)d_in[1];
  const float* enc_w1 = (const float*)d_in[2];
  const float* enc_b1 = (const float*)d_in[3];
  const float* enc_w2 = (const float*)d_in[4];
  const float* enc_b2 = (const float*)d_in[5];
  const float* g1_wl = (const float*)d_in[6];
  const float* g1_wr = (const float*)d_in[7];
  const float* g1_we = (const float*)d_in[8];
  const float* g1_att = (const float*)d_in[9];
  const float* g1_b = (const float*)d_in[10];
  const float* bn1_g = (const float*)d_in[11];
  const float* bn1_b = (const float*)d_in[12];
  const float* g2_wl = (const float*)d_in[13];
  const float* g2_wr = (const float*)d_in[14];
  const float* g2_we = (const float*)d_in[15];
  const float* g2_att = (const float*)d_in[16];
  const float* g2_b = (const float*)d_in[17];
  const float* bn2_g = (const float*)d_in[18];
  const float* bn2_b = (const float*)d_in[19];
  const float* sage_wl = (const float*)d_in[20];
  const float* sage_bl = (const float*)d_in[21];
  const float* sage_wr = (const float*)d_in[22];
  const float* bn3_g = (const float*)d_in[23];
  const float* bn3_b = (const float*)d_in[24];
  const float* gh_w1 = (const float*)d_in[25];
  const float* gh_b1 = (const float*)d_in[26];
  const float* gh_w2 = (const float*)d_in[27];
  const float* gh_b2 = (const float*)d_in[28];
  const float* gh_w3 = (const float*)d_in[29];
  const float* gh_b3 = (const float*)d_in[30];
  const float* eh_w1 = (const float*)d_in[31];
  const float* eh_b1 = (const float*)d_in[32];
  const float* eh_w2 = (const float*)d_in[33];
  const float* eh_b2 = (const float*)d_in[34];
  const int* ei    = (const int*)d_in[35];
  const int* batch = (const int*)d_in[36];
  float* out = (float*)d_out;

  float* ws = (float*)d_ws;
  ushort* xlbf = (ushort*)(ws + OFF_XL);
  float* xr = ws + OFF_XR;
  float* h1 = ws + OFF_H1;
  float* h0 = ws + OFF_H0;   // later h2
  float* h3 = ws + OFF_H3;
  unsigned* cnt = (unsigned*)(ws + OFF_CNT);
  float* psum = ws + OFF_PSUM;
  float* pmax = ws + OFF_PMAX;
  float* pcnt = ws + OFF_PCNT;
  float* ea_csr = ws + OFF_EACSR;
  int* row_ptr = (int*)(ws + OFF_RP);
  int* srcs = (int*)(ws + OFF_SRC);
  int* bsums = (int*)(ws + OFF_BSUM);
  int* rank = (int*)(ws + OFF_XL);   // transient: xl region unused until GEMMs

  hipMemsetAsync(ws + OFF_ZERO, 0, ZERO_FLOATS * sizeof(float), stream);

  k_count<<<NE / 256, 256, 0, stream>>>(ei, cnt, rank);
  k_encoder<<<NN / (4 * ENC_NPW), 256, 0, stream>>>(x, enc_w1, enc_b1, enc_w2, enc_b2, h0);
  k_scan_blk<<<SCAN_NB, 256, 0, stream>>>(cnt, row_ptr, bsums);
  k_scan_add<<<SCAN_NB, 256, 0, stream>>>(bsums, row_ptr);
  k_csr_scatter<<<NE / 256, 256, 0, stream>>>(ei, rank, row_ptr, edge_attr, srcs, ea_csr);
  k_loop_row<<<(NN + 255) / 256, 256, 0, stream>>>(row_ptr, srcs, ea_csr);

  // ---- GAT layer 1 ----
  k_gemm256<64, 1><<<NN / 32, 256, 0, stream>>>(h0, g1_wl, (void*)xlbf);
  k_gemm256<64, 0><<<NN / 32, 256, 0, stream>>>(h0, g1_wr, (void*)xr);
  k_gat_fused<1><<<NN / 4, 256, 0, stream>>>(xlbf, xr, g1_we, g1_att, srcs, ea_csr,
                                             row_ptr, g1_b, bn1_g, bn1_b, h1);

  // ---- GAT layer 2 ----
  k_gemm256<256, 1><<<NN / 32, 256, 0, stream>>>(h1, g2_wl, (void*)xlbf);
  k_gemm256<256, 0><<<NN / 32, 256, 0, stream>>>(h1, g2_wr, (void*)xr);
  k_gat_fused<0><<<NN / 4, 256, 0, stream>>>(xlbf, xr, g2_we, g2_att, srcs, ea_csr,
                                             row_ptr, g2_b, bn2_g, bn2_b, h0);

  // ---- SAGE ----
  k_sage<<<NN / 4, 256, 0, stream>>>(h0, row_ptr, srcs, cnt, sage_wl, sage_bl, sage_wr, bn3_g, bn3_b, h3);

  // ---- pooling + heads ----
  k_pool<<<(NN + 255) / 256, 256, 0, stream>>>(h3, batch, psum, pmax, pcnt);
  k_graph_head<<<NG, 64, 0, stream>>>(psum, pmax, pcnt, gh_w1, gh_b1, gh_w2, gh_b2, gh_w3, gh_b3, out);
  k_edge_head<<<NE / 256, 256, 0, stream>>>(h3, ei, edge_attr, eh_w1, eh_b1, eh_w2, eh_b2, out + NG);
}

// Round 8
// 359.209 us; speedup vs baseline: 2.8770x; 1.1399x over previous
//
#include <hip/hip_runtime.h>

#define NN 20000
#define NE 320000
#define EP (NE + NN)          // 340000 edges incl. self loops
#define NG 8
#define HC 256
#define NODE_IN 18
#define HID 64
#define NEG_SLOPE 0.2f
#define BN_EPS 1e-5f

// ---------------- workspace layout (float offsets) ----------------
#define OFF_XL    0u                      // bf16 [NN*256]; also rank[NE] during CSR build
#define OFF_XR    5120000u                // fp32 [NN*256]
#define OFF_H1    10240000u               // bf16 [NN*256] -> ends at 12800000
#define OFF_WTL   12800000u               // bf16 [256*256] n-major (g2_wl^T)
#define OFF_WTR   12832768u               // bf16 [256*256] n-major (g2_wr^T)
#define OFF_H0    15360000u               // fp32 [NN*64]  (h0, later reused as h2)
#define OFF_H3    16640000u               // fp32 [NN*64]
#define OFF_ZERO  18000000u               // start of zeroed region
#define OFF_CNT   18000000u               // uint cnt [NN]
#define OFF_PSUM  18020000u               // [8*64]
#define OFF_PMAX  18020512u               // [8*64]
#define OFF_PCNT  18021024u               // [16]
#define ZERO_FLOATS (18021040u - 18000000u)
#define OFF_EACSR 18021040u               // [EP*4] CSR-ordered edge attrs
#define OFF_RP    19381040u               // int [NN+1]
#define OFF_SRC   19421041u               // int [EP] (self-loop = LAST slot of row, sign bit)
#define OFF_BSUM  19761056u               // int [32]

#define SCAN_ELEM 1024
#define SCAN_NB ((NN + SCAN_ELEM - 1) / SCAN_ELEM)   // 20

typedef __attribute__((ext_vector_type(8))) short bf16x8_t;
typedef __attribute__((ext_vector_type(4))) float f32x4_t;

__device__ __forceinline__ ushort f2bf(float f) {   // RNE float->bf16
  unsigned u = __float_as_uint(f);
  unsigned r = (u + 0x7fffu + ((u >> 16) & 1u)) >> 16;
  return (ushort)r;
}
__device__ __forceinline__ float bf2f(ushort b) {
  return __uint_as_float(((unsigned)b) << 16);
}

// ------------------------------------------------------------------
// K1: per-dst edge count; returned old value = rank within dst row.
__global__ __launch_bounds__(256) void k_count(
    const int* __restrict__ ei, unsigned* __restrict__ cnt, int* __restrict__ rank) {
  int e = blockIdx.x * 256 + threadIdx.x;
  if (e >= NE) return;
  int d = ei[NE + e];
  rank[e] = (int)atomicAdd(&cnt[d], 1u);
}

// ------------------------------------------------------------------
// K_cast_wt: W[k][n] fp32 -> Wt[n][k] bf16 (both g2 weight matrices)
__global__ __launch_bounds__(256) void k_cast_wt(
    const float* __restrict__ Wl, const float* __restrict__ Wr,
    ushort* __restrict__ WtL, ushort* __restrict__ WtR) {
  int b = blockIdx.x;
  const float* W = (b < 256) ? Wl : Wr;
  ushort* Wt = (b < 256) ? WtL : WtR;
  int k = b & 255;
  int n = threadIdx.x;
  Wt[n * 256 + k] = f2bf(W[k * 256 + n]);
}

// ------------------------------------------------------------------
// K3: encoder, wave-per-node (lane = channel).
#define ENC_NPW 4
__global__ __launch_bounds__(256) void k_encoder(
    const float* __restrict__ x, const float* __restrict__ w1, const float* __restrict__ b1,
    const float* __restrict__ w2, const float* __restrict__ b2, float* __restrict__ h0) {
  __shared__ float W1[NODE_IN * HID];
  __shared__ float W2[HID * HID];
  __shared__ float B1s[HID];
  __shared__ float B2s[HID];
  __shared__ float hid_s[4][HID];
  const int tid = threadIdx.x;
  for (int i = tid; i < NODE_IN * HID; i += 256) W1[i] = w1[i];
  for (int i = tid; i < HID * HID; i += 256) W2[i] = w2[i];
  if (tid < HID) { B1s[tid] = b1[tid]; B2s[tid] = b2[tid]; }
  __syncthreads();
  const int lane = tid & 63;
  const int w = tid >> 6;
  #pragma unroll
  for (int t = 0; t < ENC_NPW; t++) {
    const int n = blockIdx.x * (4 * ENC_NPW) + w * ENC_NPW + t;
    const float* xp = &x[(size_t)n * NODE_IN];
    float s = B1s[lane];
    #pragma unroll
    for (int i = 0; i < NODE_IN; i++) s += xp[i] * W1[i * HID + lane];
    hid_s[w][lane] = fmaxf(s, 0.f);
    float o = B2s[lane];
    #pragma unroll 8
    for (int k = 0; k < HID; k++) o += hid_s[w][k] * W2[k * HID + lane];
    h0[(size_t)n * HID + lane] = o;
  }
}

// ------------------------------------------------------------------
__global__ __launch_bounds__(256) void k_scan_blk(
    const unsigned* __restrict__ cnt, int* __restrict__ row_ptr, int* __restrict__ bsums) {
  __shared__ int wsum[4];
  const int tid = threadIdx.x, lane = tid & 63, w = tid >> 6;
  const int i0 = blockIdx.x * SCAN_ELEM + tid * 4;
  int v0 = (i0 + 0 < NN) ? ((int)cnt[i0 + 0] + 1) : 0;
  int v1 = (i0 + 1 < NN) ? ((int)cnt[i0 + 1] + 1) : 0;
  int v2 = (i0 + 2 < NN) ? ((int)cnt[i0 + 2] + 1) : 0;
  int v3 = (i0 + 3 < NN) ? ((int)cnt[i0 + 3] + 1) : 0;
  int tsum = v0 + v1 + v2 + v3;
  int incl = tsum;
  #pragma unroll
  for (int off = 1; off < 64; off <<= 1) {
    int t = __shfl_up(incl, off);
    if (lane >= off) incl += t;
  }
  if (lane == 63) wsum[w] = incl;
  __syncthreads();
  int p = incl - tsum;
  #pragma unroll
  for (int k = 0; k < 4; k++) if (k < w) p += wsum[k];
  if (i0 + 0 < NN) row_ptr[i0 + 0] = p;
  if (i0 + 1 < NN) row_ptr[i0 + 1] = p + v0;
  if (i0 + 2 < NN) row_ptr[i0 + 2] = p + v0 + v1;
  if (i0 + 3 < NN) row_ptr[i0 + 3] = p + v0 + v1 + v2;
  if (tid == 0) bsums[blockIdx.x] = wsum[0] + wsum[1] + wsum[2] + wsum[3];
}

__global__ __launch_bounds__(256) void k_scan_add(
    const int* __restrict__ bsums, int* __restrict__ row_ptr) {
  const int b = blockIdx.x, tid = threadIdx.x;
  int off = 0;
  for (int j = 0; j < b; j++) off += bsums[j];
  const int i0 = b * SCAN_ELEM + tid * 4;
  #pragma unroll
  for (int k = 0; k < 4; k++) {
    int i = i0 + k;
    if (i < NN) row_ptr[i] += off;
  }
  if (b == 0 && tid == 0) row_ptr[NN] = EP;
}

__global__ __launch_bounds__(256) void k_csr_scatter(
    const int* __restrict__ ei, const int* __restrict__ rank,
    const int* __restrict__ row_ptr, const float* __restrict__ ea,
    int* __restrict__ srcs, float* __restrict__ ea_csr) {
  int e = blockIdx.x * 256 + threadIdx.x;
  if (e >= NE) return;
  int s = ei[e], d = ei[NE + e];
  int p = row_ptr[d] + rank[e];
  srcs[p] = s;
  *(float4*)&ea_csr[(size_t)p * 4] = *(const float4*)&ea[(size_t)e * 4];
}

__global__ __launch_bounds__(256) void k_loop_row(
    const int* __restrict__ row_ptr, int* __restrict__ srcs, float* __restrict__ ea_csr) {
  int i = blockIdx.x * 256 + threadIdx.x;
  if (i >= NN) return;
  int start = row_ptr[i], last = row_ptr[i + 1] - 1;
  float sx = 0.f, sy = 0.f, sz = 0.f, sw = 0.f;
  for (int j = start; j < last; ++j) {
    float4 a = *(const float4*)&ea_csr[(size_t)j * 4];
    sx += a.x; sy += a.y; sz += a.z; sw += a.w;
  }
  float c = (float)(last - start);
  if (c < 1.f) c = 1.f;
  float rc = 1.f / c;
  float4 o = {sx * rc, sy * rc, sz * rc, sw * rc};
  *(float4*)&ea_csr[(size_t)last * 4] = o;
  srcs[last] = i | (int)0x80000000;
}

// ------------------------------------------------------------------
// K4: fp32 vector GEMM (layer-1, K=64): OUT[NN][256] = A[NN][K]@W[K][256]
template <int K, int OBF>
__global__ __launch_bounds__(256) void k_gemm256(
    const float* __restrict__ A, const float* __restrict__ W, void* __restrict__ OUTv) {
  __shared__ float Wl[32 * 256];
  __shared__ float Al[32 * 36];
  const int tid = threadIdx.x;
  const int n0 = blockIdx.x * 32;
  const int tx = tid & 63, ty = tid >> 6;
  float acc[8][4];
  #pragma unroll
  for (int m = 0; m < 8; m++)
    #pragma unroll
    for (int c = 0; c < 4; c++) acc[m][c] = 0.f;

  for (int kt = 0; kt < K; kt += 32) {
    #pragma unroll
    for (int r = 0; r < 8; r++) {
      int i4 = tid + 256 * r;
      int row = i4 >> 6;
      int col4 = (i4 & 63) * 4;
      *(float4*)&Wl[row * 256 + col4] = *(const float4*)&W[(size_t)(kt + row) * 256 + col4];
    }
    {
      int m = tid >> 3, kk = (tid & 7) * 4;
      float4 av = *(const float4*)&A[(size_t)(n0 + m) * K + kt + kk];
      Al[(kk + 0) * 36 + m] = av.x;
      Al[(kk + 1) * 36 + m] = av.y;
      Al[(kk + 2) * 36 + m] = av.z;
      Al[(kk + 3) * 36 + m] = av.w;
    }
    __syncthreads();
    #pragma unroll 8
    for (int k = 0; k < 32; k++) {
      float4 b = *(float4*)&Wl[k * 256 + tx * 4];
      float4 a0v = *(float4*)&Al[k * 36 + ty * 8];
      float4 a1v = *(float4*)&Al[k * 36 + ty * 8 + 4];
      float am[8] = {a0v.x, a0v.y, a0v.z, a0v.w, a1v.x, a1v.y, a1v.z, a1v.w};
      #pragma unroll
      for (int m = 0; m < 8; m++) {
        acc[m][0] += am[m] * b.x;
        acc[m][1] += am[m] * b.y;
        acc[m][2] += am[m] * b.z;
        acc[m][3] += am[m] * b.w;
      }
    }
    __syncthreads();
  }
  if (OBF) {
    ushort* OUT = (ushort*)OUTv;
    #pragma unroll
    for (int m = 0; m < 8; m++) {
      ushort4 o = {f2bf(acc[m][0]), f2bf(acc[m][1]), f2bf(acc[m][2]), f2bf(acc[m][3])};
      *(ushort4*)&OUT[(size_t)(n0 + ty * 8 + m) * 256 + tx * 4] = o;
    }
  } else {
    float* OUT = (float*)OUTv;
    #pragma unroll
    for (int m = 0; m < 8; m++) {
      float4 o = {acc[m][0], acc[m][1], acc[m][2], acc[m][3]};
      *(float4*)&OUT[(size_t)(n0 + ty * 8 + m) * 256 + tx * 4] = o;
    }
  }
}

// ------------------------------------------------------------------
// K4b: MFMA bf16 GEMM (layer-2, K=256): OUT[NN][256] = A[NN][256] @ W[256][256]
// A bf16 row-major, Wt bf16 n-major ([n][k]).  M-tile 32, BK=64, 4 waves.
template <int OBF>
__global__ __launch_bounds__(256) void k_gemm_mfma(
    const ushort* __restrict__ A, const ushort* __restrict__ Wt, void* __restrict__ OUTv) {
  __shared__ ushort Asub[32][72];     // +8 pad for bank spread
  __shared__ ushort Wsub[256][72];
  const int tid = threadIdx.x;
  const int lane = tid & 63;
  const int w = tid >> 6;
  const int n0 = blockIdx.x * 32;
  const int lr = lane & 15;
  const int lk = (lane >> 4) * 8;

  f32x4_t acc[2][4];
  #pragma unroll
  for (int m = 0; m < 2; m++)
    #pragma unroll
    for (int n = 0; n < 4; n++) acc[m][n] = (f32x4_t){0.f, 0.f, 0.f, 0.f};

  for (int kt = 0; kt < 256; kt += 64) {
    {
      int r = tid >> 3, seg = (tid & 7) * 8;
      *(uint4*)&Asub[r][seg] = *(const uint4*)&A[(size_t)(n0 + r) * 256 + kt + seg];
    }
    #pragma unroll
    for (int rep = 0; rep < 8; rep++) {
      int idx = rep * 256 + tid;
      int r = idx >> 3, seg = (idx & 7) * 8;
      *(uint4*)&Wsub[r][seg] = *(const uint4*)&Wt[(size_t)r * 256 + kt + seg];
    }
    __syncthreads();
    #pragma unroll
    for (int kk = 0; kk < 2; kk++) {
      bf16x8_t af0 = *(bf16x8_t*)&Asub[lr][kk * 32 + lk];
      bf16x8_t af1 = *(bf16x8_t*)&Asub[16 + lr][kk * 32 + lk];
      #pragma unroll
      for (int n = 0; n < 4; n++) {
        bf16x8_t bfr = *(bf16x8_t*)&Wsub[w * 64 + n * 16 + lr][kk * 32 + lk];
        acc[0][n] = __builtin_amdgcn_mfma_f32_16x16x32_bf16(af0, bfr, acc[0][n], 0, 0, 0);
        acc[1][n] = __builtin_amdgcn_mfma_f32_16x16x32_bf16(af1, bfr, acc[1][n], 0, 0, 0);
      }
    }
    __syncthreads();
  }
  const int crow = (lane >> 4) * 4;
  #pragma unroll
  for (int m = 0; m < 2; m++) {
    #pragma unroll
    for (int n = 0; n < 4; n++) {
      int col = w * 64 + n * 16 + lr;
      #pragma unroll
      for (int r = 0; r < 4; r++) {
        int row = n0 + m * 16 + crow + r;
        if (OBF) ((ushort*)OUTv)[(size_t)row * 256 + col] = f2bf(acc[m][n][r]);
        else     ((float*)OUTv)[(size_t)row * 256 + col] = acc[m][n][r];
      }
    }
  }
}

// ------------------------------------------------------------------
// K5: fused GATv2, direct-exp softmax (no running max; |logit| is small),
// 2-edge unrolled gathers, single accumulator set (5 short indep chains).
template <int CONCAT>
__global__ __launch_bounds__(256) void k_gat_fused(
    const ushort* __restrict__ xl, const float* __restrict__ xr,
    const float* __restrict__ we, const float* __restrict__ att,
    const int* __restrict__ srcs, const float* __restrict__ ea_csr,
    const int* __restrict__ row_ptr,
    const float* __restrict__ bias, const float* __restrict__ bng,
    const float* __restrict__ bnb, void* __restrict__ outp) {
  const int lane = threadIdx.x & 63;
  const int w = threadIdx.x >> 6;
  const int i = blockIdx.x * 4 + w;
  const int c0 = lane * 4;

  const float4 attv = *(const float4*)&att[c0];
  const float4 we0 = *(const float4*)&we[0 * HC + c0];
  const float4 we1 = *(const float4*)&we[1 * HC + c0];
  const float4 we2 = *(const float4*)&we[2 * HC + c0];
  const float4 we3 = *(const float4*)&we[3 * HC + c0];
  const float4 xrd = *(const float4*)&xr[(size_t)i * HC + c0];

  const int start = row_ptr[i];
  const int deg = row_ptr[i + 1] - start;

  float dn = 0.f, acc0 = 0.f, acc1 = 0.f, acc2 = 0.f, acc3 = 0.f;

  for (int base = 0; base < deg; base += 64) {
    int rem = deg - base;
    if (rem > 64) rem = 64;
    int sv = 0;
    if (lane < rem) sv = srcs[start + base + lane];
    int jj = 0;
    for (; jj + 2 <= rem; jj += 2) {
      int s0 = __shfl(sv, jj) & 0x7fffffff;
      int s1 = __shfl(sv, jj + 1) & 0x7fffffff;
      float4 a0 = *(const float4*)&ea_csr[(size_t)(start + base + jj) * 4];
      float4 a1 = *(const float4*)&ea_csr[(size_t)(start + base + jj + 1) * 4];
      ushort4 u0 = *(const ushort4*)&xl[(size_t)s0 * HC + c0];
      ushort4 u1 = *(const ushort4*)&xl[(size_t)s1 * HC + c0];
      float x0x = bf2f(u0.x), x0y = bf2f(u0.y), x0z = bf2f(u0.z), x0w = bf2f(u0.w);
      float x1x = bf2f(u1.x), x1y = bf2f(u1.y), x1z = bf2f(u1.z), x1w = bf2f(u1.w);
      // ---- edge 0 ----
      {
        float m0 = x0x + xrd.x + a0.x * we0.x + a0.y * we1.x + a0.z * we2.x + a0.w * we3.x;
        float m1 = x0y + xrd.y + a0.x * we0.y + a0.y * we1.y + a0.z * we2.y + a0.w * we3.y;
        float m2 = x0z + xrd.z + a0.x * we0.z + a0.y * we1.z + a0.z * we2.z + a0.w * we3.z;
        float m3 = x0w + xrd.w + a0.x * we0.w + a0.y * we1.w + a0.z * we2.w + a0.w * we3.w;
        m0 = fmaxf(m0, NEG_SLOPE * m0);
        m1 = fmaxf(m1, NEG_SLOPE * m1);
        m2 = fmaxf(m2, NEG_SLOPE * m2);
        m3 = fmaxf(m3, NEG_SLOPE * m3);
        float lg = m0 * attv.x + m1 * attv.y + m2 * attv.z + m3 * attv.w;
        lg += __shfl_xor(lg, 1);
        lg += __shfl_xor(lg, 2);
        lg += __shfl_xor(lg, 4);
        lg += __shfl_xor(lg, 8);
        float p = __expf(lg);
        dn += p;
        acc0 = fmaf(p, x0x, acc0);
        acc1 = fmaf(p, x0y, acc1);
        acc2 = fmaf(p, x0z, acc2);
        acc3 = fmaf(p, x0w, acc3);
      }
      // ---- edge 1 ----
      {
        float m0 = x1x + xrd.x + a1.x * we0.x + a1.y * we1.x + a1.z * we2.x + a1.w * we3.x;
        float m1 = x1y + xrd.y + a1.x * we0.y + a1.y * we1.y + a1.z * we2.y + a1.w * we3.y;
        float m2 = x1z + xrd.z + a1.x * we0.z + a1.y * we1.z + a1.z * we2.z + a1.w * we3.z;
        float m3 = x1w + xrd.w + a1.x * we0.w + a1.y * we1.w + a1.z * we2.w + a1.w * we3.w;
        m0 = fmaxf(m0, NEG_SLOPE * m0);
        m1 = fmaxf(m1, NEG_SLOPE * m1);
        m2 = fmaxf(m2, NEG_SLOPE * m2);
        m3 = fmaxf(m3, NEG_SLOPE * m3);
        float lg = m0 * attv.x + m1 * attv.y + m2 * attv.z + m3 * attv.w;
        lg += __shfl_xor(lg, 1);
        lg += __shfl_xor(lg, 2);
        lg += __shfl_xor(lg, 4);
        lg += __shfl_xor(lg, 8);
        float p = __expf(lg);
        dn += p;
        acc0 = fmaf(p, x1x, acc0);
        acc1 = fmaf(p, x1y, acc1);
        acc2 = fmaf(p, x1z, acc2);
        acc3 = fmaf(p, x1w, acc3);
      }
    }
    if (jj < rem) {   // tail edge
      int s0 = __shfl(sv, jj) & 0x7fffffff;
      float4 a0 = *(const float4*)&ea_csr[(size_t)(start + base + jj) * 4];
      ushort4 u0 = *(const ushort4*)&xl[(size_t)s0 * HC + c0];
      float x0x = bf2f(u0.x), x0y = bf2f(u0.y), x0z = bf2f(u0.z), x0w = bf2f(u0.w);
      float m0 = x0x + xrd.x + a0.x * we0.x + a0.y * we1.x + a0.z * we2.x + a0.w * we3.x;
      float m1 = x0y + xrd.y + a0.x * we0.y + a0.y * we1.y + a0.z * we2.y + a0.w * we3.y;
      float m2 = x0z + xrd.z + a0.x * we0.z + a0.y * we1.z + a0.z * we2.z + a0.w * we3.z;
      float m3 = x0w + xrd.w + a0.x * we0.w + a0.y * we1.w + a0.z * we2.w + a0.w * we3.w;
      m0 = fmaxf(m0, NEG_SLOPE * m0);
      m1 = fmaxf(m1, NEG_SLOPE * m1);
      m2 = fmaxf(m2, NEG_SLOPE * m2);
      m3 = fmaxf(m3, NEG_SLOPE * m3);
      float lg = m0 * attv.x + m1 * attv.y + m2 * attv.z + m3 * attv.w;
      lg += __shfl_xor(lg, 1);
      lg += __shfl_xor(lg, 2);
      lg += __shfl_xor(lg, 4);
      lg += __shfl_xor(lg, 8);
      float p = __expf(lg);
      dn += p;
      acc0 = fmaf(p, x0x, acc0);
      acc1 = fmaf(p, x0y, acc1);
      acc2 = fmaf(p, x0z, acc2);
      acc3 = fmaf(p, x0w, acc3);
    }
  }

  float rinv = 1.f / dn;
  acc0 *= rinv; acc1 *= rinv; acc2 *= rinv; acc3 *= rinv;

  const float inv_sqrt = rsqrtf(1.f + BN_EPS);
  if (CONCAT) {
    float4 bi = *(const float4*)&bias[c0];
    float4 g = *(const float4*)&bng[c0];
    float4 bb = *(const float4*)&bnb[c0];
    float v0 = (acc0 + bi.x) * (g.x * inv_sqrt) + bb.x;
    float v1 = (acc1 + bi.y) * (g.y * inv_sqrt) + bb.y;
    float v2 = (acc2 + bi.z) * (g.z * inv_sqrt) + bb.z;
    float v3 = (acc3 + bi.w) * (g.w * inv_sqrt) + bb.w;
    v0 = (v0 > 0.f) ? v0 : (__expf(v0) - 1.f);
    v1 = (v1 > 0.f) ? v1 : (__expf(v1) - 1.f);
    v2 = (v2 > 0.f) ? v2 : (__expf(v2) - 1.f);
    v3 = (v3 > 0.f) ? v3 : (__expf(v3) - 1.f);
    ushort* op = (ushort*)outp;                      // h1 stored bf16 for MFMA
    ushort4 o = {f2bf(v0), f2bf(v1), f2bf(v2), f2bf(v3)};
    *(ushort4*)&op[(size_t)i * HC + c0] = o;
  } else {
    acc0 += __shfl_xor(acc0, 16); acc0 += __shfl_xor(acc0, 32);
    acc1 += __shfl_xor(acc1, 16); acc1 += __shfl_xor(acc1, 32);
    acc2 += __shfl_xor(acc2, 16); acc2 += __shfl_xor(acc2, 32);
    acc3 += __shfl_xor(acc3, 16); acc3 += __shfl_xor(acc3, 32);
    if (lane < 16) {
      int cc = lane * 4;
      float4 bi = *(const float4*)&bias[cc];
      float4 g = *(const float4*)&bng[cc];
      float4 bb = *(const float4*)&bnb[cc];
      float v0 = (0.25f * acc0 + bi.x) * (g.x * inv_sqrt) + bb.x;
      float v1 = (0.25f * acc1 + bi.y) * (g.y * inv_sqrt) + bb.y;
      float v2 = (0.25f * acc2 + bi.z) * (g.z * inv_sqrt) + bb.z;
      float v3 = (0.25f * acc3 + bi.w) * (g.w * inv_sqrt) + bb.w;
      v0 = (v0 > 0.f) ? v0 : (__expf(v0) - 1.f);
      v1 = (v1 > 0.f) ? v1 : (__expf(v1) - 1.f);
      v2 = (v2 > 0.f) ? v2 : (__expf(v2) - 1.f);
      v3 = (v3 > 0.f) ? v3 : (__expf(v3) - 1.f);
      float* op = (float*)outp;
      float4 o = {v0, v1, v2, v3};
      *(float4*)&op[(size_t)i * 64 + cc] = o;
    }
  }
}

// ------------------------------------------------------------------
// K8: fused SAGE, prefetched srcs + 4 independent streams.
__global__ __launch_bounds__(256) void k_sage(
    const float* __restrict__ h2, const int* __restrict__ row_ptr,
    const int* __restrict__ srcs, const unsigned* __restrict__ cnt,
    const float* __restrict__ wl, const float* __restrict__ bl,
    const float* __restrict__ wr, const float* __restrict__ bng,
    const float* __restrict__ bnb, float* __restrict__ h3) {
  __shared__ float agg_s[4][64];
  __shared__ float h2_s[4][64];
  int lane = threadIdx.x & 63;
  int w = threadIdx.x >> 6;
  int i = blockIdx.x * 4 + w;
  int start = row_ptr[i];
  int nreal = row_ptr[i + 1] - 1 - start;
  float a0 = 0.f, a1 = 0.f, a2 = 0.f, a3 = 0.f;
  for (int base = 0; base < nreal; base += 64) {
    int rem = nreal - base;
    if (rem > 64) rem = 64;
    int sv = 0;
    if (lane < rem) sv = srcs[start + base + lane];
    int jj = 0;
    for (; jj + 4 <= rem; jj += 4) {
      int s0 = __shfl(sv, jj);
      int s1 = __shfl(sv, jj + 1);
      int s2 = __shfl(sv, jj + 2);
      int s3 = __shfl(sv, jj + 3);
      a0 += h2[(size_t)s0 * 64 + lane];
      a1 += h2[(size_t)s1 * 64 + lane];
      a2 += h2[(size_t)s2 * 64 + lane];
      a3 += h2[(size_t)s3 * 64 + lane];
    }
    for (; jj < rem; ++jj) {
      int s0 = __shfl(sv, jj);
      a0 += h2[(size_t)s0 * 64 + lane];
    }
  }
  float a = (a0 + a1) + (a2 + a3);
  float c = (float)cnt[i];
  if (c < 1.f) c = 1.f;
  agg_s[w][lane] = a / c;
  h2_s[w][lane] = h2[(size_t)i * 64 + lane];
  __syncthreads();
  float s = bl[lane];
  #pragma unroll 4
  for (int k = 0; k < 64; k++)
    s += agg_s[w][k] * wl[k * 64 + lane] + h2_s[w][k] * wr[k * 64 + lane];
  s = s * (bng[lane] * rsqrtf(1.f + BN_EPS)) + bnb[lane];
  s = fmaxf(s, 0.f);
  h3[(size_t)i * 64 + lane] = s;
}

// ------------------------------------------------------------------
__global__ __launch_bounds__(256) void k_pool(
    const float* __restrict__ h3, const int* __restrict__ batch,
    float* __restrict__ psum, float* __restrict__ pmax, float* __restrict__ pcnt) {
  int j = threadIdx.x & 63, grp = threadIdx.x >> 6;
  int nbase = blockIdx.x * 256 + grp * 64;
  float s = 0.f, m = 0.f, cn = 0.f;
  int cur = -1;
  for (int t = 0; t < 64; t++) {
    int n = nbase + t;
    if (n >= NN) break;
    int g = batch[n];
    if (g != cur) {
      if (cur >= 0) {
        atomicAdd(&psum[cur * 64 + j], s);
        atomicMax((int*)&pmax[cur * 64 + j], __float_as_int(m));
        if (j == 0) atomicAdd(&pcnt[cur], cn);
      }
      cur = g; s = 0.f; m = 0.f; cn = 0.f;
    }
    float v = h3[(size_t)n * 64 + j];
    s += v; m = fmaxf(m, v); cn += 1.f;
  }
  if (cur >= 0) {
    atomicAdd(&psum[cur * 64 + j], s);
    atomicMax((int*)&pmax[cur * 64 + j], __float_as_int(m));
    if (j == 0) atomicAdd(&pcnt[cur], cn);
  }
}

// ------------------------------------------------------------------
__global__ void k_graph_head(
    const float* __restrict__ psum, const float* __restrict__ pmax,
    const float* __restrict__ pcnt,
    const float* __restrict__ w1, const float* __restrict__ b1,
    const float* __restrict__ w2, const float* __restrict__ b2,
    const float* __restrict__ w3, const float* __restrict__ b3,
    float* __restrict__ out) {
  __shared__ float hp[128];
  __shared__ float z1[64];
  __shared__ float z2[32];
  int g = blockIdx.x, j = threadIdx.x;
  float c = pcnt[g];
  if (c < 1.f) c = 1.f;
  hp[j] = psum[g * 64 + j] / c;
  hp[64 + j] = pmax[g * 64 + j];
  __syncthreads();
  float s = b1[j];
  #pragma unroll 8
  for (int k = 0; k < 128; k++) s += hp[k] * w1[k * 64 + j];
  z1[j] = fmaxf(s, 0.f);
  __syncthreads();
  if (j < 32) {
    float s2 = b2[j];
    #pragma unroll 8
    for (int k = 0; k < 64; k++) s2 += z1[k] * w2[k * 32 + j];
    z2[j] = fmaxf(s2, 0.f);
  }
  __syncthreads();
  if (j == 0) {
    float s3 = b3[0];
    #pragma unroll
    for (int k = 0; k < 32; k++) s3 += z2[k] * w3[k];
    out[g] = 1.f / (1.f + expf(-s3));
  }
}

// ------------------------------------------------------------------
__global__ __launch_bounds__(256) void k_edge_head(
    const float* __restrict__ h3, const int* __restrict__ ei,
    const float* __restrict__ ea,
    const float* __restrict__ w1, const float* __restrict__ b1,
    const float* __restrict__ w2, const float* __restrict__ b2,
    float* __restrict__ out) {
  int e = blockIdx.x * 256 + threadIdx.x;
  if (e >= NE) return;
  int s = ei[e], d = ei[NE + e];
  float acc[32];
  #pragma unroll
  for (int j = 0; j < 32; j++) acc[j] = b1[j];
  const float4* hs = (const float4*)&h3[(size_t)s * 64];
  const float4* hd = (const float4*)&h3[(size_t)d * 64];
  for (int k4 = 0; k4 < 16; k4++) {
    float4 v = hs[k4];
    const float* w = &w1[k4 * 4 * 32];
    #pragma unroll
    for (int j = 0; j < 32; j++) acc[j] += v.x * w[j];
    #pragma unroll
    for (int j = 0; j < 32; j++) acc[j] += v.y * w[32 + j];
    #pragma unroll
    for (int j = 0; j < 32; j++) acc[j] += v.z * w[64 + j];
    #pragma unroll
    for (int j = 0; j < 32; j++) acc[j] += v.w * w[96 + j];
  }
  for (int k4 = 0; k4 < 16; k4++) {
    float4 v = hd[k4];
    const float* w = &w1[(64 + k4 * 4) * 32];
    #pragma unroll
    for (int j = 0; j < 32; j++) acc[j] += v.x * w[j];
    #pragma unroll
    for (int j = 0; j < 32; j++) acc[j] += v.y * w[32 + j];
    #pragma unroll
    for (int j = 0; j < 32; j++) acc[j] += v.z * w[64 + j];
    #pragma unroll
    for (int j = 0; j < 32; j++) acc[j] += v.w * w[96 + j];
  }
  {
    float4 v = *(const float4*)&ea[(size_t)e * 4];
    const float* w = &w1[128 * 32];
    #pragma unroll
    for (int j = 0; j < 32; j++) acc[j] += v.x * w[j];
    #pragma unroll
    for (int j = 0; j < 32; j++) acc[j] += v.y * w[32 + j];
    #pragma unroll
    for (int j = 0; j < 32; j++) acc[j] += v.z * w[64 + j];
    #pragma unroll
    for (int j = 0; j < 32; j++) acc[j] += v.w * w[96 + j];
  }
  float s2 = b2[0];
  #pragma unroll
  for (int j = 0; j < 32; j++) s2 += fmaxf(acc[j], 0.f) * w2[j];
  out[e] = 1.f / (1.f + expf(-s2));
}

// ------------------------------------------------------------------
extern "C" void kernel_launch(void* const* d_in, const int* in_sizes, int n_in,
                              void* d_out, int out_size, void* d_ws, size_t ws_size,
                              hipStream_t stream) {
  const float* x         = (const float*)d_in[0];
  const float* edge_attr = (const float*)d_in[1];
  const float* enc_w1 = (const float*)d_in[2];
  const float* enc_b1 = (const float*)d_in[3];
  const float* enc_w2 = (const float*)d_in[4];
  const float* enc_b2 = (const float*)d_in[5];
  const float* g1_wl = (const float*)d_in[6];
  const float* g1_wr = (const float*)d_in[7];
  const float* g1_we = (const float*)d_in[8];
  const float* g1_att = (const float*)d_in[9];
  const float* g1_b = (const float*)d_in[10];
  const float* bn1_g = (const float*)d_in[11];
  const float* bn1_b = (const float*)d_in[12];
  const float* g2_wl = (const float*)d_in[13];
  const float* g2_wr = (const float*)d_in[14];
  const float* g2_we = (const float*)d_in[15];
  const float* g2_att = (const float*)d_in[16];
  const float* g2_b = (const float*)d_in[17];
  const float* bn2_g = (const float*)d_in[18];
  const float* bn2_b = (const float*)d_in[19];
  const float* sage_wl = (const float*)d_in[20];
  const float* sage_bl = (const float*)d_in[21];
  const float* sage_wr = (const float*)d_in[22];
  const float* bn3_g = (const float*)d_in[23];
  const float* bn3_b = (const float*)d_in[24];
  const float* gh_w1 = (const float*)d_in[25];
  const float* gh_b1 = (const float*)d_in[26];
  const float* gh_w2 = (const float*)d_in[27];
  const float* gh_b2 = (const float*)d_in[28];
  const float* gh_w3 = (const float*)d_in[29];
  const float* gh_b3 = (const float*)d_in[30];
  const float* eh_w1 = (const float*)d_in[31];
  const float* eh_b1 = (const float*)d_in[32];
  const float* eh_w2 = (const float*)d_in[33];
  const float* eh_b2 = (const float*)d_in[34];
  const int* ei    = (const int*)d_in[35];
  const int* batch = (const int*)d_in[36];
  float* out = (float*)d_out;

  float* ws = (float*)d_ws;
  ushort* xlbf = (ushort*)(ws + OFF_XL);
  float* xr = ws + OFF_XR;
  ushort* h1bf = (ushort*)(ws + OFF_H1);
  ushort* wtl = (ushort*)(ws + OFF_WTL);
  ushort* wtr = (ushort*)(ws + OFF_WTR);
  float* h0 = ws + OFF_H0;   // later h2
  float* h3 = ws + OFF_H3;
  unsigned* cnt = (unsigned*)(ws + OFF_CNT);
  float* psum = ws + OFF_PSUM;
  float* pmax = ws + OFF_PMAX;
  float* pcnt = ws + OFF_PCNT;
  float* ea_csr = ws + OFF_EACSR;
  int* row_ptr = (int*)(ws + OFF_RP);
  int* srcs = (int*)(ws + OFF_SRC);
  int* bsums = (int*)(ws + OFF_BSUM);
  int* rank = (int*)(ws + OFF_XL);   // transient: xl region unused until GEMMs

  hipMemsetAsync(ws + OFF_ZERO, 0, ZERO_FLOATS * sizeof(float), stream);

  k_count<<<NE / 256, 256, 0, stream>>>(ei, cnt, rank);
  k_cast_wt<<<512, 256, 0, stream>>>(g2_wl, g2_wr, wtl, wtr);
  k_encoder<<<NN / (4 * ENC_NPW), 256, 0, stream>>>(x, enc_w1, enc_b1, enc_w2, enc_b2, h0);
  k_scan_blk<<<SCAN_NB, 256, 0, stream>>>(cnt, row_ptr, bsums);
  k_scan_add<<<SCAN_NB, 256, 0, stream>>>(bsums, row_ptr);
  k_csr_scatter<<<NE / 256, 256, 0, stream>>>(ei, rank, row_ptr, edge_attr, srcs, ea_csr);
  k_loop_row<<<(NN + 255) / 256, 256, 0, stream>>>(row_ptr, srcs, ea_csr);

  // ---- GAT layer 1 (fp32 vector GEMMs, K=64) ----
  k_gemm256<64, 1><<<NN / 32, 256, 0, stream>>>(h0, g1_wl, (void*)xlbf);
  k_gemm256<64, 0><<<NN / 32, 256, 0, stream>>>(h0, g1_wr, (void*)xr);
  k_gat_fused<1><<<NN / 4, 256, 0, stream>>>(xlbf, xr, g1_we, g1_att, srcs, ea_csr,
                                             row_ptr, g1_b, bn1_g, bn1_b, (void*)h1bf);

  // ---- GAT layer 2 (MFMA bf16 GEMMs, K=256) ----
  k_gemm_mfma<1><<<NN / 32, 256, 0, stream>>>(h1bf, wtl, (void*)xlbf);
  k_gemm_mfma<0><<<NN / 32, 256, 0, stream>>>(h1bf, wtr, (void*)xr);
  k_gat_fused<0><<<NN / 4, 256, 0, stream>>>(xlbf, xr, g2_we, g2_att, srcs, ea_csr,
                                             row_ptr, g2_b, bn2_g, bn2_b, (void*)h0);

  // ---- SAGE ----
  k_sage<<<NN / 4, 256, 0, stream>>>(h0, row_ptr, srcs, cnt, sage_wl, sage_bl, sage_wr, bn3_g, bn3_b, h3);

  // ---- pooling + heads ----
  k_pool<<<(NN + 255) / 256, 256, 0, stream>>>(h3, batch, psum, pmax, pcnt);
  k_graph_head<<<NG, 64, 0, stream>>>(psum, pmax, pcnt, gh_w1, gh_b1, gh_w2, gh_b2, gh_w3, gh_b3, out);
  k_edge_head<<<NE / 256, 256, 0, stream>>>(h3, ei, edge_attr, eh_w1, eh_b1, eh_w2, eh_b2, out + NG);
}

// Round 9
// 353.091 us; speedup vs baseline: 2.9269x; 1.0173x over previous
//
#include <hip/hip_runtime.h>

#define NN 20000
#define NE 320000
#define EP (NE + NN)          // 340000 edges incl. self loops
#define NG 8
#define HC 256
#define NODE_IN 18
#define HID 64
#define NEG_SLOPE 0.2f
#define BN_EPS 1e-5f

// ---------------- workspace layout (float offsets) ----------------
#define OFF_XL    0u                      // bf16 [NN*256]; also rank[NE] during CSR build
#define OFF_XR    5120000u                // fp32 [NN*256]
#define OFF_H1    10240000u               // bf16 [NN*256] -> ends at 12800000
#define OFF_WTL   12800000u               // bf16 [256*256] n-major (g2_wl^T)
#define OFF_WTR   12832768u               // bf16 [256*256] n-major (g2_wr^T)
#define OFF_H0    15360000u               // fp32 [NN*64]  (h0, later reused as h2)
#define OFF_H3    16640000u               // fp32 [NN*64]
#define OFF_ZERO  18000000u               // start of zeroed region
#define OFF_CNT   18000000u               // uint cnt [NN]
#define OFF_PSUM  18020000u               // [8*64]
#define OFF_PMAX  18020512u               // [8*64]
#define OFF_PCNT  18021024u               // [16]
#define ZERO_FLOATS (18021040u - 18000000u)
#define OFF_EACSR 18021040u               // [EP*4] CSR-ordered edge attrs
#define OFF_RP    19381040u               // int [NN+1]
#define OFF_SRC   19421041u               // int [EP] (self-loop = LAST slot of row, sign bit)
#define OFF_BSUM  19761056u               // int [32]

#define SCAN_ELEM 1024
#define SCAN_NB ((NN + SCAN_ELEM - 1) / SCAN_ELEM)   // 20

typedef __attribute__((ext_vector_type(8))) short bf16x8_t;
typedef __attribute__((ext_vector_type(4))) float f32x4_t;

__device__ __forceinline__ ushort f2bf(float f) {   // RNE float->bf16
  unsigned u = __float_as_uint(f);
  unsigned r = (u + 0x7fffu + ((u >> 16) & 1u)) >> 16;
  return (ushort)r;
}
__device__ __forceinline__ float bf2f(ushort b) {
  return __uint_as_float(((unsigned)b) << 16);
}

// ------------------------------------------------------------------
// K1: per-dst edge count; returned old value = rank within dst row.
__global__ __launch_bounds__(256) void k_count(
    const int* __restrict__ ei, unsigned* __restrict__ cnt, int* __restrict__ rank) {
  int e = blockIdx.x * 256 + threadIdx.x;
  if (e >= NE) return;
  int d = ei[NE + e];
  rank[e] = (int)atomicAdd(&cnt[d], 1u);
}

// ------------------------------------------------------------------
// K_cast_wt: W[k][n] fp32 -> Wt[n][k] bf16 (both g2 weight matrices)
__global__ __launch_bounds__(256) void k_cast_wt(
    const float* __restrict__ Wl, const float* __restrict__ Wr,
    ushort* __restrict__ WtL, ushort* __restrict__ WtR) {
  int b = blockIdx.x;
  const float* W = (b < 256) ? Wl : Wr;
  ushort* Wt = (b < 256) ? WtL : WtR;
  int k = b & 255;
  int n = threadIdx.x;
  Wt[n * 256 + k] = f2bf(W[k * 256 + n]);
}

// ------------------------------------------------------------------
// K3: encoder, wave-per-node (lane = channel).
#define ENC_NPW 4
__global__ __launch_bounds__(256) void k_encoder(
    const float* __restrict__ x, const float* __restrict__ w1, const float* __restrict__ b1,
    const float* __restrict__ w2, const float* __restrict__ b2, float* __restrict__ h0) {
  __shared__ float W1[NODE_IN * HID];
  __shared__ float W2[HID * HID];
  __shared__ float B1s[HID];
  __shared__ float B2s[HID];
  __shared__ float hid_s[4][HID];
  const int tid = threadIdx.x;
  for (int i = tid; i < NODE_IN * HID; i += 256) W1[i] = w1[i];
  for (int i = tid; i < HID * HID; i += 256) W2[i] = w2[i];
  if (tid < HID) { B1s[tid] = b1[tid]; B2s[tid] = b2[tid]; }
  __syncthreads();
  const int lane = tid & 63;
  const int w = tid >> 6;
  #pragma unroll
  for (int t = 0; t < ENC_NPW; t++) {
    const int n = blockIdx.x * (4 * ENC_NPW) + w * ENC_NPW + t;
    const float* xp = &x[(size_t)n * NODE_IN];
    float s = B1s[lane];
    #pragma unroll
    for (int i = 0; i < NODE_IN; i++) s += xp[i] * W1[i * HID + lane];
    hid_s[w][lane] = fmaxf(s, 0.f);
    float o = B2s[lane];
    #pragma unroll 8
    for (int k = 0; k < HID; k++) o += hid_s[w][k] * W2[k * HID + lane];
    h0[(size_t)n * HID + lane] = o;
  }
}

// ------------------------------------------------------------------
__global__ __launch_bounds__(256) void k_scan_blk(
    const unsigned* __restrict__ cnt, int* __restrict__ row_ptr, int* __restrict__ bsums) {
  __shared__ int wsum[4];
  const int tid = threadIdx.x, lane = tid & 63, w = tid >> 6;
  const int i0 = blockIdx.x * SCAN_ELEM + tid * 4;
  int v0 = (i0 + 0 < NN) ? ((int)cnt[i0 + 0] + 1) : 0;
  int v1 = (i0 + 1 < NN) ? ((int)cnt[i0 + 1] + 1) : 0;
  int v2 = (i0 + 2 < NN) ? ((int)cnt[i0 + 2] + 1) : 0;
  int v3 = (i0 + 3 < NN) ? ((int)cnt[i0 + 3] + 1) : 0;
  int tsum = v0 + v1 + v2 + v3;
  int incl = tsum;
  #pragma unroll
  for (int off = 1; off < 64; off <<= 1) {
    int t = __shfl_up(incl, off);
    if (lane >= off) incl += t;
  }
  if (lane == 63) wsum[w] = incl;
  __syncthreads();
  int p = incl - tsum;
  #pragma unroll
  for (int k = 0; k < 4; k++) if (k < w) p += wsum[k];
  if (i0 + 0 < NN) row_ptr[i0 + 0] = p;
  if (i0 + 1 < NN) row_ptr[i0 + 1] = p + v0;
  if (i0 + 2 < NN) row_ptr[i0 + 2] = p + v0 + v1;
  if (i0 + 3 < NN) row_ptr[i0 + 3] = p + v0 + v1 + v2;
  if (tid == 0) bsums[blockIdx.x] = wsum[0] + wsum[1] + wsum[2] + wsum[3];
}

__global__ __launch_bounds__(256) void k_scan_add(
    const int* __restrict__ bsums, int* __restrict__ row_ptr) {
  const int b = blockIdx.x, tid = threadIdx.x;
  int off = 0;
  for (int j = 0; j < b; j++) off += bsums[j];
  const int i0 = b * SCAN_ELEM + tid * 4;
  #pragma unroll
  for (int k = 0; k < 4; k++) {
    int i = i0 + k;
    if (i < NN) row_ptr[i] += off;
  }
  if (b == 0 && tid == 0) row_ptr[NN] = EP;
}

__global__ __launch_bounds__(256) void k_csr_scatter(
    const int* __restrict__ ei, const int* __restrict__ rank,
    const int* __restrict__ row_ptr, const float* __restrict__ ea,
    int* __restrict__ srcs, float* __restrict__ ea_csr) {
  int e = blockIdx.x * 256 + threadIdx.x;
  if (e >= NE) return;
  int s = ei[e], d = ei[NE + e];
  int p = row_ptr[d] + rank[e];
  srcs[p] = s;
  *(float4*)&ea_csr[(size_t)p * 4] = *(const float4*)&ea[(size_t)e * 4];
}

__global__ __launch_bounds__(256) void k_loop_row(
    const int* __restrict__ row_ptr, int* __restrict__ srcs, float* __restrict__ ea_csr) {
  int i = blockIdx.x * 256 + threadIdx.x;
  if (i >= NN) return;
  int start = row_ptr[i], last = row_ptr[i + 1] - 1;
  float sx = 0.f, sy = 0.f, sz = 0.f, sw = 0.f;
  for (int j = start; j < last; ++j) {
    float4 a = *(const float4*)&ea_csr[(size_t)j * 4];
    sx += a.x; sy += a.y; sz += a.z; sw += a.w;
  }
  float c = (float)(last - start);
  if (c < 1.f) c = 1.f;
  float rc = 1.f / c;
  float4 o = {sx * rc, sy * rc, sz * rc, sw * rc};
  *(float4*)&ea_csr[(size_t)last * 4] = o;
  srcs[last] = i | (int)0x80000000;
}

// ------------------------------------------------------------------
// K4: fp32 vector GEMM (layer-1, K=64): OUT[NN][256] = A[NN][K]@W[K][256]
template <int K, int OBF>
__global__ __launch_bounds__(256) void k_gemm256(
    const float* __restrict__ A, const float* __restrict__ W, void* __restrict__ OUTv) {
  __shared__ float Wl[32 * 256];
  __shared__ float Al[32 * 36];
  const int tid = threadIdx.x;
  const int n0 = blockIdx.x * 32;
  const int tx = tid & 63, ty = tid >> 6;
  float acc[8][4];
  #pragma unroll
  for (int m = 0; m < 8; m++)
    #pragma unroll
    for (int c = 0; c < 4; c++) acc[m][c] = 0.f;

  for (int kt = 0; kt < K; kt += 32) {
    #pragma unroll
    for (int r = 0; r < 8; r++) {
      int i4 = tid + 256 * r;
      int row = i4 >> 6;
      int col4 = (i4 & 63) * 4;
      *(float4*)&Wl[row * 256 + col4] = *(const float4*)&W[(size_t)(kt + row) * 256 + col4];
    }
    {
      int m = tid >> 3, kk = (tid & 7) * 4;
      float4 av = *(const float4*)&A[(size_t)(n0 + m) * K + kt + kk];
      Al[(kk + 0) * 36 + m] = av.x;
      Al[(kk + 1) * 36 + m] = av.y;
      Al[(kk + 2) * 36 + m] = av.z;
      Al[(kk + 3) * 36 + m] = av.w;
    }
    __syncthreads();
    #pragma unroll 8
    for (int k = 0; k < 32; k++) {
      float4 b = *(float4*)&Wl[k * 256 + tx * 4];
      float4 a0v = *(float4*)&Al[k * 36 + ty * 8];
      float4 a1v = *(float4*)&Al[k * 36 + ty * 8 + 4];
      float am[8] = {a0v.x, a0v.y, a0v.z, a0v.w, a1v.x, a1v.y, a1v.z, a1v.w};
      #pragma unroll
      for (int m = 0; m < 8; m++) {
        acc[m][0] += am[m] * b.x;
        acc[m][1] += am[m] * b.y;
        acc[m][2] += am[m] * b.z;
        acc[m][3] += am[m] * b.w;
      }
    }
    __syncthreads();
  }
  if (OBF) {
    ushort* OUT = (ushort*)OUTv;
    #pragma unroll
    for (int m = 0; m < 8; m++) {
      ushort4 o = {f2bf(acc[m][0]), f2bf(acc[m][1]), f2bf(acc[m][2]), f2bf(acc[m][3])};
      *(ushort4*)&OUT[(size_t)(n0 + ty * 8 + m) * 256 + tx * 4] = o;
    }
  } else {
    float* OUT = (float*)OUTv;
    #pragma unroll
    for (int m = 0; m < 8; m++) {
      float4 o = {acc[m][0], acc[m][1], acc[m][2], acc[m][3]};
      *(float4*)&OUT[(size_t)(n0 + ty * 8 + m) * 256 + tx * 4] = o;
    }
  }
}

// ------------------------------------------------------------------
// K4b: MFMA bf16 GEMM (layer-2, K=256): OUT[NN][256] = A[NN][256] @ W[256][256]
template <int OBF>
__global__ __launch_bounds__(256) void k_gemm_mfma(
    const ushort* __restrict__ A, const ushort* __restrict__ Wt, void* __restrict__ OUTv) {
  __shared__ ushort Asub[32][72];
  __shared__ ushort Wsub[256][72];
  const int tid = threadIdx.x;
  const int lane = tid & 63;
  const int w = tid >> 6;
  const int n0 = blockIdx.x * 32;
  const int lr = lane & 15;
  const int lk = (lane >> 4) * 8;

  f32x4_t acc[2][4];
  #pragma unroll
  for (int m = 0; m < 2; m++)
    #pragma unroll
    for (int n = 0; n < 4; n++) acc[m][n] = (f32x4_t){0.f, 0.f, 0.f, 0.f};

  for (int kt = 0; kt < 256; kt += 64) {
    {
      int r = tid >> 3, seg = (tid & 7) * 8;
      *(uint4*)&Asub[r][seg] = *(const uint4*)&A[(size_t)(n0 + r) * 256 + kt + seg];
    }
    #pragma unroll
    for (int rep = 0; rep < 8; rep++) {
      int idx = rep * 256 + tid;
      int r = idx >> 3, seg = (idx & 7) * 8;
      *(uint4*)&Wsub[r][seg] = *(const uint4*)&Wt[(size_t)r * 256 + kt + seg];
    }
    __syncthreads();
    #pragma unroll
    for (int kk = 0; kk < 2; kk++) {
      bf16x8_t af0 = *(bf16x8_t*)&Asub[lr][kk * 32 + lk];
      bf16x8_t af1 = *(bf16x8_t*)&Asub[16 + lr][kk * 32 + lk];
      #pragma unroll
      for (int n = 0; n < 4; n++) {
        bf16x8_t bfr = *(bf16x8_t*)&Wsub[w * 64 + n * 16 + lr][kk * 32 + lk];
        acc[0][n] = __builtin_amdgcn_mfma_f32_16x16x32_bf16(af0, bfr, acc[0][n], 0, 0, 0);
        acc[1][n] = __builtin_amdgcn_mfma_f32_16x16x32_bf16(af1, bfr, acc[1][n], 0, 0, 0);
      }
    }
    __syncthreads();
  }
  const int crow = (lane >> 4) * 4;
  #pragma unroll
  for (int m = 0; m < 2; m++) {
    #pragma unroll
    for (int n = 0; n < 4; n++) {
      int col = w * 64 + n * 16 + lr;
      #pragma unroll
      for (int r = 0; r < 4; r++) {
        int row = n0 + m * 16 + crow + r;
        if (OBF) ((ushort*)OUTv)[(size_t)row * 256 + col] = f2bf(acc[m][n][r]);
        else     ((float*)OUTv)[(size_t)row * 256 + col] = acc[m][n][r];
      }
    }
  }
}

// ------------------------------------------------------------------
// Per-edge GAT compute body (direct exp, stream accumulators by reference)
__device__ __forceinline__ void gat_edge(
    float4 a, float xx, float xy, float xz, float xw,
    const float4& xrd, const float4& we0, const float4& we1,
    const float4& we2, const float4& we3, const float4& attv,
    float& dn, float& c0, float& c1, float& c2, float& c3) {
  float m0 = xx + xrd.x + a.x * we0.x + a.y * we1.x + a.z * we2.x + a.w * we3.x;
  float m1 = xy + xrd.y + a.x * we0.y + a.y * we1.y + a.z * we2.y + a.w * we3.y;
  float m2 = xz + xrd.z + a.x * we0.z + a.y * we1.z + a.z * we2.z + a.w * we3.z;
  float m3 = xw + xrd.w + a.x * we0.w + a.y * we1.w + a.z * we2.w + a.w * we3.w;
  m0 = fmaxf(m0, NEG_SLOPE * m0);
  m1 = fmaxf(m1, NEG_SLOPE * m1);
  m2 = fmaxf(m2, NEG_SLOPE * m2);
  m3 = fmaxf(m3, NEG_SLOPE * m3);
  float lg = m0 * attv.x + m1 * attv.y + m2 * attv.z + m3 * attv.w;
  lg += __shfl_xor(lg, 1);
  lg += __shfl_xor(lg, 2);
  lg += __shfl_xor(lg, 4);
  lg += __shfl_xor(lg, 8);
  float p = __expf(lg);
  dn += p;
  c0 = fmaf(p, xx, c0);
  c1 = fmaf(p, xy, c1);
  c2 = fmaf(p, xz, c2);
  c3 = fmaf(p, xw, c3);
}

// K5: fused GATv2, direct-exp softmax, dual streams + prefetch-ahead-1 pipeline.
template <int CONCAT>
__global__ __launch_bounds__(256) void k_gat_fused(
    const ushort* __restrict__ xl, const float* __restrict__ xr,
    const float* __restrict__ we, const float* __restrict__ att,
    const int* __restrict__ srcs, const float* __restrict__ ea_csr,
    const int* __restrict__ row_ptr,
    const float* __restrict__ bias, const float* __restrict__ bng,
    const float* __restrict__ bnb, void* __restrict__ outp) {
  const int lane = threadIdx.x & 63;
  const int w = threadIdx.x >> 6;
  const int i = blockIdx.x * 4 + w;
  const int c0 = lane * 4;

  const float4 attv = *(const float4*)&att[c0];
  const float4 we0 = *(const float4*)&we[0 * HC + c0];
  const float4 we1 = *(const float4*)&we[1 * HC + c0];
  const float4 we2 = *(const float4*)&we[2 * HC + c0];
  const float4 we3 = *(const float4*)&we[3 * HC + c0];
  const float4 xrd = *(const float4*)&xr[(size_t)i * HC + c0];

  const int start = row_ptr[i];
  const int deg = row_ptr[i + 1] - start;

  float dnA = 0.f, aA0 = 0.f, aA1 = 0.f, aA2 = 0.f, aA3 = 0.f;
  float dnB = 0.f, aB0 = 0.f, aB1 = 0.f, aB2 = 0.f, aB3 = 0.f;

  for (int base = 0; base < deg; base += 64) {
    int rem = deg - base;
    if (rem > 64) rem = 64;
    int sv = 0;
    if (lane < rem) sv = srcs[start + base + lane];
    const float4* eaB = (const float4*)&ea_csr[(size_t)(start + base) * 4];
    const int npair = rem >> 1;

    float4 pa0, pa1;
    ushort4 pu0, pu1;
    if (npair > 0) {
      int s0 = __shfl(sv, 0) & 0x7fffffff;
      int s1 = __shfl(sv, 1) & 0x7fffffff;
      pa0 = eaB[0];
      pa1 = eaB[1];
      pu0 = *(const ushort4*)&xl[(size_t)s0 * HC + c0];
      pu1 = *(const ushort4*)&xl[(size_t)s1 * HC + c0];
    }
    for (int p = 0; p < npair; p++) {
      float4 ca0 = pa0, ca1 = pa1;
      ushort4 cu0 = pu0, cu1 = pu1;
      if (p + 1 < npair) {                 // prefetch next pair
        int s0 = __shfl(sv, 2 * p + 2) & 0x7fffffff;
        int s1 = __shfl(sv, 2 * p + 3) & 0x7fffffff;
        pa0 = eaB[2 * p + 2];
        pa1 = eaB[2 * p + 3];
        pu0 = *(const ushort4*)&xl[(size_t)s0 * HC + c0];
        pu1 = *(const ushort4*)&xl[(size_t)s1 * HC + c0];
      }
      gat_edge(ca0, bf2f(cu0.x), bf2f(cu0.y), bf2f(cu0.z), bf2f(cu0.w),
               xrd, we0, we1, we2, we3, attv, dnA, aA0, aA1, aA2, aA3);
      gat_edge(ca1, bf2f(cu1.x), bf2f(cu1.y), bf2f(cu1.z), bf2f(cu1.w),
               xrd, we0, we1, we2, we3, attv, dnB, aB0, aB1, aB2, aB3);
    }
    if (rem & 1) {                          // tail edge -> stream A
      int jj = rem - 1;
      int s0 = __shfl(sv, jj) & 0x7fffffff;
      float4 a0 = eaB[jj];
      ushort4 u0 = *(const ushort4*)&xl[(size_t)s0 * HC + c0];
      gat_edge(a0, bf2f(u0.x), bf2f(u0.y), bf2f(u0.z), bf2f(u0.w),
               xrd, we0, we1, we2, we3, attv, dnA, aA0, aA1, aA2, aA3);
    }
  }

  float rinv = 1.f / (dnA + dnB);
  float acc0 = (aA0 + aB0) * rinv;
  float acc1 = (aA1 + aB1) * rinv;
  float acc2 = (aA2 + aB2) * rinv;
  float acc3 = (aA3 + aB3) * rinv;

  const float inv_sqrt = rsqrtf(1.f + BN_EPS);
  if (CONCAT) {
    float4 bi = *(const float4*)&bias[c0];
    float4 g = *(const float4*)&bng[c0];
    float4 bb = *(const float4*)&bnb[c0];
    float v0 = (acc0 + bi.x) * (g.x * inv_sqrt) + bb.x;
    float v1 = (acc1 + bi.y) * (g.y * inv_sqrt) + bb.y;
    float v2 = (acc2 + bi.z) * (g.z * inv_sqrt) + bb.z;
    float v3 = (acc3 + bi.w) * (g.w * inv_sqrt) + bb.w;
    v0 = (v0 > 0.f) ? v0 : (__expf(v0) - 1.f);
    v1 = (v1 > 0.f) ? v1 : (__expf(v1) - 1.f);
    v2 = (v2 > 0.f) ? v2 : (__expf(v2) - 1.f);
    v3 = (v3 > 0.f) ? v3 : (__expf(v3) - 1.f);
    ushort* op = (ushort*)outp;                      // h1 stored bf16 for MFMA
    ushort4 o = {f2bf(v0), f2bf(v1), f2bf(v2), f2bf(v3)};
    *(ushort4*)&op[(size_t)i * HC + c0] = o;
  } else {
    acc0 += __shfl_xor(acc0, 16); acc0 += __shfl_xor(acc0, 32);
    acc1 += __shfl_xor(acc1, 16); acc1 += __shfl_xor(acc1, 32);
    acc2 += __shfl_xor(acc2, 16); acc2 += __shfl_xor(acc2, 32);
    acc3 += __shfl_xor(acc3, 16); acc3 += __shfl_xor(acc3, 32);
    if (lane < 16) {
      int cc = lane * 4;
      float4 bi = *(const float4*)&bias[cc];
      float4 g = *(const float4*)&bng[cc];
      float4 bb = *(const float4*)&bnb[cc];
      float v0 = (0.25f * acc0 + bi.x) * (g.x * inv_sqrt) + bb.x;
      float v1 = (0.25f * acc1 + bi.y) * (g.y * inv_sqrt) + bb.y;
      float v2 = (0.25f * acc2 + bi.z) * (g.z * inv_sqrt) + bb.z;
      float v3 = (0.25f * acc3 + bi.w) * (g.w * inv_sqrt) + bb.w;
      v0 = (v0 > 0.f) ? v0 : (__expf(v0) - 1.f);
      v1 = (v1 > 0.f) ? v1 : (__expf(v1) - 1.f);
      v2 = (v2 > 0.f) ? v2 : (__expf(v2) - 1.f);
      v3 = (v3 > 0.f) ? v3 : (__expf(v3) - 1.f);
      float* op = (float*)outp;
      float4 o = {v0, v1, v2, v3};
      *(float4*)&op[(size_t)i * 64 + cc] = o;
    }
  }
}

// ------------------------------------------------------------------
// K8: fused SAGE, prefetched srcs + 4 independent streams.
__global__ __launch_bounds__(256) void k_sage(
    const float* __restrict__ h2, const int* __restrict__ row_ptr,
    const int* __restrict__ srcs, const unsigned* __restrict__ cnt,
    const float* __restrict__ wl, const float* __restrict__ bl,
    const float* __restrict__ wr, const float* __restrict__ bng,
    const float* __restrict__ bnb, float* __restrict__ h3) {
  __shared__ float agg_s[4][64];
  __shared__ float h2_s[4][64];
  int lane = threadIdx.x & 63;
  int w = threadIdx.x >> 6;
  int i = blockIdx.x * 4 + w;
  int start = row_ptr[i];
  int nreal = row_ptr[i + 1] - 1 - start;
  float a0 = 0.f, a1 = 0.f, a2 = 0.f, a3 = 0.f;
  for (int base = 0; base < nreal; base += 64) {
    int rem = nreal - base;
    if (rem > 64) rem = 64;
    int sv = 0;
    if (lane < rem) sv = srcs[start + base + lane];
    int jj = 0;
    for (; jj + 4 <= rem; jj += 4) {
      int s0 = __shfl(sv, jj);
      int s1 = __shfl(sv, jj + 1);
      int s2 = __shfl(sv, jj + 2);
      int s3 = __shfl(sv, jj + 3);
      a0 += h2[(size_t)s0 * 64 + lane];
      a1 += h2[(size_t)s1 * 64 + lane];
      a2 += h2[(size_t)s2 * 64 + lane];
      a3 += h2[(size_t)s3 * 64 + lane];
    }
    for (; jj < rem; ++jj) {
      int s0 = __shfl(sv, jj);
      a0 += h2[(size_t)s0 * 64 + lane];
    }
  }
  float a = (a0 + a1) + (a2 + a3);
  float c = (float)cnt[i];
  if (c < 1.f) c = 1.f;
  agg_s[w][lane] = a / c;
  h2_s[w][lane] = h2[(size_t)i * 64 + lane];
  __syncthreads();
  float s = bl[lane];
  #pragma unroll 4
  for (int k = 0; k < 64; k++)
    s += agg_s[w][k] * wl[k * 64 + lane] + h2_s[w][k] * wr[k * 64 + lane];
  s = s * (bng[lane] * rsqrtf(1.f + BN_EPS)) + bnb[lane];
  s = fmaxf(s, 0.f);
  h3[(size_t)i * 64 + lane] = s;
}

// ------------------------------------------------------------------
__global__ __launch_bounds__(256) void k_pool(
    const float* __restrict__ h3, const int* __restrict__ batch,
    float* __restrict__ psum, float* __restrict__ pmax, float* __restrict__ pcnt) {
  int j = threadIdx.x & 63, grp = threadIdx.x >> 6;
  int nbase = blockIdx.x * 256 + grp * 64;
  float s = 0.f, m = 0.f, cn = 0.f;
  int cur = -1;
  for (int t = 0; t < 64; t++) {
    int n = nbase + t;
    if (n >= NN) break;
    int g = batch[n];
    if (g != cur) {
      if (cur >= 0) {
        atomicAdd(&psum[cur * 64 + j], s);
        atomicMax((int*)&pmax[cur * 64 + j], __float_as_int(m));
        if (j == 0) atomicAdd(&pcnt[cur], cn);
      }
      cur = g; s = 0.f; m = 0.f; cn = 0.f;
    }
    float v = h3[(size_t)n * 64 + j];
    s += v; m = fmaxf(m, v); cn += 1.f;
  }
  if (cur >= 0) {
    atomicAdd(&psum[cur * 64 + j], s);
    atomicMax((int*)&pmax[cur * 64 + j], __float_as_int(m));
    if (j == 0) atomicAdd(&pcnt[cur], cn);
  }
}

// ------------------------------------------------------------------
__global__ void k_graph_head(
    const float* __restrict__ psum, const float* __restrict__ pmax,
    const float* __restrict__ pcnt,
    const float* __restrict__ w1, const float* __restrict__ b1,
    const float* __restrict__ w2, const float* __restrict__ b2,
    const float* __restrict__ w3, const float* __restrict__ b3,
    float* __restrict__ out) {
  __shared__ float hp[128];
  __shared__ float z1[64];
  __shared__ float z2[32];
  int g = blockIdx.x, j = threadIdx.x;
  float c = pcnt[g];
  if (c < 1.f) c = 1.f;
  hp[j] = psum[g * 64 + j] / c;
  hp[64 + j] = pmax[g * 64 + j];
  __syncthreads();
  float s = b1[j];
  #pragma unroll 8
  for (int k = 0; k < 128; k++) s += hp[k] * w1[k * 64 + j];
  z1[j] = fmaxf(s, 0.f);
  __syncthreads();
  if (j < 32) {
    float s2 = b2[j];
    #pragma unroll 8
    for (int k = 0; k < 64; k++) s2 += z1[k] * w2[k * 32 + j];
    z2[j] = fmaxf(s2, 0.f);
  }
  __syncthreads();
  if (j == 0) {
    float s3 = b3[0];
    #pragma unroll
    for (int k = 0; k < 32; k++) s3 += z2[k] * w3[k];
    out[g] = 1.f / (1.f + expf(-s3));
  }
}

// ------------------------------------------------------------------
__global__ __launch_bounds__(256) void k_edge_head(
    const float* __restrict__ h3, const int* __restrict__ ei,
    const float* __restrict__ ea,
    const float* __restrict__ w1, const float* __restrict__ b1,
    const float* __restrict__ w2, const float* __restrict__ b2,
    float* __restrict__ out) {
  int e = blockIdx.x * 256 + threadIdx.x;
  if (e >= NE) return;
  int s = ei[e], d = ei[NE + e];
  float acc[32];
  #pragma unroll
  for (int j = 0; j < 32; j++) acc[j] = b1[j];
  const float4* hs = (const float4*)&h3[(size_t)s * 64];
  const float4* hd = (const float4*)&h3[(size_t)d * 64];
  for (int k4 = 0; k4 < 16; k4++) {
    float4 v = hs[k4];
    const float* w = &w1[k4 * 4 * 32];
    #pragma unroll
    for (int j = 0; j < 32; j++) acc[j] += v.x * w[j];
    #pragma unroll
    for (int j = 0; j < 32; j++) acc[j] += v.y * w[32 + j];
    #pragma unroll
    for (int j = 0; j < 32; j++) acc[j] += v.z * w[64 + j];
    #pragma unroll
    for (int j = 0; j < 32; j++) acc[j] += v.w * w[96 + j];
  }
  for (int k4 = 0; k4 < 16; k4++) {
    float4 v = hd[k4];
    const float* w = &w1[(64 + k4 * 4) * 32];
    #pragma unroll
    for (int j = 0; j < 32; j++) acc[j] += v.x * w[j];
    #pragma unroll
    for (int j = 0; j < 32; j++) acc[j] += v.y * w[32 + j];
    #pragma unroll
    for (int j = 0; j < 32; j++) acc[j] += v.z * w[64 + j];
    #pragma unroll
    for (int j = 0; j < 32; j++) acc[j] += v.w * w[96 + j];
  }
  {
    float4 v = *(const float4*)&ea[(size_t)e * 4];
    const float* w = &w1[128 * 32];
    #pragma unroll
    for (int j = 0; j < 32; j++) acc[j] += v.x * w[j];
    #pragma unroll
    for (int j = 0; j < 32; j++) acc[j] += v.y * w[32 + j];
    #pragma unroll
    for (int j = 0; j < 32; j++) acc[j] += v.z * w[64 + j];
    #pragma unroll
    for (int j = 0; j < 32; j++) acc[j] += v.w * w[96 + j];
  }
  float s2 = b2[0];
  #pragma unroll
  for (int j = 0; j < 32; j++) s2 += fmaxf(acc[j], 0.f) * w2[j];
  out[e] = 1.f / (1.f + expf(-s2));
}

// ------------------------------------------------------------------
extern "C" void kernel_launch(void* const* d_in, const int* in_sizes, int n_in,
                              void* d_out, int out_size, void* d_ws, size_t ws_size,
                              hipStream_t stream) {
  const float* x         = (const float*)d_in[0];
  const float* edge_attr = (const float*)d_in[1];
  const float* enc_w1 = (const float*)d_in[2];
  const float* enc_b1 = (const float*)d_in[3];
  const float* enc_w2 = (const float*)d_in[4];
  const float* enc_b2 = (const float*)d_in[5];
  const float* g1_wl = (const float*)d_in[6];
  const float* g1_wr = (const float*)d_in[7];
  const float* g1_we = (const float*)d_in[8];
  const float* g1_att = (const float*)d_in[9];
  const float* g1_b = (const float*)d_in[10];
  const float* bn1_g = (const float*)d_in[11];
  const float* bn1_b = (const float*)d_in[12];
  const float* g2_wl = (const float*)d_in[13];
  const float* g2_wr = (const float*)d_in[14];
  const float* g2_we = (const float*)d_in[15];
  const float* g2_att = (const float*)d_in[16];
  const float* g2_b = (const float*)d_in[17];
  const float* bn2_g = (const float*)d_in[18];
  const float* bn2_b = (const float*)d_in[19];
  const float* sage_wl = (const float*)d_in[20];
  const float* sage_bl = (const float*)d_in[21];
  const float* sage_wr = (const float*)d_in[22];
  const float* bn3_g = (const float*)d_in[23];
  const float* bn3_b = (const float*)d_in[24];
  const float* gh_w1 = (const float*)d_in[25];
  const float* gh_b1 = (const float*)d_in[26];
  const float* gh_w2 = (const float*)d_in[27];
  const float* gh_b2 = (const float*)d_in[28];
  const float* gh_w3 = (const float*)d_in[29];
  const float* gh_b3 = (const float*)d_in[30];
  const float* eh_w1 = (const float*)d_in[31];
  const float* eh_b1 = (const float*)d_in[32];
  const float* eh_w2 = (const float*)d_in[33];
  const float* eh_b2 = (const float*)d_in[34];
  const int* ei    = (const int*)d_in[35];
  const int* batch = (const int*)d_in[36];
  float* out = (float*)d_out;

  float* ws = (float*)d_ws;
  ushort* xlbf = (ushort*)(ws + OFF_XL);
  float* xr = ws + OFF_XR;
  ushort* h1bf = (ushort*)(ws + OFF_H1);
  ushort* wtl = (ushort*)(ws + OFF_WTL);
  ushort* wtr = (ushort*)(ws + OFF_WTR);
  float* h0 = ws + OFF_H0;   // later h2
  float* h3 = ws + OFF_H3;
  unsigned* cnt = (unsigned*)(ws + OFF_CNT);
  float* psum = ws + OFF_PSUM;
  float* pmax = ws + OFF_PMAX;
  float* pcnt = ws + OFF_PCNT;
  float* ea_csr = ws + OFF_EACSR;
  int* row_ptr = (int*)(ws + OFF_RP);
  int* srcs = (int*)(ws + OFF_SRC);
  int* bsums = (int*)(ws + OFF_BSUM);
  int* rank = (int*)(ws + OFF_XL);   // transient

  hipMemsetAsync(ws + OFF_ZERO, 0, ZERO_FLOATS * sizeof(float), stream);

  k_count<<<NE / 256, 256, 0, stream>>>(ei, cnt, rank);
  k_cast_wt<<<512, 256, 0, stream>>>(g2_wl, g2_wr, wtl, wtr);
  k_encoder<<<NN / (4 * ENC_NPW), 256, 0, stream>>>(x, enc_w1, enc_b1, enc_w2, enc_b2, h0);
  k_scan_blk<<<SCAN_NB, 256, 0, stream>>>(cnt, row_ptr, bsums);
  k_scan_add<<<SCAN_NB, 256, 0, stream>>>(bsums, row_ptr);
  k_csr_scatter<<<NE / 256, 256, 0, stream>>>(ei, rank, row_ptr, edge_attr, srcs, ea_csr);
  k_loop_row<<<(NN + 255) / 256, 256, 0, stream>>>(row_ptr, srcs, ea_csr);

  // ---- GAT layer 1 (fp32 vector GEMMs, K=64) ----
  k_gemm256<64, 1><<<NN / 32, 256, 0, stream>>>(h0, g1_wl, (void*)xlbf);
  k_gemm256<64, 0><<<NN / 32, 256, 0, stream>>>(h0, g1_wr, (void*)xr);
  k_gat_fused<1><<<NN / 4, 256, 0, stream>>>(xlbf, xr, g1_we, g1_att, srcs, ea_csr,
                                             row_ptr, g1_b, bn1_g, bn1_b, (void*)h1bf);

  // ---- GAT layer 2 (MFMA bf16 GEMMs, K=256) ----
  k_gemm_mfma<1><<<NN / 32, 256, 0, stream>>>(h1bf, wtl, (void*)xlbf);
  k_gemm_mfma<0><<<NN / 32, 256, 0, stream>>>(h1bf, wtr, (void*)xr);
  k_gat_fused<0><<<NN / 4, 256, 0, stream>>>(xlbf, xr, g2_we, g2_att, srcs, ea_csr,
                                             row_ptr, g2_b, bn2_g, bn2_b, (void*)h0);

  // ---- SAGE ----
  k_sage<<<NN / 4, 256, 0, stream>>>(h0, row_ptr, srcs, cnt, sage_wl, sage_bl, sage_wr, bn3_g, bn3_b, h3);

  // ---- pooling + heads ----
  k_pool<<<(NN + 255) / 256, 256, 0, stream>>>(h3, batch, psum, pmax, pcnt);
  k_graph_head<<<NG, 64, 0, stream>>>(psum, pmax, pcnt, gh_w1, gh_b1, gh_w2, gh_b2, gh_w3, gh_b3, out);
  k_edge_head<<<NE / 256, 256, 0, stream>>>(h3, ei, edge_attr, eh_w1, eh_b1, eh_w2, eh_b2, out + NG);
}